// Round 8
// baseline (464.332 us; speedup 1.0000x reference)
//
#include <hip/hip_runtime.h>
#include <hip/hip_bf16.h>

#define NEG_SLOPE 0.2f
#define EPS_BN 1e-5f
#define EPS_SM 1e-16f
#define CAP 128   // padded adjacency row capacity (Poisson(17): P(deg>128) ~ 0; clamped anyway)
#define DEGS 16   // deg counter stride (ints): one counter per 64B line

typedef __bf16 bf16x8 __attribute__((ext_vector_type(8)));
typedef __bf16 bf16x4 __attribute__((ext_vector_type(4)));
typedef float floatx4 __attribute__((ext_vector_type(4)));

__device__ __forceinline__ float leaky(float x) { return x > 0.f ? x : NEG_SLOPE * x; }

// ---- init: block 0 = edge dtype detect; blocks 1..128 = zero; blocks 129.. = weight conv ----
// (wconv moved here so the fused hist+gemm1 kernel can safely read Wb1)
__global__ void k_init(const int* __restrict__ ei, int* __restrict__ flag,
                       int* __restrict__ zbase, int zwords, int e,
                       const float* __restrict__ W1, __bf16* __restrict__ Wb1,
                       const float* __restrict__ W2, __bf16* __restrict__ Wb2,
                       const float* __restrict__ W3, __bf16* __restrict__ Wb3) {
    if (blockIdx.x == 0) {
        __shared__ int cnt_s[256];
        int i = threadIdx.x;  // pairs 0..255
        int nz = (2 * i + 1 < 2 * e && ei[2 * i + 1] != 0) ? 1 : 0;
        cnt_s[i] = nz;
        __syncthreads();
        for (int off = 128; off > 0; off >>= 1) {
            if (i < off) cnt_s[i] += cnt_s[i + off];
            __syncthreads();
        }
        if (i == 0) *flag = (cnt_s[0] < 128) ? 1 : 0;  // 1 => int64 layout
        return;
    }
    if (blockIdx.x >= 129) {
        int idx = (blockIdx.x - 129) * 256 + threadIdx.x;
        if (idx < 32768) {                      // W1: K=128, M=256
            int mm = idx >> 7, kk = idx & 127;
            Wb1[idx] = (__bf16)W1[(size_t)kk * 256 + mm];
        } else if (idx < 65536) {               // W2: K=256, M=128
            int i2 = idx - 32768;
            int mm = i2 >> 8, kk = i2 & 255;
            Wb2[i2] = (__bf16)W2[(size_t)kk * 128 + mm];
        } else if (idx < 81920) {               // W3: K=128, M=128
            int i3 = idx - 65536;
            int mm = i3 >> 7, kk = i3 & 127;
            Wb3[i3] = (__bf16)W3[(size_t)kk * 128 + mm];
        }
        return;
    }
    int g = (blockIdx.x - 1) * 256 + threadIdx.x;
    const int stride = 128 * 256;
    for (int k = g; k < zwords; k += stride) zbase[k] = 0;
}

// ---- FUSED: layer-1 GEMM (CSR-independent MFMA work) + edge hist/scatter.
//      GEMM blocks first in grid; they compute while edge blocks grind on the
//      device-scope atomic service rate (~60us of near-idle CU time).
__global__ __launch_bounds__(256) void k_hist_gemm1(
        const int* __restrict__ ei, const int* __restrict__ flag,
        int* __restrict__ deg, int* __restrict__ col, int e, int ng1,
        const float* __restrict__ x, const __bf16* __restrict__ Bt,
        __bf16* __restrict__ xhb, int n,
        const float* __restrict__ att_s, const float* __restrict__ att_d,
        float* __restrict__ asrc, float* __restrict__ adst) {
    __shared__ __align__(16) __bf16 As[128][72];
    __shared__ __align__(16) __bf16 Bs[128][72];
    if ((int)blockIdx.x >= ng1) {
        // ---- edge phase: hist + direct scatter (rank from returning atomic) ----
        int g = (blockIdx.x - ng1) * 256 + threadIdx.x;
        if (g < e) {
            bool is64 = (*flag) != 0;
            int s = is64 ? ei[2 * g] : ei[g];
            int d = is64 ? ei[2 * (e + g)] : ei[e + g];
            int r = atomicAdd(&deg[(size_t)d * DEGS], 1);
            if (r < CAP) col[((size_t)d << 7) + r] = s;
        }
        return;
    }
    // ---- gemm1: xh[row, col0+*] = x[row,:] @ W1[:, col0+*]; fused attn dots ----
    const int row0 = (blockIdx.x >> 1) * 128, col0 = (blockIdx.x & 1) * 128;
    const int lane = threadIdx.x & 63, w = threadIdx.x >> 6;
    const int m = lane & 15, quad = lane >> 4;
    floatx4 acc[2][8];
#pragma unroll
    for (int i = 0; i < 2; ++i)
#pragma unroll
        for (int j = 0; j < 8; ++j) acc[i][j] = (floatx4)0.f;
    const int sr = threadIdx.x >> 1;
    const int sk = (threadIdx.x & 1) * 32;
    for (int kc = 0; kc < 128; kc += 64) {
        {
            int grow = row0 + sr;
            if (grow < n) {
                const float* p = x + (size_t)grow * 128 + kc + sk;
#pragma unroll
                for (int q = 0; q < 8; ++q) {
                    float4 v = *reinterpret_cast<const float4*>(p + q * 4);
                    bf16x4 cv = {(__bf16)v.x, (__bf16)v.y, (__bf16)v.z, (__bf16)v.w};
                    *reinterpret_cast<bf16x4*>(&As[sr][sk + q * 4]) = cv;
                }
            } else {
#pragma unroll
                for (int q = 0; q < 4; ++q)
                    *reinterpret_cast<bf16x8*>(&As[sr][sk + q * 8]) = (bf16x8)(__bf16)0.f;
            }
        }
        {
            const __bf16* p = Bt + (size_t)(col0 + sr) * 128 + kc + sk;
#pragma unroll
            for (int q = 0; q < 4; ++q)
                *reinterpret_cast<bf16x8*>(&Bs[sr][sk + q * 8]) =
                    *reinterpret_cast<const bf16x8*>(p + q * 8);
        }
        __syncthreads();
#pragma unroll
        for (int ks = 0; ks < 64; ks += 32) {
            bf16x8 a0 = *reinterpret_cast<const bf16x8*>(&As[w * 32 + m][ks + quad * 8]);
            bf16x8 a1 = *reinterpret_cast<const bf16x8*>(&As[w * 32 + 16 + m][ks + quad * 8]);
#pragma unroll
            for (int nt = 0; nt < 8; ++nt) {
                bf16x8 b = *reinterpret_cast<const bf16x8*>(&Bs[nt * 16 + m][ks + quad * 8]);
                acc[0][nt] = __builtin_amdgcn_mfma_f32_16x16x32_bf16(a0, b, acc[0][nt], 0, 0, 0);
                acc[1][nt] = __builtin_amdgcn_mfma_f32_16x16x32_bf16(a1, b, acc[1][nt], 0, 0, 0);
            }
        }
        __syncthreads();
    }
#pragma unroll
    for (int mt = 0; mt < 2; ++mt)
#pragma unroll
        for (int nt = 0; nt < 8; ++nt)
#pragma unroll
            for (int r = 0; r < 4; ++r) {
                int row = row0 + w * 32 + mt * 16 + quad * 4 + r;
                if (row < n) xhb[(size_t)row * 256 + col0 + nt * 16 + m] = (__bf16)acc[mt][nt][r];
            }
    // fused attention dots (single complete head per block -> plain store)
    {
        float asv[8], adv[8];
#pragma unroll
        for (int nt = 0; nt < 8; ++nt) {
            int c = col0 + nt * 16 + m;
            asv[nt] = att_s[c];
            adv[nt] = att_d[c];
        }
        const int h = (col0 >> 7) & 1;
#pragma unroll
        for (int mt = 0; mt < 2; ++mt)
#pragma unroll
            for (int r = 0; r < 4; ++r) {
                int row = row0 + w * 32 + mt * 16 + quad * 4 + r;
                float pa = 0.f, pb = 0.f;
#pragma unroll
                for (int nt = 0; nt < 8; ++nt) {
                    float v = acc[mt][nt][r];
                    pa += v * asv[nt];
                    pb += v * adv[nt];
                }
#pragma unroll
                for (int off = 1; off <= 8; off <<= 1) {
                    pa += __shfl_xor(pa, off);
                    pb += __shfl_xor(pb, off);
                }
                if (m == 0 && row < n) {
                    asrc[2 * row + h] = pa;
                    adst[2 * row + h] = pb;
                }
            }
    }
}

// ---- bf16 MFMA GEMM (layers 2/3), inline BN prep + attn dots ----
template <int K, int LC, bool BF16IN, int NT>
__global__ __launch_bounds__(256) void k_gemm(const void* __restrict__ Ain,
                                              const __bf16* __restrict__ Bt,
                                              __bf16* __restrict__ Cb, int n, int M,
                                              const float* __restrict__ bnsums,
                                              const float* __restrict__ gam,
                                              const float* __restrict__ bet,
                                              const float* __restrict__ att_s,
                                              const float* __restrict__ att_d,
                                              float* __restrict__ asrc,
                                              float* __restrict__ adst) {
    __shared__ __align__(16) __bf16 As[128][72];
    __shared__ __align__(16) __bf16 Bs[NT * 16][72];
    __shared__ float sc_lds[K], sh_lds[K];
    const int row0 = blockIdx.y * 128, col0 = blockIdx.x * (NT * 16);
    const int lane = threadIdx.x & 63, w = threadIdx.x >> 6;
    const int m = lane & 15, quad = lane >> 4;

    if (bnsums) {
        for (int c = threadIdx.x; c < K; c += 256) {
            float mean = bnsums[c] / n;
            float var = bnsums[256 + c] / n - mean * mean;
            float sc = gam[c] * rsqrtf(var + EPS_BN);
            sc_lds[c] = sc;
            sh_lds[c] = bet[c] - mean * sc;
        }
        __syncthreads();
    }

    floatx4 acc[2][NT];
#pragma unroll
    for (int i = 0; i < 2; ++i)
#pragma unroll
        for (int j = 0; j < NT; ++j) acc[i][j] = (floatx4)0.f;

    const int sr = threadIdx.x >> 1;        // A-stage: 0..127
    const int sk = (threadIdx.x & 1) * 32;

    for (int kc = 0; kc < K; kc += 64) {
        {
            int grow = row0 + sr;
            if (grow < n) {
                if (BF16IN) {
                    const __bf16* p = (const __bf16*)Ain + (size_t)grow * K + kc + sk;
#pragma unroll
                    for (int q = 0; q < 4; ++q) {
                        bf16x8 vv = *reinterpret_cast<const bf16x8*>(p + q * 8);
                        if (bnsums) {
                            int c = kc + sk + q * 8;
                            bf16x8 r;
#pragma unroll
                            for (int e2 = 0; e2 < 8; ++e2)
                                r[e2] = (__bf16)((float)vv[e2] * sc_lds[c + e2] + sh_lds[c + e2]);
                            vv = r;
                        }
                        *reinterpret_cast<bf16x8*>(&As[sr][sk + q * 8]) = vv;
                    }
                } else {
                    const float* p = (const float*)Ain + (size_t)grow * K + kc + sk;
#pragma unroll
                    for (int q = 0; q < 8; ++q) {
                        float4 v = *reinterpret_cast<const float4*>(p + q * 4);
                        bf16x4 cv = {(__bf16)v.x, (__bf16)v.y, (__bf16)v.z, (__bf16)v.w};
                        *reinterpret_cast<bf16x4*>(&As[sr][sk + q * 4]) = cv;
                    }
                }
            } else {
#pragma unroll
                for (int q = 0; q < 4; ++q)
                    *reinterpret_cast<bf16x8*>(&As[sr][sk + q * 8]) = (bf16x8)(__bf16)0.f;
            }
        }
        if (NT == 8) {
            const __bf16* p = Bt + (size_t)(col0 + sr) * K + kc + sk;
#pragma unroll
            for (int q = 0; q < 4; ++q)
                *reinterpret_cast<bf16x8*>(&Bs[sr][sk + q * 8]) =
                    *reinterpret_cast<const bf16x8*>(p + q * 8);
        } else {  // NT==4: 64 B-rows, 16 bf16 per thread
            int sr4 = threadIdx.x >> 2, sk4 = (threadIdx.x & 3) * 16;
            const __bf16* p = Bt + (size_t)(col0 + sr4) * K + kc + sk4;
            *reinterpret_cast<bf16x8*>(&Bs[sr4][sk4]) = *reinterpret_cast<const bf16x8*>(p);
            *reinterpret_cast<bf16x8*>(&Bs[sr4][sk4 + 8]) = *reinterpret_cast<const bf16x8*>(p + 8);
        }
        __syncthreads();
#pragma unroll
        for (int ks = 0; ks < 64; ks += 32) {
            bf16x8 a0 = *reinterpret_cast<const bf16x8*>(&As[w * 32 + m][ks + quad * 8]);
            bf16x8 a1 = *reinterpret_cast<const bf16x8*>(&As[w * 32 + 16 + m][ks + quad * 8]);
#pragma unroll
            for (int nt = 0; nt < NT; ++nt) {
                bf16x8 b = *reinterpret_cast<const bf16x8*>(&Bs[nt * 16 + m][ks + quad * 8]);
                acc[0][nt] = __builtin_amdgcn_mfma_f32_16x16x32_bf16(a0, b, acc[0][nt], 0, 0, 0);
                acc[1][nt] = __builtin_amdgcn_mfma_f32_16x16x32_bf16(a1, b, acc[1][nt], 0, 0, 0);
            }
        }
        __syncthreads();
    }
#pragma unroll
    for (int mt = 0; mt < 2; ++mt)
#pragma unroll
        for (int nt = 0; nt < NT; ++nt)
#pragma unroll
            for (int r = 0; r < 4; ++r) {
                int row = row0 + w * 32 + mt * 16 + quad * 4 + r;
                if (row < n) Cb[(size_t)row * M + col0 + nt * 16 + m] = (__bf16)acc[mt][nt][r];
            }
    // fused attention dots (single complete head per block -> plain store)
    {
        float asv[NT], adv[NT];
#pragma unroll
        for (int nt = 0; nt < NT; ++nt) {
            int c = col0 + nt * 16 + m;
            asv[nt] = att_s[c];
            adv[nt] = att_d[c];
        }
        const int h = (col0 >> LC) & 1;
#pragma unroll
        for (int mt = 0; mt < 2; ++mt)
#pragma unroll
            for (int r = 0; r < 4; ++r) {
                int row = row0 + w * 32 + mt * 16 + quad * 4 + r;
                float pa = 0.f, pb = 0.f;
#pragma unroll
                for (int nt = 0; nt < NT; ++nt) {
                    float v = acc[mt][nt][r];
                    pa += v * asv[nt];
                    pb += v * adv[nt];
                }
#pragma unroll
                for (int off = 1; off <= 8; off <<= 1) {
                    pa += __shfl_xor(pa, off);
                    pb += __shfl_xor(pb, off);
                }
                if (m == 0 && row < n) {
                    asrc[2 * row + h] = pa;
                    adst[2 * row + h] = pb;
                }
            }
    }
}

// ---- final linear via MFMA: out[n,64](f32) = A[n,128](f32) @ lw[128,64] + lb ----
__global__ __launch_bounds__(256) void k_lin(const float* __restrict__ A,
                                             const float* __restrict__ lw,
                                             const float* __restrict__ lb,
                                             float* __restrict__ out, int n) {
    __shared__ __align__(16) __bf16 Ahi[64][136];
    __shared__ __align__(16) __bf16 Alo[64][136];
    __shared__ __align__(16) __bf16 Bhi[64][136];
    const int row0 = blockIdx.x * 64;
    const int lane = threadIdx.x & 63, w = threadIdx.x >> 6;
    const int m = lane & 15, quad = lane >> 4;
    floatx4 acc[4];
#pragma unroll
    for (int i = 0; i < 4; ++i) acc[i] = (floatx4)0.f;
    {
        int sr = threadIdx.x >> 2, sk0 = (threadIdx.x & 3) * 32;
        int grow = row0 + sr;
#pragma unroll
        for (int q = 0; q < 8; ++q) {
            float4 v = make_float4(0.f, 0.f, 0.f, 0.f);
            if (grow < n) v = *reinterpret_cast<const float4*>(A + (size_t)grow * 128 + sk0 + q * 4);
            float vv[4] = {v.x, v.y, v.z, v.w};
#pragma unroll
            for (int i = 0; i < 4; ++i) {
                __bf16 h = (__bf16)vv[i];
                Ahi[sr][sk0 + q * 4 + i] = h;
                Alo[sr][sk0 + q * 4 + i] = (__bf16)(vv[i] - (float)h);
            }
        }
    }
    {
        int k0 = threadIdx.x >> 1, m0 = (threadIdx.x & 1) * 32;
#pragma unroll
        for (int q = 0; q < 8; ++q) {
            float4 v = *reinterpret_cast<const float4*>(lw + (size_t)k0 * 64 + m0 + q * 4);
            float vv[4] = {v.x, v.y, v.z, v.w};
#pragma unroll
            for (int i = 0; i < 4; ++i) Bhi[m0 + q * 4 + i][k0] = (__bf16)vv[i];
        }
    }
    __syncthreads();
#pragma unroll
    for (int ks = 0; ks < 128; ks += 32) {
        bf16x8 ah = *reinterpret_cast<const bf16x8*>(&Ahi[w * 16 + m][ks + quad * 8]);
        bf16x8 al = *reinterpret_cast<const bf16x8*>(&Alo[w * 16 + m][ks + quad * 8]);
#pragma unroll
        for (int nt = 0; nt < 4; ++nt) {
            bf16x8 bh = *reinterpret_cast<const bf16x8*>(&Bhi[nt * 16 + m][ks + quad * 8]);
            acc[nt] = __builtin_amdgcn_mfma_f32_16x16x32_bf16(ah, bh, acc[nt], 0, 0, 0);
            acc[nt] = __builtin_amdgcn_mfma_f32_16x16x32_bf16(al, bh, acc[nt], 0, 0, 0);
        }
    }
#pragma unroll
    for (int nt = 0; nt < 4; ++nt)
#pragma unroll
        for (int r = 0; r < 4; ++r) {
            int row = row0 + w * 16 + quad * 4 + r;
            int c = nt * 16 + m;
            if (row < n) out[(size_t)row * 64 + c] = acc[nt][r] + lb[c];
        }
}

// ---- GAT aggregation (all layers): node-per-wave depth-4 + SPLIT slots
//      (addr-early / weight-late; row gathers overlap asrc gather + exp chain) ----
template <int C, bool OUTBF16>
__global__ __launch_bounds__(256) void k_agg(const __bf16* __restrict__ xh,
                                             const float* __restrict__ asrc,
                                             const float* __restrict__ adst,
                                             const int* __restrict__ degv,
                                             const int* __restrict__ col,
                                             const float* __restrict__ bias,
                                             void* __restrict__ outv, int n) {
    constexpr int F = 2 * C;          // bf16 per row (256 or 128)
    constexpr int G = F / 8;          // lanes per edge (32 or 16)
    constexpr int NG = 64 / G;        // edges per wave-step (2 or 4)
    constexpr int GSH = (G == 32) ? 5 : 4;
    __shared__ int sA[4][80];
    __shared__ float2 sW[4][80];
    const int widx = threadIdx.x >> 6;
    const int node = blockIdx.x * 4 + widx;
    const int lane = threadIdx.x & 63;
    if (node >= n) return;
    const int t = lane & (G - 1);
    const int g = lane >> GSH;
    const bool h1 = (t * 8) >= C;
    const int selfoff = node * (F * 2);
    if (lane >= 48) { sA[widx][lane + 16] = selfoff; sW[widx][lane + 16] = make_float2(0.f, 0.f); }
    const char* xbt = (const char*)xh + t * 16;
    const int* crow = col + ((size_t)node << 7);
    const int deg = min(degv[(size_t)node * DEGS], CAP);
    const float2 adv = *reinterpret_cast<const float2*>(adst + 2 * node);
    const float2 asv = *reinterpret_cast<const float2*>(asrc + 2 * node);
    const float es0 = leaky(asv.x + adv.x), es1 = leaky(asv.y + adv.y);
    bf16x8 vself = *reinterpret_cast<const bf16x8*>(xbt + selfoff);  // early issue
    float acc[8] = {};
    float d0 = 0.f, d1 = 0.f;
    for (int base = 0; base < deg; base += 64) {
        const int cnt = min(64, deg - base);
        int s = (lane < cnt) ? crow[base + lane] : node;
        sA[widx][lane] = s * (F * 2);
        float2 av = *reinterpret_cast<const float2*>(asrc + 2 * s);
        float w0 = 0.f, w1 = 0.f;
        if (lane < cnt) {
            w0 = __expf(leaky(av.x + adv.x));
            w1 = __expf(leaky(av.y + adv.y));
            d0 += w0; d1 += w1;
        }
        sW[widx][lane] = make_float2(w0, w1);
        for (int j = g; j < cnt; j += 4 * NG) {
            int o0 = sA[widx][j], o1 = sA[widx][j + NG], o2 = sA[widx][j + 2 * NG], o3 = sA[widx][j + 3 * NG];
            bf16x8 v0 = *reinterpret_cast<const bf16x8*>(xbt + o0);
            bf16x8 v1 = *reinterpret_cast<const bf16x8*>(xbt + o1);
            bf16x8 v2 = *reinterpret_cast<const bf16x8*>(xbt + o2);
            bf16x8 v3 = *reinterpret_cast<const bf16x8*>(xbt + o3);
            float2 x0 = sW[widx][j], x1 = sW[widx][j + NG], x2 = sW[widx][j + 2 * NG], x3 = sW[widx][j + 3 * NG];
            float w0 = h1 ? x0.y : x0.x;
            float w1 = h1 ? x1.y : x1.x;
            float w2 = h1 ? x2.y : x2.x;
            float w3 = h1 ? x3.y : x3.x;
#pragma unroll
            for (int q = 0; q < 8; ++q)
                acc[q] += w0 * (float)v0[q] + w1 * (float)v1[q] +
                          w2 * (float)v2[q] + w3 * (float)v3[q];
        }
    }
#pragma unroll
    for (int off = 1; off <= 32; off <<= 1) {
        d0 += __shfl_xor(d0, off);
        d1 += __shfl_xor(d1, off);
    }
#pragma unroll
    for (int q = 0; q < 8; ++q) {
#pragma unroll
        for (int off = G; off < 64; off <<= 1) acc[q] += __shfl_xor(acc[q], off);
    }
    float exs0 = __expf(es0), exs1 = __expf(es1);
    d0 += exs0; d1 += exs1;
    {
        float ws = h1 ? exs1 : exs0;
#pragma unroll
        for (int q = 0; q < 8; ++q) acc[q] += ws * (float)vself[q];
    }
    float inv = 1.0f / ((h1 ? d1 : d0) + EPS_SM);
    float o[8];
#pragma unroll
    for (int q = 0; q < 8; ++q) o[q] = fmaxf(acc[q] * inv + bias[t * 8 + q], 0.f);
    if (g == 0) {
        if constexpr (OUTBF16) {
            __bf16* po = (__bf16*)outv + (size_t)node * F + t * 8;
            bf16x8 st;
#pragma unroll
            for (int q = 0; q < 8; ++q) st[q] = (__bf16)o[q];
            *reinterpret_cast<bf16x8*>(po) = st;
        } else {
            float* po = (float*)outv + (size_t)node * F + t * 8;
            *reinterpret_cast<float4*>(po) = make_float4(o[0], o[1], o[2], o[3]);
            *reinterpret_cast<float4*>(po + 4) = make_float4(o[4], o[5], o[6], o[7]);
        }
    }
}

// ---------------- BatchNorm stats (256 blocks = low contention) ----
template <typename T>
__global__ void k_bn_stats(const T* __restrict__ x, float* __restrict__ sums,
                           float* __restrict__ sqs, int n, int f) {
    int c = threadIdx.x;
    float s = 0.f, q = 0.f;
    for (int r = blockIdx.x; r < n; r += gridDim.x) {
        float v = (float)x[(size_t)r * f + c];
        s += v; q += v * v;
    }
    atomicAdd(&sums[c], s);
    atomicAdd(&sqs[c], q);
}

// ---------------- launch ----------------
extern "C" void kernel_launch(void* const* d_in, const int* in_sizes, int n_in,
                              void* d_out, int out_size, void* d_ws, size_t ws_size,
                              hipStream_t stream) {
    const float* x   = (const float*)d_in[0];
    const int*   ei  = (const int*)d_in[1];
    const float* W1  = (const float*)d_in[2];
    const float* as1 = (const float*)d_in[3];
    const float* ad1 = (const float*)d_in[4];
    const float* b1  = (const float*)d_in[5];
    const float* g1  = (const float*)d_in[6];
    const float* be1 = (const float*)d_in[7];
    const float* W2  = (const float*)d_in[8];
    const float* as2 = (const float*)d_in[9];
    const float* ad2 = (const float*)d_in[10];
    const float* b2  = (const float*)d_in[11];
    const float* g2  = (const float*)d_in[12];
    const float* be2 = (const float*)d_in[13];
    const float* W3  = (const float*)d_in[14];
    const float* as3 = (const float*)d_in[15];
    const float* ad3 = (const float*)d_in[16];
    const float* b3  = (const float*)d_in[17];
    const float* lw  = (const float*)d_in[18];
    const float* lb  = (const float*)d_in[19];
    float* outp = (float*)d_out;

    const int n = in_sizes[0] / 128;  // 50000
    const int e = in_sizes[1] / 2;    // 800000

    char* w = (char*)d_ws;
    size_t off = 0;
    auto alloc = [&](size_t bytes) -> void* {
        void* p = w + off;
        off += (bytes + 255) & ~(size_t)255;
        return p;
    };
    __bf16* xhb = (__bf16*)alloc((size_t)n * 256 * 2);  // xh1; reused as xh2/xh3
    __bf16* h1b = (__bf16*)alloc((size_t)n * 256 * 2);
    __bf16* h2b = (__bf16*)alloc((size_t)n * 128 * 2);
    float*  h3f = (float*)alloc((size_t)n * 128 * 4);
    int* colb   = (int*)alloc((size_t)n * CAP * 4);  // padded adjacency (25.6 MB)
    __bf16* Wb1 = (__bf16*)alloc(256 * 128 * 2);
    __bf16* Wb2 = (__bf16*)alloc(128 * 256 * 2);
    __bf16* Wb3 = (__bf16*)alloc(128 * 128 * 2);
    int* flag   = (int*)alloc(256);
    float* as1p = (float*)alloc((size_t)n * 2 * 4);
    float* ad1p = (float*)alloc((size_t)n * 2 * 4);
    float* as2p = (float*)alloc((size_t)n * 2 * 4);
    float* ad2p = (float*)alloc((size_t)n * 2 * 4);
    float* as3p = (float*)alloc((size_t)n * 2 * 4);
    float* ad3p = (float*)alloc((size_t)n * 2 * 4);
    // ---- contiguous zero block ----
    char* zb_begin = (char*)(w + off);
    int* deg    = (int*)alloc((size_t)n * DEGS * 4);  // line-padded counters (3.2 MB)
    float* bn1  = (float*)alloc(512 * 4);
    float* bn2  = (float*)alloc(512 * 4);
    char* zb_end = (char*)(w + off);
    const int zwords = (int)((zb_end - zb_begin) / 4);

    // init: detect (block 0) + zero (blocks 1..128) + weight convert (blocks 129..448)
    k_init<<<449, 256, 0, stream>>>(ei, flag, (int*)zb_begin, zwords, e,
                                    W1, Wb1, W2, Wb2, W3, Wb3);

    const int nrow = (n + 127) / 128;
    const int ng1 = 2 * nrow;                 // gemm1 blocks (placed FIRST in grid)
    const int eb = ((e + 255) / 256);         // edge blocks
    k_hist_gemm1<<<ng1 + eb, 256, 0, stream>>>(ei, flag, deg, colb, e, ng1,
                                               x, Wb1, xhb, n, as1, ad1, as1p, ad1p);

    const int nwb = (n + 3) / 4;

    // ---- layer 1: aggregation (gemm1 already done under the hist atomic drain) ----
    k_agg<128, true><<<nwb, 256, 0, stream>>>(xhb, as1p, ad1p, deg, colb, b1, h1b, n);
    k_bn_stats<__bf16><<<256, 256, 0, stream>>>(h1b, bn1, bn1 + 256, n, 256);

    // ---- layer 2: 256 -> 2x64 (BN1 inline in GEMM prologue; 64-col tiles) ----
    k_gemm<256, 6, true, 4><<<dim3(2, nrow), 256, 0, stream>>>(
        h1b, Wb2, xhb, n, 128, bn1, g1, be1, as2, ad2, as2p, ad2p);
    k_agg<64, true><<<nwb, 256, 0, stream>>>(xhb, as2p, ad2p, deg, colb, b2, h2b, n);
    k_bn_stats<__bf16><<<256, 128, 0, stream>>>(h2b, bn2, bn2 + 256, n, 128);

    // ---- layer 3: 128 -> 2x64 (BN2 inline) ----
    k_gemm<128, 6, true, 4><<<dim3(2, nrow), 256, 0, stream>>>(
        h2b, Wb3, xhb, n, 128, bn2, g2, be2, as3, ad3, as3p, ad3p);
    k_agg<64, false><<<nwb, 256, 0, stream>>>(xhb, as3p, ad3p, deg, colb, b3, h3f, n);

    // ---- final linear ----
    k_lin<<<(n + 63) / 64, 256, 0, stream>>>(h3f, lw, lb, outp, n);
}

// Round 9
// 455.577 us; speedup vs baseline: 1.0192x; 1.0192x over previous
//
#include <hip/hip_runtime.h>
#include <hip/hip_bf16.h>

#define NEG_SLOPE 0.2f
#define EPS_BN 1e-5f
#define EPS_SM 1e-16f
#define CAP 128   // padded adjacency row capacity (Poisson(17): P(deg>128) ~ 0; clamped anyway)
#define DEGS 16   // deg counter stride (ints): one counter per 64B line

typedef __bf16 bf16x8 __attribute__((ext_vector_type(8)));
typedef __bf16 bf16x4 __attribute__((ext_vector_type(4)));
typedef float floatx4 __attribute__((ext_vector_type(4)));

__device__ __forceinline__ float leaky(float x) { return x > 0.f ? x : NEG_SLOPE * x; }

// ---- init: block 0 = edge dtype detect; blocks 1..128 = zero; blocks 129.. = weight conv ----
__global__ void k_init(const int* __restrict__ ei, int* __restrict__ flag,
                       int* __restrict__ zbase, int zwords, int e,
                       const float* __restrict__ W1, __bf16* __restrict__ Wb1,
                       const float* __restrict__ W2, __bf16* __restrict__ Wb2,
                       const float* __restrict__ W3, __bf16* __restrict__ Wb3) {
    if (blockIdx.x == 0) {
        __shared__ int cnt_s[256];
        int i = threadIdx.x;  // pairs 0..255
        int nz = (2 * i + 1 < 2 * e && ei[2 * i + 1] != 0) ? 1 : 0;
        cnt_s[i] = nz;
        __syncthreads();
        for (int off = 128; off > 0; off >>= 1) {
            if (i < off) cnt_s[i] += cnt_s[i + off];
            __syncthreads();
        }
        if (i == 0) *flag = (cnt_s[0] < 128) ? 1 : 0;  // 1 => int64 layout
        return;
    }
    if (blockIdx.x >= 129) {
        int idx = (blockIdx.x - 129) * 256 + threadIdx.x;
        if (idx < 32768) {                      // W1: K=128, M=256
            int mm = idx >> 7, kk = idx & 127;
            Wb1[idx] = (__bf16)W1[(size_t)kk * 256 + mm];
        } else if (idx < 65536) {               // W2: K=256, M=128
            int i2 = idx - 32768;
            int mm = i2 >> 8, kk = i2 & 255;
            Wb2[i2] = (__bf16)W2[(size_t)kk * 128 + mm];
        } else if (idx < 81920) {               // W3: K=128, M=128
            int i3 = idx - 65536;
            int mm = i3 >> 7, kk = i3 & 127;
            Wb3[i3] = (__bf16)W3[(size_t)kk * 128 + mm];
        }
        return;
    }
    int g = (blockIdx.x - 1) * 256 + threadIdx.x;
    const int stride = 128 * 256;
    for (int k = g; k < zwords; k += stride) zbase[k] = 0;
}

// ---- FUSED: every block = one gemm1 tile + a 1024-edge chunk, interleaved:
//      issue atomics -> MFMA iter0 (hides atomic latency) -> scatter stores
//      (drain under iter1+epilogue+other blocks). 782 blocks, all co-resident.
__global__ __launch_bounds__(256) void k_hist_gemm1(
        const int* __restrict__ ei, const int* __restrict__ flag,
        int* __restrict__ deg, int* __restrict__ col, int e, int ng1,
        const float* __restrict__ x, const __bf16* __restrict__ Bt,
        __bf16* __restrict__ xhb, int n,
        const float* __restrict__ att_s, const float* __restrict__ att_d,
        float* __restrict__ asrc, float* __restrict__ adst) {
    __shared__ __align__(16) __bf16 As[128][72];
    __shared__ __align__(16) __bf16 Bs[128][72];
    const int estride = ng1 * 256;
    const int ebase = blockIdx.x * 256 + threadIdx.x;

    // ---- phase 1: load up to 4 edges, ISSUE returning atomics (non-blocking) ----
    int es[4], ed[4], er[4];
    int ecnt = 0;
    {
        bool is64 = (*flag) != 0;
#pragma unroll 4
        for (int i = 0; i < 4; ++i) {
            int g = ebase + i * estride;
            if (g < e) {
                int s = is64 ? ei[2 * g] : ei[g];
                int d = is64 ? ei[2 * (e + g)] : ei[e + g];
                es[i] = s; ed[i] = d;
                er[i] = atomicAdd(&deg[(size_t)d * DEGS], 1);
                ecnt = i + 1;
            }
        }
    }

    // ---- gemm1: xh[row, col0+*] = x[row,:] @ W1[:, col0+*]; fused attn dots ----
    const int row0 = (blockIdx.x >> 1) * 128, col0 = (blockIdx.x & 1) * 128;
    const int lane = threadIdx.x & 63, w = threadIdx.x >> 6;
    const int m = lane & 15, quad = lane >> 4;
    floatx4 acc[2][8];
#pragma unroll
    for (int i = 0; i < 2; ++i)
#pragma unroll
        for (int j = 0; j < 8; ++j) acc[i][j] = (floatx4)0.f;
    const int sr = threadIdx.x >> 1;
    const int sk = (threadIdx.x & 1) * 32;
#pragma unroll
    for (int kc = 0; kc < 128; kc += 64) {
        {
            int grow = row0 + sr;
            if (grow < n) {
                const float* p = x + (size_t)grow * 128 + kc + sk;
#pragma unroll
                for (int q = 0; q < 8; ++q) {
                    float4 v = *reinterpret_cast<const float4*>(p + q * 4);
                    bf16x4 cv = {(__bf16)v.x, (__bf16)v.y, (__bf16)v.z, (__bf16)v.w};
                    *reinterpret_cast<bf16x4*>(&As[sr][sk + q * 4]) = cv;
                }
            } else {
#pragma unroll
                for (int q = 0; q < 4; ++q)
                    *reinterpret_cast<bf16x8*>(&As[sr][sk + q * 8]) = (bf16x8)(__bf16)0.f;
            }
        }
        {
            const __bf16* p = Bt + (size_t)(col0 + sr) * 128 + kc + sk;
#pragma unroll
            for (int q = 0; q < 4; ++q)
                *reinterpret_cast<bf16x8*>(&Bs[sr][sk + q * 8]) =
                    *reinterpret_cast<const bf16x8*>(p + q * 8);
        }
        __syncthreads();
#pragma unroll
        for (int ks = 0; ks < 64; ks += 32) {
            bf16x8 a0 = *reinterpret_cast<const bf16x8*>(&As[w * 32 + m][ks + quad * 8]);
            bf16x8 a1 = *reinterpret_cast<const bf16x8*>(&As[w * 32 + 16 + m][ks + quad * 8]);
#pragma unroll
            for (int nt = 0; nt < 8; ++nt) {
                bf16x8 b = *reinterpret_cast<const bf16x8*>(&Bs[nt * 16 + m][ks + quad * 8]);
                acc[0][nt] = __builtin_amdgcn_mfma_f32_16x16x32_bf16(a0, b, acc[0][nt], 0, 0, 0);
                acc[1][nt] = __builtin_amdgcn_mfma_f32_16x16x32_bf16(a1, b, acc[1][nt], 0, 0, 0);
            }
        }
        __syncthreads();
        // ---- phase 2 (after iter 0): consume atomic ranks, issue scatter stores ----
        if (kc == 0) {
#pragma unroll 4
            for (int i = 0; i < 4; ++i)
                if (i < ecnt && er[i] < CAP) col[((size_t)ed[i] << 7) + er[i]] = es[i];
        }
    }
#pragma unroll
    for (int mt = 0; mt < 2; ++mt)
#pragma unroll
        for (int nt = 0; nt < 8; ++nt)
#pragma unroll
            for (int r = 0; r < 4; ++r) {
                int row = row0 + w * 32 + mt * 16 + quad * 4 + r;
                if (row < n) xhb[(size_t)row * 256 + col0 + nt * 16 + m] = (__bf16)acc[mt][nt][r];
            }
    // fused attention dots (single complete head per block -> plain store)
    {
        float asv[8], adv[8];
#pragma unroll
        for (int nt = 0; nt < 8; ++nt) {
            int c = col0 + nt * 16 + m;
            asv[nt] = att_s[c];
            adv[nt] = att_d[c];
        }
        const int h = (col0 >> 7) & 1;
#pragma unroll
        for (int mt = 0; mt < 2; ++mt)
#pragma unroll
            for (int r = 0; r < 4; ++r) {
                int row = row0 + w * 32 + mt * 16 + quad * 4 + r;
                float pa = 0.f, pb = 0.f;
#pragma unroll
                for (int nt = 0; nt < 8; ++nt) {
                    float v = acc[mt][nt][r];
                    pa += v * asv[nt];
                    pb += v * adv[nt];
                }
#pragma unroll
                for (int off = 1; off <= 8; off <<= 1) {
                    pa += __shfl_xor(pa, off);
                    pb += __shfl_xor(pb, off);
                }
                if (m == 0 && row < n) {
                    asrc[2 * row + h] = pa;
                    adst[2 * row + h] = pb;
                }
            }
    }
    // leftovers (only if e > 4*estride; not expected at e=800k, ng1=782)
    for (int g = ebase + 4 * estride; g < e; g += estride) {
        bool is64 = (*flag) != 0;
        int s = is64 ? ei[2 * g] : ei[g];
        int d = is64 ? ei[2 * (e + g)] : ei[e + g];
        int r = atomicAdd(&deg[(size_t)d * DEGS], 1);
        if (r < CAP) col[((size_t)d << 7) + r] = s;
    }
}

// ---- bf16 MFMA GEMM (layers 2/3), inline BN prep + attn dots ----
template <int K, int LC, bool BF16IN, int NT>
__global__ __launch_bounds__(256) void k_gemm(const void* __restrict__ Ain,
                                              const __bf16* __restrict__ Bt,
                                              __bf16* __restrict__ Cb, int n, int M,
                                              const float* __restrict__ bnsums,
                                              const float* __restrict__ gam,
                                              const float* __restrict__ bet,
                                              const float* __restrict__ att_s,
                                              const float* __restrict__ att_d,
                                              float* __restrict__ asrc,
                                              float* __restrict__ adst) {
    __shared__ __align__(16) __bf16 As[128][72];
    __shared__ __align__(16) __bf16 Bs[NT * 16][72];
    __shared__ float sc_lds[K], sh_lds[K];
    const int row0 = blockIdx.y * 128, col0 = blockIdx.x * (NT * 16);
    const int lane = threadIdx.x & 63, w = threadIdx.x >> 6;
    const int m = lane & 15, quad = lane >> 4;

    if (bnsums) {
        for (int c = threadIdx.x; c < K; c += 256) {
            float mean = bnsums[c] / n;
            float var = bnsums[256 + c] / n - mean * mean;
            float sc = gam[c] * rsqrtf(var + EPS_BN);
            sc_lds[c] = sc;
            sh_lds[c] = bet[c] - mean * sc;
        }
        __syncthreads();
    }

    floatx4 acc[2][NT];
#pragma unroll
    for (int i = 0; i < 2; ++i)
#pragma unroll
        for (int j = 0; j < NT; ++j) acc[i][j] = (floatx4)0.f;

    const int sr = threadIdx.x >> 1;        // A-stage: 0..127
    const int sk = (threadIdx.x & 1) * 32;

    for (int kc = 0; kc < K; kc += 64) {
        {
            int grow = row0 + sr;
            if (grow < n) {
                if (BF16IN) {
                    const __bf16* p = (const __bf16*)Ain + (size_t)grow * K + kc + sk;
#pragma unroll
                    for (int q = 0; q < 4; ++q) {
                        bf16x8 vv = *reinterpret_cast<const bf16x8*>(p + q * 8);
                        if (bnsums) {
                            int c = kc + sk + q * 8;
                            bf16x8 r;
#pragma unroll
                            for (int e2 = 0; e2 < 8; ++e2)
                                r[e2] = (__bf16)((float)vv[e2] * sc_lds[c + e2] + sh_lds[c + e2]);
                            vv = r;
                        }
                        *reinterpret_cast<bf16x8*>(&As[sr][sk + q * 8]) = vv;
                    }
                } else {
                    const float* p = (const float*)Ain + (size_t)grow * K + kc + sk;
#pragma unroll
                    for (int q = 0; q < 8; ++q) {
                        float4 v = *reinterpret_cast<const float4*>(p + q * 4);
                        bf16x4 cv = {(__bf16)v.x, (__bf16)v.y, (__bf16)v.z, (__bf16)v.w};
                        *reinterpret_cast<bf16x4*>(&As[sr][sk + q * 4]) = cv;
                    }
                }
            } else {
#pragma unroll
                for (int q = 0; q < 4; ++q)
                    *reinterpret_cast<bf16x8*>(&As[sr][sk + q * 8]) = (bf16x8)(__bf16)0.f;
            }
        }
        if (NT == 8) {
            const __bf16* p = Bt + (size_t)(col0 + sr) * K + kc + sk;
#pragma unroll
            for (int q = 0; q < 4; ++q)
                *reinterpret_cast<bf16x8*>(&Bs[sr][sk + q * 8]) =
                    *reinterpret_cast<const bf16x8*>(p + q * 8);
        } else {  // NT==4: 64 B-rows, 16 bf16 per thread
            int sr4 = threadIdx.x >> 2, sk4 = (threadIdx.x & 3) * 16;
            const __bf16* p = Bt + (size_t)(col0 + sr4) * K + kc + sk4;
            *reinterpret_cast<bf16x8*>(&Bs[sr4][sk4]) = *reinterpret_cast<const bf16x8*>(p);
            *reinterpret_cast<bf16x8*>(&Bs[sr4][sk4 + 8]) = *reinterpret_cast<const bf16x8*>(p + 8);
        }
        __syncthreads();
#pragma unroll
        for (int ks = 0; ks < 64; ks += 32) {
            bf16x8 a0 = *reinterpret_cast<const bf16x8*>(&As[w * 32 + m][ks + quad * 8]);
            bf16x8 a1 = *reinterpret_cast<const bf16x8*>(&As[w * 32 + 16 + m][ks + quad * 8]);
#pragma unroll
            for (int nt = 0; nt < NT; ++nt) {
                bf16x8 b = *reinterpret_cast<const bf16x8*>(&Bs[nt * 16 + m][ks + quad * 8]);
                acc[0][nt] = __builtin_amdgcn_mfma_f32_16x16x32_bf16(a0, b, acc[0][nt], 0, 0, 0);
                acc[1][nt] = __builtin_amdgcn_mfma_f32_16x16x32_bf16(a1, b, acc[1][nt], 0, 0, 0);
            }
        }
        __syncthreads();
    }
#pragma unroll
    for (int mt = 0; mt < 2; ++mt)
#pragma unroll
        for (int nt = 0; nt < NT; ++nt)
#pragma unroll
            for (int r = 0; r < 4; ++r) {
                int row = row0 + w * 32 + mt * 16 + quad * 4 + r;
                if (row < n) Cb[(size_t)row * M + col0 + nt * 16 + m] = (__bf16)acc[mt][nt][r];
            }
    // fused attention dots (single complete head per block -> plain store)
    {
        float asv[NT], adv[NT];
#pragma unroll
        for (int nt = 0; nt < NT; ++nt) {
            int c = col0 + nt * 16 + m;
            asv[nt] = att_s[c];
            adv[nt] = att_d[c];
        }
        const int h = (col0 >> LC) & 1;
#pragma unroll
        for (int mt = 0; mt < 2; ++mt)
#pragma unroll
            for (int r = 0; r < 4; ++r) {
                int row = row0 + w * 32 + mt * 16 + quad * 4 + r;
                float pa = 0.f, pb = 0.f;
#pragma unroll
                for (int nt = 0; nt < NT; ++nt) {
                    float v = acc[mt][nt][r];
                    pa += v * asv[nt];
                    pb += v * adv[nt];
                }
#pragma unroll
                for (int off = 1; off <= 8; off <<= 1) {
                    pa += __shfl_xor(pa, off);
                    pb += __shfl_xor(pb, off);
                }
                if (m == 0 && row < n) {
                    asrc[2 * row + h] = pa;
                    adst[2 * row + h] = pb;
                }
            }
    }
}

// ---- final linear via MFMA: out[n,64](f32) = A[n,128](f32) @ lw[128,64] + lb ----
__global__ __launch_bounds__(256) void k_lin(const float* __restrict__ A,
                                             const float* __restrict__ lw,
                                             const float* __restrict__ lb,
                                             float* __restrict__ out, int n) {
    __shared__ __align__(16) __bf16 Ahi[64][136];
    __shared__ __align__(16) __bf16 Alo[64][136];
    __shared__ __align__(16) __bf16 Bhi[64][136];
    const int row0 = blockIdx.x * 64;
    const int lane = threadIdx.x & 63, w = threadIdx.x >> 6;
    const int m = lane & 15, quad = lane >> 4;
    floatx4 acc[4];
#pragma unroll
    for (int i = 0; i < 4; ++i) acc[i] = (floatx4)0.f;
    {
        int sr = threadIdx.x >> 2, sk0 = (threadIdx.x & 3) * 32;
        int grow = row0 + sr;
#pragma unroll
        for (int q = 0; q < 8; ++q) {
            float4 v = make_float4(0.f, 0.f, 0.f, 0.f);
            if (grow < n) v = *reinterpret_cast<const float4*>(A + (size_t)grow * 128 + sk0 + q * 4);
            float vv[4] = {v.x, v.y, v.z, v.w};
#pragma unroll
            for (int i = 0; i < 4; ++i) {
                __bf16 h = (__bf16)vv[i];
                Ahi[sr][sk0 + q * 4 + i] = h;
                Alo[sr][sk0 + q * 4 + i] = (__bf16)(vv[i] - (float)h);
            }
        }
    }
    {
        int k0 = threadIdx.x >> 1, m0 = (threadIdx.x & 1) * 32;
#pragma unroll
        for (int q = 0; q < 8; ++q) {
            float4 v = *reinterpret_cast<const float4*>(lw + (size_t)k0 * 64 + m0 + q * 4);
            float vv[4] = {v.x, v.y, v.z, v.w};
#pragma unroll
            for (int i = 0; i < 4; ++i) Bhi[m0 + q * 4 + i][k0] = (__bf16)vv[i];
        }
    }
    __syncthreads();
#pragma unroll
    for (int ks = 0; ks < 128; ks += 32) {
        bf16x8 ah = *reinterpret_cast<const bf16x8*>(&Ahi[w * 16 + m][ks + quad * 8]);
        bf16x8 al = *reinterpret_cast<const bf16x8*>(&Alo[w * 16 + m][ks + quad * 8]);
#pragma unroll
        for (int nt = 0; nt < 4; ++nt) {
            bf16x8 bh = *reinterpret_cast<const bf16x8*>(&Bhi[nt * 16 + m][ks + quad * 8]);
            acc[nt] = __builtin_amdgcn_mfma_f32_16x16x32_bf16(ah, bh, acc[nt], 0, 0, 0);
            acc[nt] = __builtin_amdgcn_mfma_f32_16x16x32_bf16(al, bh, acc[nt], 0, 0, 0);
        }
    }
#pragma unroll
    for (int nt = 0; nt < 4; ++nt)
#pragma unroll
        for (int r = 0; r < 4; ++r) {
            int row = row0 + w * 16 + quad * 4 + r;
            int c = nt * 16 + m;
            if (row < n) out[(size_t)row * 64 + c] = acc[nt][r] + lb[c];
        }
}

// ---- GAT aggregation (all layers): node-per-wave depth-4 + SPLIT slots
//      (addr-early / weight-late; row gathers overlap asrc gather + exp chain) ----
template <int C, bool OUTBF16>
__global__ __launch_bounds__(256) void k_agg(const __bf16* __restrict__ xh,
                                             const float* __restrict__ asrc,
                                             const float* __restrict__ adst,
                                             const int* __restrict__ degv,
                                             const int* __restrict__ col,
                                             const float* __restrict__ bias,
                                             void* __restrict__ outv, int n) {
    constexpr int F = 2 * C;          // bf16 per row (256 or 128)
    constexpr int G = F / 8;          // lanes per edge (32 or 16)
    constexpr int NG = 64 / G;        // edges per wave-step (2 or 4)
    constexpr int GSH = (G == 32) ? 5 : 4;
    __shared__ int sA[4][80];
    __shared__ float2 sW[4][80];
    const int widx = threadIdx.x >> 6;
    const int node = blockIdx.x * 4 + widx;
    const int lane = threadIdx.x & 63;
    if (node >= n) return;
    const int t = lane & (G - 1);
    const int g = lane >> GSH;
    const bool h1 = (t * 8) >= C;
    const int selfoff = node * (F * 2);
    if (lane >= 48) { sA[widx][lane + 16] = selfoff; sW[widx][lane + 16] = make_float2(0.f, 0.f); }
    const char* xbt = (const char*)xh + t * 16;
    const int* crow = col + ((size_t)node << 7);
    const int deg = min(degv[(size_t)node * DEGS], CAP);
    const float2 adv = *reinterpret_cast<const float2*>(adst + 2 * node);
    const float2 asv = *reinterpret_cast<const float2*>(asrc + 2 * node);
    const float es0 = leaky(asv.x + adv.x), es1 = leaky(asv.y + adv.y);
    bf16x8 vself = *reinterpret_cast<const bf16x8*>(xbt + selfoff);  // early issue
    float acc[8] = {};
    float d0 = 0.f, d1 = 0.f;
    for (int base = 0; base < deg; base += 64) {
        const int cnt = min(64, deg - base);
        int s = (lane < cnt) ? crow[base + lane] : node;
        sA[widx][lane] = s * (F * 2);
        float2 av = *reinterpret_cast<const float2*>(asrc + 2 * s);
        float w0 = 0.f, w1 = 0.f;
        if (lane < cnt) {
            w0 = __expf(leaky(av.x + adv.x));
            w1 = __expf(leaky(av.y + adv.y));
            d0 += w0; d1 += w1;
        }
        sW[widx][lane] = make_float2(w0, w1);
        for (int j = g; j < cnt; j += 4 * NG) {
            int o0 = sA[widx][j], o1 = sA[widx][j + NG], o2 = sA[widx][j + 2 * NG], o3 = sA[widx][j + 3 * NG];
            bf16x8 v0 = *reinterpret_cast<const bf16x8*>(xbt + o0);
            bf16x8 v1 = *reinterpret_cast<const bf16x8*>(xbt + o1);
            bf16x8 v2 = *reinterpret_cast<const bf16x8*>(xbt + o2);
            bf16x8 v3 = *reinterpret_cast<const bf16x8*>(xbt + o3);
            float2 x0 = sW[widx][j], x1 = sW[widx][j + NG], x2 = sW[widx][j + 2 * NG], x3 = sW[widx][j + 3 * NG];
            float w0 = h1 ? x0.y : x0.x;
            float w1 = h1 ? x1.y : x1.x;
            float w2 = h1 ? x2.y : x2.x;
            float w3 = h1 ? x3.y : x3.x;
#pragma unroll
            for (int q = 0; q < 8; ++q)
                acc[q] += w0 * (float)v0[q] + w1 * (float)v1[q] +
                          w2 * (float)v2[q] + w3 * (float)v3[q];
        }
    }
#pragma unroll
    for (int off = 1; off <= 32; off <<= 1) {
        d0 += __shfl_xor(d0, off);
        d1 += __shfl_xor(d1, off);
    }
#pragma unroll
    for (int q = 0; q < 8; ++q) {
#pragma unroll
        for (int off = G; off < 64; off <<= 1) acc[q] += __shfl_xor(acc[q], off);
    }
    float exs0 = __expf(es0), exs1 = __expf(es1);
    d0 += exs0; d1 += exs1;
    {
        float ws = h1 ? exs1 : exs0;
#pragma unroll
        for (int q = 0; q < 8; ++q) acc[q] += ws * (float)vself[q];
    }
    float inv = 1.0f / ((h1 ? d1 : d0) + EPS_SM);
    float o[8];
#pragma unroll
    for (int q = 0; q < 8; ++q) o[q] = fmaxf(acc[q] * inv + bias[t * 8 + q], 0.f);
    if (g == 0) {
        if constexpr (OUTBF16) {
            __bf16* po = (__bf16*)outv + (size_t)node * F + t * 8;
            bf16x8 st;
#pragma unroll
            for (int q = 0; q < 8; ++q) st[q] = (__bf16)o[q];
            *reinterpret_cast<bf16x8*>(po) = st;
        } else {
            float* po = (float*)outv + (size_t)node * F + t * 8;
            *reinterpret_cast<float4*>(po) = make_float4(o[0], o[1], o[2], o[3]);
            *reinterpret_cast<float4*>(po + 4) = make_float4(o[4], o[5], o[6], o[7]);
        }
    }
}

// ---------------- BatchNorm stats (256 blocks = low contention) ----
template <typename T>
__global__ void k_bn_stats(const T* __restrict__ x, float* __restrict__ sums,
                           float* __restrict__ sqs, int n, int f) {
    int c = threadIdx.x;
    float s = 0.f, q = 0.f;
    for (int r = blockIdx.x; r < n; r += gridDim.x) {
        float v = (float)x[(size_t)r * f + c];
        s += v; q += v * v;
    }
    atomicAdd(&sums[c], s);
    atomicAdd(&sqs[c], q);
}

// ---------------- launch ----------------
extern "C" void kernel_launch(void* const* d_in, const int* in_sizes, int n_in,
                              void* d_out, int out_size, void* d_ws, size_t ws_size,
                              hipStream_t stream) {
    const float* x   = (const float*)d_in[0];
    const int*   ei  = (const int*)d_in[1];
    const float* W1  = (const float*)d_in[2];
    const float* as1 = (const float*)d_in[3];
    const float* ad1 = (const float*)d_in[4];
    const float* b1  = (const float*)d_in[5];
    const float* g1  = (const float*)d_in[6];
    const float* be1 = (const float*)d_in[7];
    const float* W2  = (const float*)d_in[8];
    const float* as2 = (const float*)d_in[9];
    const float* ad2 = (const float*)d_in[10];
    const float* b2  = (const float*)d_in[11];
    const float* g2  = (const float*)d_in[12];
    const float* be2 = (const float*)d_in[13];
    const float* W3  = (const float*)d_in[14];
    const float* as3 = (const float*)d_in[15];
    const float* ad3 = (const float*)d_in[16];
    const float* b3  = (const float*)d_in[17];
    const float* lw  = (const float*)d_in[18];
    const float* lb  = (const float*)d_in[19];
    float* outp = (float*)d_out;

    const int n = in_sizes[0] / 128;  // 50000
    const int e = in_sizes[1] / 2;    // 800000

    char* w = (char*)d_ws;
    size_t off = 0;
    auto alloc = [&](size_t bytes) -> void* {
        void* p = w + off;
        off += (bytes + 255) & ~(size_t)255;
        return p;
    };
    __bf16* xhb = (__bf16*)alloc((size_t)n * 256 * 2);  // xh1; reused as xh2/xh3
    __bf16* h1b = (__bf16*)alloc((size_t)n * 256 * 2);
    __bf16* h2b = (__bf16*)alloc((size_t)n * 128 * 2);
    float*  h3f = (float*)alloc((size_t)n * 128 * 4);
    int* colb   = (int*)alloc((size_t)n * CAP * 4);  // padded adjacency (25.6 MB)
    __bf16* Wb1 = (__bf16*)alloc(256 * 128 * 2);
    __bf16* Wb2 = (__bf16*)alloc(128 * 256 * 2);
    __bf16* Wb3 = (__bf16*)alloc(128 * 128 * 2);
    int* flag   = (int*)alloc(256);
    float* as1p = (float*)alloc((size_t)n * 2 * 4);
    float* ad1p = (float*)alloc((size_t)n * 2 * 4);
    float* as2p = (float*)alloc((size_t)n * 2 * 4);
    float* ad2p = (float*)alloc((size_t)n * 2 * 4);
    float* as3p = (float*)alloc((size_t)n * 2 * 4);
    float* ad3p = (float*)alloc((size_t)n * 2 * 4);
    // ---- contiguous zero block ----
    char* zb_begin = (char*)(w + off);
    int* deg    = (int*)alloc((size_t)n * DEGS * 4);  // line-padded counters (3.2 MB)
    float* bn1  = (float*)alloc(512 * 4);
    float* bn2  = (float*)alloc(512 * 4);
    char* zb_end = (char*)(w + off);
    const int zwords = (int)((zb_end - zb_begin) / 4);

    // init: detect (block 0) + zero (blocks 1..128) + weight convert (blocks 129..448)
    k_init<<<449, 256, 0, stream>>>(ei, flag, (int*)zb_begin, zwords, e,
                                    W1, Wb1, W2, Wb2, W3, Wb3);

    const int nrow = (n + 127) / 128;
    const int ng1 = 2 * nrow;                 // 782 gemm1 blocks; each also owns ~1024 edges
    k_hist_gemm1<<<ng1, 256, 0, stream>>>(ei, flag, deg, colb, e, ng1,
                                          x, Wb1, xhb, n, as1, ad1, as1p, ad1p);

    const int nwb = (n + 3) / 4;

    // ---- layer 1: aggregation (gemm1 + CSR build done in one overlapped kernel) ----
    k_agg<128, true><<<nwb, 256, 0, stream>>>(xhb, as1p, ad1p, deg, colb, b1, h1b, n);
    k_bn_stats<__bf16><<<256, 256, 0, stream>>>(h1b, bn1, bn1 + 256, n, 256);

    // ---- layer 2: 256 -> 2x64 (BN1 inline in GEMM prologue; 64-col tiles) ----
    k_gemm<256, 6, true, 4><<<dim3(2, nrow), 256, 0, stream>>>(
        h1b, Wb2, xhb, n, 128, bn1, g1, be1, as2, ad2, as2p, ad2p);
    k_agg<64, true><<<nwb, 256, 0, stream>>>(xhb, as2p, ad2p, deg, colb, b2, h2b, n);
    k_bn_stats<__bf16><<<256, 128, 0, stream>>>(h2b, bn2, bn2 + 256, n, 128);

    // ---- layer 3: 128 -> 2x64 (BN2 inline) ----
    k_gemm<128, 6, true, 4><<<dim3(2, nrow), 256, 0, stream>>>(
        h2b, Wb3, xhb, n, 128, bn2, g2, be2, as3, ad3, as3p, ad3p);
    k_agg<64, false><<<nwb, 256, 0, stream>>>(xhb, as3p, ad3p, deg, colb, b3, h3f, n);

    // ---- final linear ----
    k_lin<<<(n + 63) / 64, 256, 0, stream>>>(h3f, lw, lb, outp, n);
}

// Round 10
// 449.971 us; speedup vs baseline: 1.0319x; 1.0125x over previous
//
#include <hip/hip_runtime.h>
#include <hip/hip_bf16.h>

#define NEG_SLOPE 0.2f
#define EPS_BN 1e-5f
#define EPS_SM 1e-16f
#define CAP 128   // padded adjacency row capacity (Poisson(17): P(deg>128) ~ 0; clamped anyway)
#define DEGS 16   // deg counter stride (ints): one counter per 64B line

typedef __bf16 bf16x8 __attribute__((ext_vector_type(8)));
typedef __bf16 bf16x4 __attribute__((ext_vector_type(4)));
typedef float floatx4 __attribute__((ext_vector_type(4)));

__device__ __forceinline__ float leaky(float x) { return x > 0.f ? x : NEG_SLOPE * x; }

// ---- init: block 0 = edge dtype detect; blocks 1..128 = zero; block 129 = wsd ----
// wsd[j][k], j in {src_h0, src_h1, dst_h0, dst_h1}: wsd_s[h][k] = sum_c W1[k, h*128+c]*att[h,c]
__global__ void k_init(const int* __restrict__ ei, int* __restrict__ flag,
                       int* __restrict__ zbase, int zwords, int e,
                       const float* __restrict__ W1, const float* __restrict__ as1,
                       const float* __restrict__ ad1, float* __restrict__ wsd) {
    if (blockIdx.x == 0) {
        __shared__ int cnt_s[256];
        int i = threadIdx.x;  // pairs 0..255
        int nz = (2 * i + 1 < 2 * e && ei[2 * i + 1] != 0) ? 1 : 0;
        cnt_s[i] = nz;
        __syncthreads();
        for (int off = 128; off > 0; off >>= 1) {
            if (i < off) cnt_s[i] += cnt_s[i + off];
            __syncthreads();
        }
        if (i == 0) *flag = (cnt_s[0] < 128) ? 1 : 0;  // 1 => int64 layout
        return;
    }
    if (blockIdx.x == 129) {
        int k = threadIdx.x;
        if (k < 128) {
            const float* wr = W1 + (size_t)k * 256;
            float s0 = 0.f, s1 = 0.f, d0 = 0.f, d1 = 0.f;
            for (int c = 0; c < 128; ++c) {
                float w0 = wr[c], w1 = wr[128 + c];
                s0 += w0 * as1[c];
                s1 += w1 * as1[128 + c];
                d0 += w0 * ad1[c];
                d1 += w1 * ad1[128 + c];
            }
            wsd[k] = s0; wsd[128 + k] = s1; wsd[256 + k] = d0; wsd[384 + k] = d1;
        }
        return;
    }
    int g = (blockIdx.x - 1) * 256 + threadIdx.x;
    const int stride = 128 * 256;
    for (int k = g; k < zwords; k += stride) zbase[k] = 0;
}

// ---- hist + DIRECT scatter + weight convert (incl. lwb) + fused layer-1 pre-pass ----
// pre-pass: xb = bf16(x); attention dots directly from x via wsd (overlaps with hist)
__global__ void k_hist_wconv(const int* __restrict__ ei, const int* __restrict__ flag,
                             int* __restrict__ deg, int* __restrict__ col, int e, int ebase,
                             const float* __restrict__ W1, __bf16* __restrict__ Wb1,
                             const float* __restrict__ W2, __bf16* __restrict__ Wb2,
                             const float* __restrict__ W3, __bf16* __restrict__ Wb3,
                             const float* __restrict__ lw, __bf16* __restrict__ lwb,
                             const float* __restrict__ x, const float* __restrict__ wsd,
                             __bf16* __restrict__ xb, float* __restrict__ asp,
                             float* __restrict__ adp, int n) {
    int g = threadIdx.x + blockIdx.x * blockDim.x;
    if (g < e) {
        bool is64 = (*flag) != 0;
        int s = is64 ? ei[2 * g] : ei[g];
        int d = is64 ? ei[2 * (e + g)] : ei[e + g];
        int r = atomicAdd(&deg[(size_t)d * DEGS], 1);   // padded counter: 1 per 64B line
        if (r < CAP) col[((size_t)d << 7) + r] = s;
        return;
    }
    int idx = g - ebase;
    if (idx < 0) return;
    if (idx < 90112) {
        if (idx < 32768) {                      // W1: K=128, M=256
            int mm = idx >> 7, kk = idx & 127;
            Wb1[idx] = (__bf16)W1[(size_t)kk * 256 + mm];
        } else if (idx < 65536) {               // W2: K=256, M=128
            int i2 = idx - 32768;
            int mm = i2 >> 8, kk = i2 & 255;
            Wb2[i2] = (__bf16)W2[(size_t)kk * 128 + mm];
        } else if (idx < 81920) {               // W3: K=128, M=128
            int i3 = idx - 65536;
            int mm = i3 >> 7, kk = i3 & 127;
            Wb3[i3] = (__bf16)W3[(size_t)kk * 128 + mm];
        } else {                                // lw: [128][64] k-major, straight copy
            int i4 = idx - 81920;
            lwb[i4] = (__bf16)lw[i4];
        }
        return;
    }
    // ---- pre-pass region (whole blocks: e%256==0, 90112%256==0) ----
    int p = idx - 90112;
    __shared__ float ws[4][128];
    for (int i = threadIdx.x; i < 512; i += 256) ws[i >> 7][i & 127] = wsd[i];
    __syncthreads();
    const int lane = threadIdx.x & 63, widx = threadIdx.x >> 6;
    const int sub = lane & 7;
    const int node = (p >> 8) * 32 + widx * 8 + (lane >> 3);
    if (node >= n) return;
    const int c0 = sub * 16;
    const float* xp = x + (size_t)node * 128 + c0;
    float xv[16];
#pragma unroll
    for (int q = 0; q < 4; ++q) {
        float4 v = *reinterpret_cast<const float4*>(xp + q * 4);
        xv[q * 4 + 0] = v.x; xv[q * 4 + 1] = v.y; xv[q * 4 + 2] = v.z; xv[q * 4 + 3] = v.w;
    }
    float s0 = 0.f, s1 = 0.f, d0 = 0.f, d1 = 0.f;
#pragma unroll
    for (int i = 0; i < 16; ++i) {
        float xi = xv[i];
        int c = c0 + i;
        s0 += xi * ws[0][c]; s1 += xi * ws[1][c];
        d0 += xi * ws[2][c]; d1 += xi * ws[3][c];
    }
#pragma unroll
    for (int off = 1; off <= 4; off <<= 1) {
        s0 += __shfl_xor(s0, off); s1 += __shfl_xor(s1, off);
        d0 += __shfl_xor(d0, off); d1 += __shfl_xor(d1, off);
    }
    bf16x8 b0, b1;
#pragma unroll
    for (int i = 0; i < 8; ++i) { b0[i] = (__bf16)xv[i]; b1[i] = (__bf16)xv[8 + i]; }
    __bf16* po = xb + (size_t)node * 128 + c0;
    *reinterpret_cast<bf16x8*>(po) = b0;
    *reinterpret_cast<bf16x8*>(po + 8) = b1;
    if (sub == 0) {
        *reinterpret_cast<float2*>(asp + 2 * node) = make_float2(s0, s1);
        *reinterpret_cast<float2*>(adp + 2 * node) = make_float2(d0, d1);
    }
}

// ---- layer-1 aggregation in INPUT space, SPLIT slots ----
__global__ __launch_bounds__(256) void k_agg_in(const __bf16* __restrict__ xb,
                                                const float* __restrict__ asrc,
                                                const float* __restrict__ adst,
                                                const int* __restrict__ degv,
                                                const int* __restrict__ col,
                                                __bf16* __restrict__ aggv, int n) {
    __shared__ int sA[4][80];
    __shared__ float2 sW[4][80];
    const int widx = threadIdx.x >> 6;
    const int node = blockIdx.x * 4 + widx;
    const int lane = threadIdx.x & 63;
    if (node >= n) return;
    const int t = lane & 15;          // 16 lanes per edge, 8 ch each
    const int g = lane >> 4;          // 4 edges per wave-instr
    const int selfoff = node * 256;
    if (lane >= 48) { sA[widx][lane + 16] = selfoff; sW[widx][lane + 16] = make_float2(0.f, 0.f); }
    const char* xbt = (const char*)xb + t * 16;
    const int* crow = col + ((size_t)node << 7);
    const int deg = min(degv[(size_t)node * DEGS], CAP);
    const float2 adv = *reinterpret_cast<const float2*>(adst + 2 * node);
    const float2 asv = *reinterpret_cast<const float2*>(asrc + 2 * node);
    const float es0 = leaky(asv.x + adv.x), es1 = leaky(asv.y + adv.y);
    bf16x8 vself = *reinterpret_cast<const bf16x8*>(xbt + selfoff);  // early issue
    float a0[8] = {}, a1[8] = {};
    float d0 = 0.f, d1 = 0.f;
    for (int base = 0; base < deg; base += 64) {
        const int cnt = min(64, deg - base);
        int s = (lane < cnt) ? crow[base + lane] : node;
        sA[widx][lane] = s * 256;     // address available BEFORE exp chain completes
        float2 av = *reinterpret_cast<const float2*>(asrc + 2 * s);
        float w0 = 0.f, w1 = 0.f;
        if (lane < cnt) {
            w0 = __expf(leaky(av.x + adv.x));
            w1 = __expf(leaky(av.y + adv.y));
            d0 += w0; d1 += w1;
        }
        sW[widx][lane] = make_float2(w0, w1);
        for (int j = g; j < cnt; j += 16) {
            int o0 = sA[widx][j], o1 = sA[widx][j + 4], o2 = sA[widx][j + 8], o3 = sA[widx][j + 12];
            bf16x8 v0 = *reinterpret_cast<const bf16x8*>(xbt + o0);
            bf16x8 v1 = *reinterpret_cast<const bf16x8*>(xbt + o1);
            bf16x8 v2 = *reinterpret_cast<const bf16x8*>(xbt + o2);
            bf16x8 v3 = *reinterpret_cast<const bf16x8*>(xbt + o3);
            float2 x0 = sW[widx][j], x1 = sW[widx][j + 4], x2 = sW[widx][j + 8], x3 = sW[widx][j + 12];
#pragma unroll
            for (int q = 0; q < 8; ++q) {
                float f0 = (float)v0[q], f1 = (float)v1[q], f2 = (float)v2[q], f3 = (float)v3[q];
                a0[q] += x0.x * f0 + x1.x * f1 + x2.x * f2 + x3.x * f3;
                a1[q] += x0.y * f0 + x1.y * f1 + x2.y * f2 + x3.y * f3;
            }
        }
    }
#pragma unroll
    for (int off = 1; off <= 32; off <<= 1) {
        d0 += __shfl_xor(d0, off);
        d1 += __shfl_xor(d1, off);
    }
#pragma unroll
    for (int q = 0; q < 8; ++q) {
#pragma unroll
        for (int off = 16; off < 64; off <<= 1) {
            a0[q] += __shfl_xor(a0[q], off);
            a1[q] += __shfl_xor(a1[q], off);
        }
    }
    float exs0 = __expf(es0), exs1 = __expf(es1);
    d0 += exs0; d1 += exs1;
#pragma unroll
    for (int q = 0; q < 8; ++q) {
        a0[q] += exs0 * (float)vself[q];
        a1[q] += exs1 * (float)vself[q];
    }
    float i0 = 1.0f / (d0 + EPS_SM), i1 = 1.0f / (d1 + EPS_SM);
    if (g == 0) {
        bf16x8 st0, st1;
#pragma unroll
        for (int q = 0; q < 8; ++q) {
            st0[q] = (__bf16)(a0[q] * i0);
            st1[q] = (__bf16)(a1[q] * i1);
        }
        __bf16* po = aggv + (size_t)node * 256 + t * 8;
        *reinterpret_cast<bf16x8*>(po) = st0;
        *reinterpret_cast<bf16x8*>(po + 128) = st1;
    }
}

// ---- layer-1 post-GEMM with fused BN1 stats ----
__global__ __launch_bounds__(256) void k_gemm_ar(const __bf16* __restrict__ A,
                                                 const __bf16* __restrict__ Bt,
                                                 const float* __restrict__ bias,
                                                 __bf16* __restrict__ Cb,
                                                 float* __restrict__ bnsums, int n) {
    __shared__ __align__(16) __bf16 As[128][72];
    __shared__ __align__(16) __bf16 Bs[128][72];
    const int row0 = blockIdx.y * 128, col0 = blockIdx.x * 128;
    const int h = col0 >> 7;
    const int lane = threadIdx.x & 63, w = threadIdx.x >> 6;
    const int m = lane & 15, quad = lane >> 4;
    floatx4 acc[2][8];
#pragma unroll
    for (int i = 0; i < 2; ++i)
#pragma unroll
        for (int j = 0; j < 8; ++j) acc[i][j] = (floatx4)0.f;
    const int sr = threadIdx.x >> 1;
    const int sk = (threadIdx.x & 1) * 32;
    for (int kc = 0; kc < 128; kc += 64) {
        {
            int grow = row0 + sr;
            if (grow < n) {
                const __bf16* p = A + (size_t)grow * 256 + h * 128 + kc + sk;
#pragma unroll
                for (int q = 0; q < 4; ++q)
                    *reinterpret_cast<bf16x8*>(&As[sr][sk + q * 8]) =
                        *reinterpret_cast<const bf16x8*>(p + q * 8);
            } else {
#pragma unroll
                for (int q = 0; q < 4; ++q)
                    *reinterpret_cast<bf16x8*>(&As[sr][sk + q * 8]) = (bf16x8)(__bf16)0.f;
            }
        }
        {
            const __bf16* p = Bt + (size_t)(col0 + sr) * 128 + kc + sk;
#pragma unroll
            for (int q = 0; q < 4; ++q)
                *reinterpret_cast<bf16x8*>(&Bs[sr][sk + q * 8]) =
                    *reinterpret_cast<const bf16x8*>(p + q * 8);
        }
        __syncthreads();
#pragma unroll
        for (int ks = 0; ks < 64; ks += 32) {
            bf16x8 a0 = *reinterpret_cast<const bf16x8*>(&As[w * 32 + m][ks + quad * 8]);
            bf16x8 a1 = *reinterpret_cast<const bf16x8*>(&As[w * 32 + 16 + m][ks + quad * 8]);
#pragma unroll
            for (int nt = 0; nt < 8; ++nt) {
                bf16x8 b = *reinterpret_cast<const bf16x8*>(&Bs[nt * 16 + m][ks + quad * 8]);
                acc[0][nt] = __builtin_amdgcn_mfma_f32_16x16x32_bf16(a0, b, acc[0][nt], 0, 0, 0);
                acc[1][nt] = __builtin_amdgcn_mfma_f32_16x16x32_bf16(a1, b, acc[1][nt], 0, 0, 0);
            }
        }
        __syncthreads();
    }
    // epilogue: store relu + accumulate BN stats (As free after final k-loop sync)
    float* redS = reinterpret_cast<float*>(As);      // [4][128]
    float* redQ = redS + 512;                        // [4][128]
#pragma unroll
    for (int nt = 0; nt < 8; ++nt) {
        float bsv = bias[col0 + nt * 16 + m];
        float ssum = 0.f, ssq = 0.f;
#pragma unroll
        for (int mt = 0; mt < 2; ++mt)
#pragma unroll
            for (int r = 0; r < 4; ++r) {
                int row = row0 + w * 32 + mt * 16 + quad * 4 + r;
                float v = 0.f;
                if (row < n) {
                    v = fmaxf(acc[mt][nt][r] + bsv, 0.f);
                    Cb[(size_t)row * 256 + col0 + nt * 16 + m] = (__bf16)v;
                }
                ssum += v; ssq += v * v;
            }
        ssum += __shfl_xor(ssum, 16); ssum += __shfl_xor(ssum, 32);
        ssq  += __shfl_xor(ssq, 16);  ssq  += __shfl_xor(ssq, 32);
        if (quad == 0) {
            redS[w * 128 + nt * 16 + m] = ssum;
            redQ[w * 128 + nt * 16 + m] = ssq;
        }
    }
    __syncthreads();
    if (threadIdx.x < 128) {
        int c = threadIdx.x;
        float s = redS[c] + redS[128 + c] + redS[256 + c] + redS[384 + c];
        float q2 = redQ[c] + redQ[128 + c] + redQ[256 + c] + redQ[384 + c];
        atomicAdd(&bnsums[col0 + c], s);
        atomicAdd(&bnsums[256 + col0 + c], q2);
    }
}

// ---- bf16 MFMA GEMM (layers 2/3), inline BN prep + attn dots ----
template <int K, int LC, bool BF16IN, int NT>
__global__ __launch_bounds__(256) void k_gemm(const void* __restrict__ Ain,
                                              const __bf16* __restrict__ Bt,
                                              __bf16* __restrict__ Cb, int n, int M,
                                              const float* __restrict__ bnsums,
                                              const float* __restrict__ gam,
                                              const float* __restrict__ bet,
                                              const float* __restrict__ att_s,
                                              const float* __restrict__ att_d,
                                              float* __restrict__ asrc,
                                              float* __restrict__ adst) {
    __shared__ __align__(16) __bf16 As[128][72];
    __shared__ __align__(16) __bf16 Bs[NT * 16][72];
    __shared__ float sc_lds[K], sh_lds[K];
    const int row0 = blockIdx.y * 128, col0 = blockIdx.x * (NT * 16);
    const int lane = threadIdx.x & 63, w = threadIdx.x >> 6;
    const int m = lane & 15, quad = lane >> 4;

    if (bnsums) {
        for (int c = threadIdx.x; c < K; c += 256) {
            float mean = bnsums[c] / n;
            float var = bnsums[256 + c] / n - mean * mean;
            float sc = gam[c] * rsqrtf(var + EPS_BN);
            sc_lds[c] = sc;
            sh_lds[c] = bet[c] - mean * sc;
        }
        __syncthreads();
    }

    floatx4 acc[2][NT];
#pragma unroll
    for (int i = 0; i < 2; ++i)
#pragma unroll
        for (int j = 0; j < NT; ++j) acc[i][j] = (floatx4)0.f;

    const int sr = threadIdx.x >> 1;        // A-stage: 0..127
    const int sk = (threadIdx.x & 1) * 32;

    for (int kc = 0; kc < K; kc += 64) {
        {
            int grow = row0 + sr;
            if (grow < n) {
                if (BF16IN) {
                    const __bf16* p = (const __bf16*)Ain + (size_t)grow * K + kc + sk;
#pragma unroll
                    for (int q = 0; q < 4; ++q) {
                        bf16x8 vv = *reinterpret_cast<const bf16x8*>(p + q * 8);
                        if (bnsums) {
                            int c = kc + sk + q * 8;
                            bf16x8 r;
#pragma unroll
                            for (int e2 = 0; e2 < 8; ++e2)
                                r[e2] = (__bf16)((float)vv[e2] * sc_lds[c + e2] + sh_lds[c + e2]);
                            vv = r;
                        }
                        *reinterpret_cast<bf16x8*>(&As[sr][sk + q * 8]) = vv;
                    }
                } else {
                    const float* p = (const float*)Ain + (size_t)grow * K + kc + sk;
#pragma unroll
                    for (int q = 0; q < 8; ++q) {
                        float4 v = *reinterpret_cast<const float4*>(p + q * 4);
                        bf16x4 cv = {(__bf16)v.x, (__bf16)v.y, (__bf16)v.z, (__bf16)v.w};
                        *reinterpret_cast<bf16x4*>(&As[sr][sk + q * 4]) = cv;
                    }
                }
            } else {
#pragma unroll
                for (int q = 0; q < 4; ++q)
                    *reinterpret_cast<bf16x8*>(&As[sr][sk + q * 8]) = (bf16x8)(__bf16)0.f;
            }
        }
        if (NT == 8) {
            const __bf16* p = Bt + (size_t)(col0 + sr) * K + kc + sk;
#pragma unroll
            for (int q = 0; q < 4; ++q)
                *reinterpret_cast<bf16x8*>(&Bs[sr][sk + q * 8]) =
                    *reinterpret_cast<const bf16x8*>(p + q * 8);
        } else {  // NT==4: 64 B-rows, 16 bf16 per thread
            int sr4 = threadIdx.x >> 2, sk4 = (threadIdx.x & 3) * 16;
            const __bf16* p = Bt + (size_t)(col0 + sr4) * K + kc + sk4;
            *reinterpret_cast<bf16x8*>(&Bs[sr4][sk4]) = *reinterpret_cast<const bf16x8*>(p);
            *reinterpret_cast<bf16x8*>(&Bs[sr4][sk4 + 8]) = *reinterpret_cast<const bf16x8*>(p + 8);
        }
        __syncthreads();
#pragma unroll
        for (int ks = 0; ks < 64; ks += 32) {
            bf16x8 a0 = *reinterpret_cast<const bf16x8*>(&As[w * 32 + m][ks + quad * 8]);
            bf16x8 a1 = *reinterpret_cast<const bf16x8*>(&As[w * 32 + 16 + m][ks + quad * 8]);
#pragma unroll
            for (int nt = 0; nt < NT; ++nt) {
                bf16x8 b = *reinterpret_cast<const bf16x8*>(&Bs[nt * 16 + m][ks + quad * 8]);
                acc[0][nt] = __builtin_amdgcn_mfma_f32_16x16x32_bf16(a0, b, acc[0][nt], 0, 0, 0);
                acc[1][nt] = __builtin_amdgcn_mfma_f32_16x16x32_bf16(a1, b, acc[1][nt], 0, 0, 0);
            }
        }
        __syncthreads();
    }
#pragma unroll
    for (int mt = 0; mt < 2; ++mt)
#pragma unroll
        for (int nt = 0; nt < NT; ++nt)
#pragma unroll
            for (int r = 0; r < 4; ++r) {
                int row = row0 + w * 32 + mt * 16 + quad * 4 + r;
                if (row < n) Cb[(size_t)row * M + col0 + nt * 16 + m] = (__bf16)acc[mt][nt][r];
            }
    // fused attention dots (single complete head per block -> plain store)
    {
        float asv[NT], adv[NT];
#pragma unroll
        for (int nt = 0; nt < NT; ++nt) {
            int c = col0 + nt * 16 + m;
            asv[nt] = att_s[c];
            adv[nt] = att_d[c];
        }
        const int h = (col0 >> LC) & 1;
#pragma unroll
        for (int mt = 0; mt < 2; ++mt)
#pragma unroll
            for (int r = 0; r < 4; ++r) {
                int row = row0 + w * 32 + mt * 16 + quad * 4 + r;
                float pa = 0.f, pb = 0.f;
#pragma unroll
                for (int nt = 0; nt < NT; ++nt) {
                    float v = acc[mt][nt][r];
                    pa += v * asv[nt];
                    pb += v * adv[nt];
                }
#pragma unroll
                for (int off = 1; off <= 8; off <<= 1) {
                    pa += __shfl_xor(pa, off);
                    pb += __shfl_xor(pb, off);
                }
                if (m == 0 && row < n) {
                    asrc[2 * row + h] = pa;
                    adst[2 * row + h] = pb;
                }
            }
    }
}

// ---- GAT aggregation (layer 2): node-per-wave depth-4 + SPLIT slots ----
template <int C, bool OUTBF16>
__global__ __launch_bounds__(256) void k_agg(const __bf16* __restrict__ xh,
                                             const float* __restrict__ asrc,
                                             const float* __restrict__ adst,
                                             const int* __restrict__ degv,
                                             const int* __restrict__ col,
                                             const float* __restrict__ bias,
                                             void* __restrict__ outv, int n) {
    constexpr int F = 2 * C;          // bf16 per row (128)
    constexpr int G = F / 8;          // lanes per edge (16)
    constexpr int NG = 64 / G;        // edges per wave-step (4)
    constexpr int GSH = (G == 32) ? 5 : 4;
    __shared__ int sA[4][80];
    __shared__ float2 sW[4][80];
    const int widx = threadIdx.x >> 6;
    const int node = blockIdx.x * 4 + widx;
    const int lane = threadIdx.x & 63;
    if (node >= n) return;
    const int t = lane & (G - 1);
    const int g = lane >> GSH;
    const bool h1 = (t * 8) >= C;
    const int selfoff = node * (F * 2);
    if (lane >= 48) { sA[widx][lane + 16] = selfoff; sW[widx][lane + 16] = make_float2(0.f, 0.f); }
    const char* xbt = (const char*)xh + t * 16;
    const int* crow = col + ((size_t)node << 7);
    const int deg = min(degv[(size_t)node * DEGS], CAP);
    const float2 adv = *reinterpret_cast<const float2*>(adst + 2 * node);
    const float2 asv = *reinterpret_cast<const float2*>(asrc + 2 * node);
    const float es0 = leaky(asv.x + adv.x), es1 = leaky(asv.y + adv.y);
    bf16x8 vself = *reinterpret_cast<const bf16x8*>(xbt + selfoff);  // early issue
    float acc[8] = {};
    float d0 = 0.f, d1 = 0.f;
    for (int base = 0; base < deg; base += 64) {
        const int cnt = min(64, deg - base);
        int s = (lane < cnt) ? crow[base + lane] : node;
        sA[widx][lane] = s * (F * 2);
        float2 av = *reinterpret_cast<const float2*>(asrc + 2 * s);
        float w0 = 0.f, w1 = 0.f;
        if (lane < cnt) {
            w0 = __expf(leaky(av.x + adv.x));
            w1 = __expf(leaky(av.y + adv.y));
            d0 += w0; d1 += w1;
        }
        sW[widx][lane] = make_float2(w0, w1);
        for (int j = g; j < cnt; j += 4 * NG) {
            int o0 = sA[widx][j], o1 = sA[widx][j + NG], o2 = sA[widx][j + 2 * NG], o3 = sA[widx][j + 3 * NG];
            bf16x8 v0 = *reinterpret_cast<const bf16x8*>(xbt + o0);
            bf16x8 v1 = *reinterpret_cast<const bf16x8*>(xbt + o1);
            bf16x8 v2 = *reinterpret_cast<const bf16x8*>(xbt + o2);
            bf16x8 v3 = *reinterpret_cast<const bf16x8*>(xbt + o3);
            float2 x0 = sW[widx][j], x1 = sW[widx][j + NG], x2 = sW[widx][j + 2 * NG], x3 = sW[widx][j + 3 * NG];
            float w0 = h1 ? x0.y : x0.x;
            float w1 = h1 ? x1.y : x1.x;
            float w2 = h1 ? x2.y : x2.x;
            float w3 = h1 ? x3.y : x3.x;
#pragma unroll
            for (int q = 0; q < 8; ++q)
                acc[q] += w0 * (float)v0[q] + w1 * (float)v1[q] +
                          w2 * (float)v2[q] + w3 * (float)v3[q];
        }
    }
#pragma unroll
    for (int off = 1; off <= 32; off <<= 1) {
        d0 += __shfl_xor(d0, off);
        d1 += __shfl_xor(d1, off);
    }
#pragma unroll
    for (int q = 0; q < 8; ++q) {
#pragma unroll
        for (int off = G; off < 64; off <<= 1) acc[q] += __shfl_xor(acc[q], off);
    }
    float exs0 = __expf(es0), exs1 = __expf(es1);
    d0 += exs0; d1 += exs1;
    {
        float ws = h1 ? exs1 : exs0;
#pragma unroll
        for (int q = 0; q < 8; ++q) acc[q] += ws * (float)vself[q];
    }
    float inv = 1.0f / ((h1 ? d1 : d0) + EPS_SM);
    float o[8];
#pragma unroll
    for (int q = 0; q < 8; ++q) o[q] = fmaxf(acc[q] * inv + bias[t * 8 + q], 0.f);
    if (g == 0) {
        if constexpr (OUTBF16) {
            __bf16* po = (__bf16*)outv + (size_t)node * F + t * 8;
            bf16x8 st;
#pragma unroll
            for (int q = 0; q < 8; ++q) st[q] = (__bf16)o[q];
            *reinterpret_cast<bf16x8*>(po) = st;
        } else {
            float* po = (float*)outv + (size_t)node * F + t * 8;
            *reinterpret_cast<float4*>(po) = make_float4(o[0], o[1], o[2], o[3]);
            *reinterpret_cast<float4*>(po + 4) = make_float4(o[4], o[5], o[6], o[7]);
        }
    }
}

// ---- layer-3 aggregation + FUSED final linear: per-wave row h3 stays on-chip;
//      out[node, c] = lb[c] + sum_k h3[k] * lw[k][c] computed from LDS (bf16 lw,
//      matching k_lin's old B precision; dot in f32 = better than old hi/lo A).
__global__ __launch_bounds__(256) void k_agg_lin(const __bf16* __restrict__ xh,
                                                 const float* __restrict__ asrc,
                                                 const float* __restrict__ adst,
                                                 const int* __restrict__ degv,
                                                 const int* __restrict__ col,
                                                 const float* __restrict__ bias,
                                                 const __bf16* __restrict__ lwb,
                                                 const float* __restrict__ lb,
                                                 float* __restrict__ out, int n) {
    constexpr int C = 64, F = 128, G = 16;
    __shared__ int sA[4][80];
    __shared__ float2 sW[4][80];
    __shared__ __align__(16) __bf16 lwL[128 * 64];   // [k][c] bf16, 16KB
    __shared__ float orow[4][128];
    // cooperative lw staging BEFORE any early return (barrier safety)
    for (int i = threadIdx.x; i < 4096; i += 256)
        reinterpret_cast<int*>(lwL)[i] = reinterpret_cast<const int*>(lwb)[i];
    __syncthreads();
    const int widx = threadIdx.x >> 6;
    const int node = blockIdx.x * 4 + widx;
    const int lane = threadIdx.x & 63;
    if (node >= n) return;
    const int t = lane & (G - 1);
    const int g = lane >> 4;
    const bool h1 = (t * 8) >= C;
    const int selfoff = node * (F * 2);
    if (lane >= 48) { sA[widx][lane + 16] = selfoff; sW[widx][lane + 16] = make_float2(0.f, 0.f); }
    const char* xbt = (const char*)xh + t * 16;
    const int* crow = col + ((size_t)node << 7);
    const int deg = min(degv[(size_t)node * DEGS], CAP);
    const float2 adv = *reinterpret_cast<const float2*>(adst + 2 * node);
    const float2 asv = *reinterpret_cast<const float2*>(asrc + 2 * node);
    const float es0 = leaky(asv.x + adv.x), es1 = leaky(asv.y + adv.y);
    bf16x8 vself = *reinterpret_cast<const bf16x8*>(xbt + selfoff);
    float acc[8] = {};
    float d0 = 0.f, d1 = 0.f;
    for (int base = 0; base < deg; base += 64) {
        const int cnt = min(64, deg - base);
        int s = (lane < cnt) ? crow[base + lane] : node;
        sA[widx][lane] = s * (F * 2);
        float2 av = *reinterpret_cast<const float2*>(asrc + 2 * s);
        float w0 = 0.f, w1 = 0.f;
        if (lane < cnt) {
            w0 = __expf(leaky(av.x + adv.x));
            w1 = __expf(leaky(av.y + adv.y));
            d0 += w0; d1 += w1;
        }
        sW[widx][lane] = make_float2(w0, w1);
        for (int j = g; j < cnt; j += 16) {
            int o0 = sA[widx][j], o1 = sA[widx][j + 4], o2 = sA[widx][j + 8], o3 = sA[widx][j + 12];
            bf16x8 v0 = *reinterpret_cast<const bf16x8*>(xbt + o0);
            bf16x8 v1 = *reinterpret_cast<const bf16x8*>(xbt + o1);
            bf16x8 v2 = *reinterpret_cast<const bf16x8*>(xbt + o2);
            bf16x8 v3 = *reinterpret_cast<const bf16x8*>(xbt + o3);
            float2 x0 = sW[widx][j], x1 = sW[widx][j + 4], x2 = sW[widx][j + 8], x3 = sW[widx][j + 12];
            float w0 = h1 ? x0.y : x0.x;
            float w1 = h1 ? x1.y : x1.x;
            float w2 = h1 ? x2.y : x2.x;
            float w3 = h1 ? x3.y : x3.x;
#pragma unroll
            for (int q = 0; q < 8; ++q)
                acc[q] += w0 * (float)v0[q] + w1 * (float)v1[q] +
                          w2 * (float)v2[q] + w3 * (float)v3[q];
        }
    }
#pragma unroll
    for (int off = 1; off <= 32; off <<= 1) {
        d0 += __shfl_xor(d0, off);
        d1 += __shfl_xor(d1, off);
    }
#pragma unroll
    for (int q = 0; q < 8; ++q) {
#pragma unroll
        for (int off = G; off < 64; off <<= 1) acc[q] += __shfl_xor(acc[q], off);
    }
    float exs0 = __expf(es0), exs1 = __expf(es1);
    d0 += exs0; d1 += exs1;
    {
        float ws = h1 ? exs1 : exs0;
#pragma unroll
        for (int q = 0; q < 8; ++q) acc[q] += ws * (float)vself[q];
    }
    float inv = 1.0f / ((h1 ? d1 : d0) + EPS_SM);
    // h3 row (relu'd) -> LDS broadcast row (wave-synchronous: writer+reader same wave)
    if (g == 0) {
#pragma unroll
        for (int q = 0; q < 8; ++q)
            orow[widx][t * 8 + q] = fmaxf(acc[q] * inv + bias[t * 8 + q], 0.f);
    }
    // fused linear: lane c computes out[node][c]
    const int c = lane;
    float a2 = lb[c];
#pragma unroll 8
    for (int k = 0; k < 128; ++k)
        a2 += orow[widx][k] * (float)lwL[k * 64 + c];
    out[(size_t)node * 64 + c] = a2;
}

// ---------------- BatchNorm stats (layer 2 only; 256 blocks = low contention) ----
template <typename T>
__global__ void k_bn_stats(const T* __restrict__ x, float* __restrict__ sums,
                           float* __restrict__ sqs, int n, int f) {
    int c = threadIdx.x;
    float s = 0.f, q = 0.f;
    for (int r = blockIdx.x; r < n; r += gridDim.x) {
        float v = (float)x[(size_t)r * f + c];
        s += v; q += v * v;
    }
    atomicAdd(&sums[c], s);
    atomicAdd(&sqs[c], q);
}

// ---------------- launch ----------------
extern "C" void kernel_launch(void* const* d_in, const int* in_sizes, int n_in,
                              void* d_out, int out_size, void* d_ws, size_t ws_size,
                              hipStream_t stream) {
    const float* x   = (const float*)d_in[0];
    const int*   ei  = (const int*)d_in[1];
    const float* W1  = (const float*)d_in[2];
    const float* as1 = (const float*)d_in[3];
    const float* ad1 = (const float*)d_in[4];
    const float* b1  = (const float*)d_in[5];
    const float* g1  = (const float*)d_in[6];
    const float* be1 = (const float*)d_in[7];
    const float* W2  = (const float*)d_in[8];
    const float* as2 = (const float*)d_in[9];
    const float* ad2 = (const float*)d_in[10];
    const float* b2  = (const float*)d_in[11];
    const float* g2  = (const float*)d_in[12];
    const float* be2 = (const float*)d_in[13];
    const float* W3  = (const float*)d_in[14];
    const float* as3 = (const float*)d_in[15];
    const float* ad3 = (const float*)d_in[16];
    const float* b3  = (const float*)d_in[17];
    const float* lw  = (const float*)d_in[18];
    const float* lb  = (const float*)d_in[19];
    float* outp = (float*)d_out;

    const int n = in_sizes[0] / 128;  // 50000
    const int e = in_sizes[1] / 2;    // 800000

    char* w = (char*)d_ws;
    size_t off = 0;
    auto alloc = [&](size_t bytes) -> void* {
        void* p = w + off;
        off += (bytes + 255) & ~(size_t)255;
        return p;
    };
    __bf16* xhb = (__bf16*)alloc((size_t)n * 256 * 2);  // layer-1 agg out; later xh2/xh3
    __bf16* h1b = (__bf16*)alloc((size_t)n * 256 * 2);
    __bf16* h2b = (__bf16*)alloc((size_t)n * 128 * 2);
    int* colb   = (int*)alloc((size_t)n * CAP * 4);  // padded adjacency (25.6 MB)
    __bf16* xb  = (__bf16*)alloc((size_t)n * 128 * 2);  // bf16 copy of x (12.8 MB)
    __bf16* Wb1 = (__bf16*)alloc(256 * 128 * 2);
    __bf16* Wb2 = (__bf16*)alloc(128 * 256 * 2);
    __bf16* Wb3 = (__bf16*)alloc(128 * 128 * 2);
    __bf16* lwb = (__bf16*)alloc(128 * 64 * 2);
    float* wsd  = (float*)alloc(512 * 4);
    int* flag   = (int*)alloc(256);
    float* as1p = (float*)alloc((size_t)n * 2 * 4);
    float* ad1p = (float*)alloc((size_t)n * 2 * 4);
    float* as2p = (float*)alloc((size_t)n * 2 * 4);
    float* ad2p = (float*)alloc((size_t)n * 2 * 4);
    float* as3p = (float*)alloc((size_t)n * 2 * 4);
    float* ad3p = (float*)alloc((size_t)n * 2 * 4);
    // ---- contiguous zero block ----
    char* zb_begin = (char*)(w + off);
    int* deg    = (int*)alloc((size_t)n * DEGS * 4);  // line-padded counters (3.2 MB)
    float* bn1  = (float*)alloc(512 * 4);
    float* bn2  = (float*)alloc(512 * 4);
    char* zb_end = (char*)(w + off);
    const int zwords = (int)((zb_end - zb_begin) / 4);

    // init: detect (block 0) + zero (blocks 1..128) + wsd projection (block 129)
    k_init<<<130, 256, 0, stream>>>(ei, flag, (int*)zb_begin, zwords, e, W1, as1, ad1, wsd);

    const int ebase = ((e + 255) / 256) * 256;
    const int preblocks = (n + 31) / 32;
    const int histblocks = ebase / 256 + 352 + preblocks;  // edges + wconv(+lwb) + pre-pass
    k_hist_wconv<<<histblocks, 256, 0, stream>>>(ei, flag, deg, colb, e, ebase,
                                                 W1, Wb1, W2, Wb2, W3, Wb3,
                                                 lw, lwb, x, wsd, xb, as1p, ad1p, n);

    const int nwb = (n + 3) / 4;
    const int nrow = (n + 127) / 128;

    // ---- layer 1: input-space aggregation, then GEMM (+fused BN1 stats) ----
    k_agg_in<<<nwb, 256, 0, stream>>>(xb, as1p, ad1p, deg, colb, xhb, n);
    k_gemm_ar<<<dim3(2, nrow), 256, 0, stream>>>(xhb, Wb1, b1, h1b, bn1, n);

    // ---- layer 2: 256 -> 2x64 (BN1 inline in GEMM prologue; 64-col tiles) ----
    k_gemm<256, 6, true, 4><<<dim3(2, nrow), 256, 0, stream>>>(
        h1b, Wb2, xhb, n, 128, bn1, g1, be1, as2, ad2, as2p, ad2p);
    k_agg<64, true><<<nwb, 256, 0, stream>>>(xhb, as2p, ad2p, deg, colb, b2, h2b, n);
    k_bn_stats<__bf16><<<256, 128, 0, stream>>>(h2b, bn2, bn2 + 256, n, 128);

    // ---- layer 3: 128 -> 2x64 (BN2 inline) + fused final linear in aggregation ----
    k_gemm<128, 6, true, 4><<<dim3(2, nrow), 256, 0, stream>>>(
        h2b, Wb3, xhb, n, 128, bn2, g2, be2, as3, ad3, as3p, ad3p);
    k_agg_lin<<<nwb, 256, 0, stream>>>(xhb, as3p, ad3p, deg, colb, b3, lwb, lb, outp, n);
}

// Round 12
// 442.006 us; speedup vs baseline: 1.0505x; 1.0180x over previous
//
#include <hip/hip_runtime.h>
#include <hip/hip_bf16.h>

#define NEG_SLOPE 0.2f
#define EPS_BN 1e-5f
#define EPS_SM 1e-16f
#define CAP 128   // padded adjacency row capacity (Poisson(17): P(deg>128) ~ 0; clamped anyway)
#define DEGS 16   // deg counter stride (ints): one counter per 64B line

typedef __bf16 bf16x8 __attribute__((ext_vector_type(8)));
typedef __bf16 bf16x4 __attribute__((ext_vector_type(4)));
typedef float floatx4 __attribute__((ext_vector_type(4)));

__device__ __forceinline__ float leaky(float x) { return x > 0.f ? x : NEG_SLOPE * x; }

// ---- init: block 0 = edge dtype detect; blocks 1..128 = zero; block 129 = wsd ----
// wsd[j][k], j in {src_h0, src_h1, dst_h0, dst_h1}: wsd_s[h][k] = sum_c W1[k, h*128+c]*att[h,c]
__global__ void k_init(const int* __restrict__ ei, int* __restrict__ flag,
                       int* __restrict__ zbase, int zwords, int e,
                       const float* __restrict__ W1, const float* __restrict__ as1,
                       const float* __restrict__ ad1, float* __restrict__ wsd) {
    if (blockIdx.x == 0) {
        __shared__ int cnt_s[256];
        int i = threadIdx.x;  // pairs 0..255
        int nz = (2 * i + 1 < 2 * e && ei[2 * i + 1] != 0) ? 1 : 0;
        cnt_s[i] = nz;
        __syncthreads();
        for (int off = 128; off > 0; off >>= 1) {
            if (i < off) cnt_s[i] += cnt_s[i + off];
            __syncthreads();
        }
        if (i == 0) *flag = (cnt_s[0] < 128) ? 1 : 0;  // 1 => int64 layout
        return;
    }
    if (blockIdx.x == 129) {
        int k = threadIdx.x;
        if (k < 128) {
            const float* wr = W1 + (size_t)k * 256;
            float s0 = 0.f, s1 = 0.f, d0 = 0.f, d1 = 0.f;
            for (int c = 0; c < 128; ++c) {
                float w0 = wr[c], w1 = wr[128 + c];
                s0 += w0 * as1[c];
                s1 += w1 * as1[128 + c];
                d0 += w0 * ad1[c];
                d1 += w1 * ad1[128 + c];
            }
            wsd[k] = s0; wsd[128 + k] = s1; wsd[256 + k] = d0; wsd[384 + k] = d1;
        }
        return;
    }
    int g = (blockIdx.x - 1) * 256 + threadIdx.x;
    const int stride = 128 * 256;
    for (int k = g; k < zwords; k += stride) zbase[k] = 0;
}

// ---- hist + DIRECT scatter + weight convert (incl. lwb) + fused layer-1 pre-pass ----
__global__ void k_hist_wconv(const int* __restrict__ ei, const int* __restrict__ flag,
                             int* __restrict__ deg, int* __restrict__ col, int e, int ebase,
                             const float* __restrict__ W1, __bf16* __restrict__ Wb1,
                             const float* __restrict__ W2, __bf16* __restrict__ Wb2,
                             const float* __restrict__ W3, __bf16* __restrict__ Wb3,
                             const float* __restrict__ lw, __bf16* __restrict__ lwb,
                             const float* __restrict__ x, const float* __restrict__ wsd,
                             __bf16* __restrict__ xb, float* __restrict__ asp,
                             float* __restrict__ adp, int n) {
    int g = threadIdx.x + blockIdx.x * blockDim.x;
    if (g < e) {
        bool is64 = (*flag) != 0;
        int s = is64 ? ei[2 * g] : ei[g];
        int d = is64 ? ei[2 * (e + g)] : ei[e + g];
        int r = atomicAdd(&deg[(size_t)d * DEGS], 1);   // padded counter: 1 per 64B line
        if (r < CAP) col[((size_t)d << 7) + r] = s;
        return;
    }
    int idx = g - ebase;
    if (idx < 0) return;
    if (idx < 90112) {
        if (idx < 32768) {                      // W1: K=128, M=256
            int mm = idx >> 7, kk = idx & 127;
            Wb1[idx] = (__bf16)W1[(size_t)kk * 256 + mm];
        } else if (idx < 65536) {               // W2: K=256, M=128
            int i2 = idx - 32768;
            int mm = i2 >> 8, kk = i2 & 255;
            Wb2[i2] = (__bf16)W2[(size_t)kk * 128 + mm];
        } else if (idx < 81920) {               // W3: K=128, M=128
            int i3 = idx - 65536;
            int mm = i3 >> 7, kk = i3 & 127;
            Wb3[i3] = (__bf16)W3[(size_t)kk * 128 + mm];
        } else {                                // lw: [128][64] k-major, straight copy
            int i4 = idx - 81920;
            lwb[i4] = (__bf16)lw[i4];
        }
        return;
    }
    // ---- pre-pass region (whole blocks: e%256==0, 90112%256==0) ----
    int p = idx - 90112;
    __shared__ float ws[4][128];
    for (int i = threadIdx.x; i < 512; i += 256) ws[i >> 7][i & 127] = wsd[i];
    __syncthreads();
    const int lane = threadIdx.x & 63, widx = threadIdx.x >> 6;
    const int sub = lane & 7;
    const int node = (p >> 8) * 32 + widx * 8 + (lane >> 3);
    if (node >= n) return;
    const int c0 = sub * 16;
    const float* xp = x + (size_t)node * 128 + c0;
    float xv[16];
#pragma unroll
    for (int q = 0; q < 4; ++q) {
        float4 v = *reinterpret_cast<const float4*>(xp + q * 4);
        xv[q * 4 + 0] = v.x; xv[q * 4 + 1] = v.y; xv[q * 4 + 2] = v.z; xv[q * 4 + 3] = v.w;
    }
    float s0 = 0.f, s1 = 0.f, d0 = 0.f, d1 = 0.f;
#pragma unroll
    for (int i = 0; i < 16; ++i) {
        float xi = xv[i];
        int c = c0 + i;
        s0 += xi * ws[0][c]; s1 += xi * ws[1][c];
        d0 += xi * ws[2][c]; d1 += xi * ws[3][c];
    }
#pragma unroll
    for (int off = 1; off <= 4; off <<= 1) {
        s0 += __shfl_xor(s0, off); s1 += __shfl_xor(s1, off);
        d0 += __shfl_xor(d0, off); d1 += __shfl_xor(d1, off);
    }
    bf16x8 b0, b1;
#pragma unroll
    for (int i = 0; i < 8; ++i) { b0[i] = (__bf16)xv[i]; b1[i] = (__bf16)xv[8 + i]; }
    __bf16* po = xb + (size_t)node * 128 + c0;
    *reinterpret_cast<bf16x8*>(po) = b0;
    *reinterpret_cast<bf16x8*>(po + 8) = b1;
    if (sub == 0) {
        *reinterpret_cast<float2*>(asp + 2 * node) = make_float2(s0, s1);
        *reinterpret_cast<float2*>(adp + 2 * node) = make_float2(d0, d1);
    }
}

// ---- layer-1 aggregation in INPUT space, SPLIT slots ----
__global__ __launch_bounds__(256) void k_agg_in(const __bf16* __restrict__ xb,
                                                const float* __restrict__ asrc,
                                                const float* __restrict__ adst,
                                                const int* __restrict__ degv,
                                                const int* __restrict__ col,
                                                __bf16* __restrict__ aggv, int n) {
    __shared__ int sA[4][80];
    __shared__ float2 sW[4][80];
    const int widx = threadIdx.x >> 6;
    const int node = blockIdx.x * 4 + widx;
    const int lane = threadIdx.x & 63;
    if (node >= n) return;
    const int t = lane & 15;          // 16 lanes per edge, 8 ch each
    const int g = lane >> 4;          // 4 edges per wave-instr
    const int selfoff = node * 256;
    if (lane >= 48) { sA[widx][lane + 16] = selfoff; sW[widx][lane + 16] = make_float2(0.f, 0.f); }
    const char* xbt = (const char*)xb + t * 16;
    const int* crow = col + ((size_t)node << 7);
    const int deg = min(degv[(size_t)node * DEGS], CAP);
    const float2 adv = *reinterpret_cast<const float2*>(adst + 2 * node);
    const float2 asv = *reinterpret_cast<const float2*>(asrc + 2 * node);
    const float es0 = leaky(asv.x + adv.x), es1 = leaky(asv.y + adv.y);
    bf16x8 vself = *reinterpret_cast<const bf16x8*>(xbt + selfoff);  // early issue
    float a0[8] = {}, a1[8] = {};
    float d0 = 0.f, d1 = 0.f;
    for (int base = 0; base < deg; base += 64) {
        const int cnt = min(64, deg - base);
        int s = (lane < cnt) ? crow[base + lane] : node;
        sA[widx][lane] = s * 256;     // address available BEFORE exp chain completes
        float2 av = *reinterpret_cast<const float2*>(asrc + 2 * s);
        float w0 = 0.f, w1 = 0.f;
        if (lane < cnt) {
            w0 = __expf(leaky(av.x + adv.x));
            w1 = __expf(leaky(av.y + adv.y));
            d0 += w0; d1 += w1;
        }
        sW[widx][lane] = make_float2(w0, w1);
        for (int j = g; j < cnt; j += 16) {
            int o0 = sA[widx][j], o1 = sA[widx][j + 4], o2 = sA[widx][j + 8], o3 = sA[widx][j + 12];
            bf16x8 v0 = *reinterpret_cast<const bf16x8*>(xbt + o0);
            bf16x8 v1 = *reinterpret_cast<const bf16x8*>(xbt + o1);
            bf16x8 v2 = *reinterpret_cast<const bf16x8*>(xbt + o2);
            bf16x8 v3 = *reinterpret_cast<const bf16x8*>(xbt + o3);
            float2 x0 = sW[widx][j], x1 = sW[widx][j + 4], x2 = sW[widx][j + 8], x3 = sW[widx][j + 12];
#pragma unroll
            for (int q = 0; q < 8; ++q) {
                float f0 = (float)v0[q], f1 = (float)v1[q], f2 = (float)v2[q], f3 = (float)v3[q];
                a0[q] += x0.x * f0 + x1.x * f1 + x2.x * f2 + x3.x * f3;
                a1[q] += x0.y * f0 + x1.y * f1 + x2.y * f2 + x3.y * f3;
            }
        }
    }
#pragma unroll
    for (int off = 1; off <= 32; off <<= 1) {
        d0 += __shfl_xor(d0, off);
        d1 += __shfl_xor(d1, off);
    }
#pragma unroll
    for (int q = 0; q < 8; ++q) {
#pragma unroll
        for (int off = 16; off < 64; off <<= 1) {
            a0[q] += __shfl_xor(a0[q], off);
            a1[q] += __shfl_xor(a1[q], off);
        }
    }
    float exs0 = __expf(es0), exs1 = __expf(es1);
    d0 += exs0; d1 += exs1;
#pragma unroll
    for (int q = 0; q < 8; ++q) {
        a0[q] += exs0 * (float)vself[q];
        a1[q] += exs1 * (float)vself[q];
    }
    float i0 = 1.0f / (d0 + EPS_SM), i1 = 1.0f / (d1 + EPS_SM);
    if (g == 0) {
        bf16x8 st0, st1;
#pragma unroll
        for (int q = 0; q < 8; ++q) {
            st0[q] = (__bf16)(a0[q] * i0);
            st1[q] = (__bf16)(a1[q] * i1);
        }
        __bf16* po = aggv + (size_t)node * 256 + t * 8;
        *reinterpret_cast<bf16x8*>(po) = st0;
        *reinterpret_cast<bf16x8*>(po + 128) = st1;
    }
}

// ---- layer-1 post-GEMM with fused BN1 stats ----
__global__ __launch_bounds__(256) void k_gemm_ar(const __bf16* __restrict__ A,
                                                 const __bf16* __restrict__ Bt,
                                                 const float* __restrict__ bias,
                                                 __bf16* __restrict__ Cb,
                                                 float* __restrict__ bnsums, int n) {
    __shared__ __align__(16) __bf16 As[128][72];
    __shared__ __align__(16) __bf16 Bs[128][72];
    const int row0 = blockIdx.y * 128, col0 = blockIdx.x * 128;
    const int h = col0 >> 7;
    const int lane = threadIdx.x & 63, w = threadIdx.x >> 6;
    const int m = lane & 15, quad = lane >> 4;
    floatx4 acc[2][8];
#pragma unroll
    for (int i = 0; i < 2; ++i)
#pragma unroll
        for (int j = 0; j < 8; ++j) acc[i][j] = (floatx4)0.f;
    const int sr = threadIdx.x >> 1;
    const int sk = (threadIdx.x & 1) * 32;
    for (int kc = 0; kc < 128; kc += 64) {
        {
            int grow = row0 + sr;
            if (grow < n) {
                const __bf16* p = A + (size_t)grow * 256 + h * 128 + kc + sk;
#pragma unroll
                for (int q = 0; q < 4; ++q)
                    *reinterpret_cast<bf16x8*>(&As[sr][sk + q * 8]) =
                        *reinterpret_cast<const bf16x8*>(p + q * 8);
            } else {
#pragma unroll
                for (int q = 0; q < 4; ++q)
                    *reinterpret_cast<bf16x8*>(&As[sr][sk + q * 8]) = (bf16x8)(__bf16)0.f;
            }
        }
        {
            const __bf16* p = Bt + (size_t)(col0 + sr) * 128 + kc + sk;
#pragma unroll
            for (int q = 0; q < 4; ++q)
                *reinterpret_cast<bf16x8*>(&Bs[sr][sk + q * 8]) =
                    *reinterpret_cast<const bf16x8*>(p + q * 8);
        }
        __syncthreads();
#pragma unroll
        for (int ks = 0; ks < 64; ks += 32) {
            bf16x8 a0 = *reinterpret_cast<const bf16x8*>(&As[w * 32 + m][ks + quad * 8]);
            bf16x8 a1 = *reinterpret_cast<const bf16x8*>(&As[w * 32 + 16 + m][ks + quad * 8]);
#pragma unroll
            for (int nt = 0; nt < 8; ++nt) {
                bf16x8 b = *reinterpret_cast<const bf16x8*>(&Bs[nt * 16 + m][ks + quad * 8]);
                acc[0][nt] = __builtin_amdgcn_mfma_f32_16x16x32_bf16(a0, b, acc[0][nt], 0, 0, 0);
                acc[1][nt] = __builtin_amdgcn_mfma_f32_16x16x32_bf16(a1, b, acc[1][nt], 0, 0, 0);
            }
        }
        __syncthreads();
    }
    // epilogue: store relu + accumulate BN stats (As free after final k-loop sync)
    float* redS = reinterpret_cast<float*>(As);      // [4][128]
    float* redQ = redS + 512;                        // [4][128]
#pragma unroll
    for (int nt = 0; nt < 8; ++nt) {
        float bsv = bias[col0 + nt * 16 + m];
        float ssum = 0.f, ssq = 0.f;
#pragma unroll
        for (int mt = 0; mt < 2; ++mt)
#pragma unroll
            for (int r = 0; r < 4; ++r) {
                int row = row0 + w * 32 + mt * 16 + quad * 4 + r;
                float v = 0.f;
                if (row < n) {
                    v = fmaxf(acc[mt][nt][r] + bsv, 0.f);
                    Cb[(size_t)row * 256 + col0 + nt * 16 + m] = (__bf16)v;
                }
                ssum += v; ssq += v * v;
            }
        ssum += __shfl_xor(ssum, 16); ssum += __shfl_xor(ssum, 32);
        ssq  += __shfl_xor(ssq, 16);  ssq  += __shfl_xor(ssq, 32);
        if (quad == 0) {
            redS[w * 128 + nt * 16 + m] = ssum;
            redQ[w * 128 + nt * 16 + m] = ssq;
        }
    }
    __syncthreads();
    if (threadIdx.x < 128) {
        int c = threadIdx.x;
        float s = redS[c] + redS[128 + c] + redS[256 + c] + redS[384 + c];
        float q2 = redQ[c] + redQ[128 + c] + redQ[256 + c] + redQ[384 + c];
        atomicAdd(&bnsums[col0 + c], s);
        atomicAdd(&bnsums[256 + col0 + c], q2);
    }
}

// ---- bf16 MFMA GEMM (layers 2/3), inline BN prep + attn dots ----
template <int K, int LC, bool BF16IN, int NT>
__global__ __launch_bounds__(256) void k_gemm(const void* __restrict__ Ain,
                                              const __bf16* __restrict__ Bt,
                                              __bf16* __restrict__ Cb, int n, int M,
                                              const float* __restrict__ bnsums,
                                              const float* __restrict__ gam,
                                              const float* __restrict__ bet,
                                              const float* __restrict__ att_s,
                                              const float* __restrict__ att_d,
                                              float* __restrict__ asrc,
                                              float* __restrict__ adst) {
    __shared__ __align__(16) __bf16 As[128][72];
    __shared__ __align__(16) __bf16 Bs[NT * 16][72];
    __shared__ float sc_lds[K], sh_lds[K];
    const int row0 = blockIdx.y * 128, col0 = blockIdx.x * (NT * 16);
    const int lane = threadIdx.x & 63, w = threadIdx.x >> 6;
    const int m = lane & 15, quad = lane >> 4;

    if (bnsums) {
        for (int c = threadIdx.x; c < K; c += 256) {
            float mean = bnsums[c] / n;
            float var = bnsums[256 + c] / n - mean * mean;
            float sc = gam[c] * rsqrtf(var + EPS_BN);
            sc_lds[c] = sc;
            sh_lds[c] = bet[c] - mean * sc;
        }
        __syncthreads();
    }

    floatx4 acc[2][NT];
#pragma unroll
    for (int i = 0; i < 2; ++i)
#pragma unroll
        for (int j = 0; j < NT; ++j) acc[i][j] = (floatx4)0.f;

    const int sr = threadIdx.x >> 1;        // A-stage: 0..127
    const int sk = (threadIdx.x & 1) * 32;

    for (int kc = 0; kc < K; kc += 64) {
        {
            int grow = row0 + sr;
            if (grow < n) {
                if (BF16IN) {
                    const __bf16* p = (const __bf16*)Ain + (size_t)grow * K + kc + sk;
#pragma unroll
                    for (int q = 0; q < 4; ++q) {
                        bf16x8 vv = *reinterpret_cast<const bf16x8*>(p + q * 8);
                        if (bnsums) {
                            int c = kc + sk + q * 8;
                            bf16x8 r;
#pragma unroll
                            for (int e2 = 0; e2 < 8; ++e2)
                                r[e2] = (__bf16)((float)vv[e2] * sc_lds[c + e2] + sh_lds[c + e2]);
                            vv = r;
                        }
                        *reinterpret_cast<bf16x8*>(&As[sr][sk + q * 8]) = vv;
                    }
                } else {
                    const float* p = (const float*)Ain + (size_t)grow * K + kc + sk;
#pragma unroll
                    for (int q = 0; q < 8; ++q) {
                        float4 v = *reinterpret_cast<const float4*>(p + q * 4);
                        bf16x4 cv = {(__bf16)v.x, (__bf16)v.y, (__bf16)v.z, (__bf16)v.w};
                        *reinterpret_cast<bf16x4*>(&As[sr][sk + q * 4]) = cv;
                    }
                }
            } else {
#pragma unroll
                for (int q = 0; q < 4; ++q)
                    *reinterpret_cast<bf16x8*>(&As[sr][sk + q * 8]) = (bf16x8)(__bf16)0.f;
            }
        }
        if (NT == 8) {
            const __bf16* p = Bt + (size_t)(col0 + sr) * K + kc + sk;
#pragma unroll
            for (int q = 0; q < 4; ++q)
                *reinterpret_cast<bf16x8*>(&Bs[sr][sk + q * 8]) =
                    *reinterpret_cast<const bf16x8*>(p + q * 8);
        } else {  // NT==4: 64 B-rows, 16 bf16 per thread
            int sr4 = threadIdx.x >> 2, sk4 = (threadIdx.x & 3) * 16;
            const __bf16* p = Bt + (size_t)(col0 + sr4) * K + kc + sk4;
            *reinterpret_cast<bf16x8*>(&Bs[sr4][sk4]) = *reinterpret_cast<const bf16x8*>(p);
            *reinterpret_cast<bf16x8*>(&Bs[sr4][sk4 + 8]) = *reinterpret_cast<const bf16x8*>(p + 8);
        }
        __syncthreads();
#pragma unroll
        for (int ks = 0; ks < 64; ks += 32) {
            bf16x8 a0 = *reinterpret_cast<const bf16x8*>(&As[w * 32 + m][ks + quad * 8]);
            bf16x8 a1 = *reinterpret_cast<const bf16x8*>(&As[w * 32 + 16 + m][ks + quad * 8]);
#pragma unroll
            for (int nt = 0; nt < NT; ++nt) {
                bf16x8 b = *reinterpret_cast<const bf16x8*>(&Bs[nt * 16 + m][ks + quad * 8]);
                acc[0][nt] = __builtin_amdgcn_mfma_f32_16x16x32_bf16(a0, b, acc[0][nt], 0, 0, 0);
                acc[1][nt] = __builtin_amdgcn_mfma_f32_16x16x32_bf16(a1, b, acc[1][nt], 0, 0, 0);
            }
        }
        __syncthreads();
    }
#pragma unroll
    for (int mt = 0; mt < 2; ++mt)
#pragma unroll
        for (int nt = 0; nt < NT; ++nt)
#pragma unroll
            for (int r = 0; r < 4; ++r) {
                int row = row0 + w * 32 + mt * 16 + quad * 4 + r;
                if (row < n) Cb[(size_t)row * M + col0 + nt * 16 + m] = (__bf16)acc[mt][nt][r];
            }
    // fused attention dots (single complete head per block -> plain store)
    {
        float asv[NT], adv[NT];
#pragma unroll
        for (int nt = 0; nt < NT; ++nt) {
            int c = col0 + nt * 16 + m;
            asv[nt] = att_s[c];
            adv[nt] = att_d[c];
        }
        const int h = (col0 >> LC) & 1;
#pragma unroll
        for (int mt = 0; mt < 2; ++mt)
#pragma unroll
            for (int r = 0; r < 4; ++r) {
                int row = row0 + w * 32 + mt * 16 + quad * 4 + r;
                float pa = 0.f, pb = 0.f;
#pragma unroll
                for (int nt = 0; nt < NT; ++nt) {
                    float v = acc[mt][nt][r];
                    pa += v * asv[nt];
                    pb += v * adv[nt];
                }
#pragma unroll
                for (int off = 1; off <= 8; off <<= 1) {
                    pa += __shfl_xor(pa, off);
                    pb += __shfl_xor(pb, off);
                }
                if (m == 0 && row < n) {
                    asrc[2 * row + h] = pa;
                    adst[2 * row + h] = pb;
                }
            }
    }
}

// ---- GAT aggregation (layer 2): node-per-wave depth-4 + SPLIT slots ----
template <int C, bool OUTBF16>
__global__ __launch_bounds__(256) void k_agg(const __bf16* __restrict__ xh,
                                             const float* __restrict__ asrc,
                                             const float* __restrict__ adst,
                                             const int* __restrict__ degv,
                                             const int* __restrict__ col,
                                             const float* __restrict__ bias,
                                             void* __restrict__ outv, int n) {
    constexpr int F = 2 * C;          // bf16 per row (128)
    constexpr int G = F / 8;          // lanes per edge (16)
    constexpr int NG = 64 / G;        // edges per wave-step (4)
    constexpr int GSH = (G == 32) ? 5 : 4;
    __shared__ int sA[4][80];
    __shared__ float2 sW[4][80];
    const int widx = threadIdx.x >> 6;
    const int node = blockIdx.x * 4 + widx;
    const int lane = threadIdx.x & 63;
    if (node >= n) return;
    const int t = lane & (G - 1);
    const int g = lane >> GSH;
    const bool h1 = (t * 8) >= C;
    const int selfoff = node * (F * 2);
    if (lane >= 48) { sA[widx][lane + 16] = selfoff; sW[widx][lane + 16] = make_float2(0.f, 0.f); }
    const char* xbt = (const char*)xh + t * 16;
    const int* crow = col + ((size_t)node << 7);
    const int deg = min(degv[(size_t)node * DEGS], CAP);
    const float2 adv = *reinterpret_cast<const float2*>(adst + 2 * node);
    const float2 asv = *reinterpret_cast<const float2*>(asrc + 2 * node);
    const float es0 = leaky(asv.x + adv.x), es1 = leaky(asv.y + adv.y);
    bf16x8 vself = *reinterpret_cast<const bf16x8*>(xbt + selfoff);  // early issue
    float acc[8] = {};
    float d0 = 0.f, d1 = 0.f;
    for (int base = 0; base < deg; base += 64) {
        const int cnt = min(64, deg - base);
        int s = (lane < cnt) ? crow[base + lane] : node;
        sA[widx][lane] = s * (F * 2);
        float2 av = *reinterpret_cast<const float2*>(asrc + 2 * s);
        float w0 = 0.f, w1 = 0.f;
        if (lane < cnt) {
            w0 = __expf(leaky(av.x + adv.x));
            w1 = __expf(leaky(av.y + adv.y));
            d0 += w0; d1 += w1;
        }
        sW[widx][lane] = make_float2(w0, w1);
        for (int j = g; j < cnt; j += 4 * NG) {
            int o0 = sA[widx][j], o1 = sA[widx][j + NG], o2 = sA[widx][j + 2 * NG], o3 = sA[widx][j + 3 * NG];
            bf16x8 v0 = *reinterpret_cast<const bf16x8*>(xbt + o0);
            bf16x8 v1 = *reinterpret_cast<const bf16x8*>(xbt + o1);
            bf16x8 v2 = *reinterpret_cast<const bf16x8*>(xbt + o2);
            bf16x8 v3 = *reinterpret_cast<const bf16x8*>(xbt + o3);
            float2 x0 = sW[widx][j], x1 = sW[widx][j + NG], x2 = sW[widx][j + 2 * NG], x3 = sW[widx][j + 3 * NG];
            float w0 = h1 ? x0.y : x0.x;
            float w1 = h1 ? x1.y : x1.x;
            float w2 = h1 ? x2.y : x2.x;
            float w3 = h1 ? x3.y : x3.x;
#pragma unroll
            for (int q = 0; q < 8; ++q)
                acc[q] += w0 * (float)v0[q] + w1 * (float)v1[q] +
                          w2 * (float)v2[q] + w3 * (float)v3[q];
        }
    }
#pragma unroll
    for (int off = 1; off <= 32; off <<= 1) {
        d0 += __shfl_xor(d0, off);
        d1 += __shfl_xor(d1, off);
    }
#pragma unroll
    for (int q = 0; q < 8; ++q) {
#pragma unroll
        for (int off = G; off < 64; off <<= 1) acc[q] += __shfl_xor(acc[q], off);
    }
    float exs0 = __expf(es0), exs1 = __expf(es1);
    d0 += exs0; d1 += exs1;
    {
        float ws = h1 ? exs1 : exs0;
#pragma unroll
        for (int q = 0; q < 8; ++q) acc[q] += ws * (float)vself[q];
    }
    float inv = 1.0f / ((h1 ? d1 : d0) + EPS_SM);
    float o[8];
#pragma unroll
    for (int q = 0; q < 8; ++q) o[q] = fmaxf(acc[q] * inv + bias[t * 8 + q], 0.f);
    if (g == 0) {
        if constexpr (OUTBF16) {
            __bf16* po = (__bf16*)outv + (size_t)node * F + t * 8;
            bf16x8 st;
#pragma unroll
            for (int q = 0; q < 8; ++q) st[q] = (__bf16)o[q];
            *reinterpret_cast<bf16x8*>(po) = st;
        } else {
            float* po = (float*)outv + (size_t)node * F + t * 8;
            *reinterpret_cast<float4*>(po) = make_float4(o[0], o[1], o[2], o[3]);
            *reinterpret_cast<float4*>(po + 4) = make_float4(o[4], o[5], o[6], o[7]);
        }
    }
}

// ---- layer-3 aggregation + FUSED final linear via MFMA:
//      per block, 4 nodes' h3 rows -> shared A tile (hi/lo bf16, = old k_lin precision);
//      out[4x64] = A @ lw via 8 MFMAs/wave. No h3f round trip, no k_lin dispatch.
__global__ __launch_bounds__(256) void k_agg_lin(const __bf16* __restrict__ xh,
                                                 const float* __restrict__ asrc,
                                                 const float* __restrict__ adst,
                                                 const int* __restrict__ degv,
                                                 const int* __restrict__ col,
                                                 const float* __restrict__ bias,
                                                 const __bf16* __restrict__ lwb,
                                                 const float* __restrict__ lb,
                                                 float* __restrict__ out, int n) {
    constexpr int C = 64, F = 128, G = 16;
    __shared__ int sA[4][80];
    __shared__ float2 sW[4][80];
    __shared__ __align__(16) __bf16 Ahi[16][136];
    __shared__ __align__(16) __bf16 Alo[16][136];
    __shared__ __align__(16) __bf16 Bls[64][136];   // lw transposed: [c][k]
    // cooperative staging + A-tile zero (before any divergence; no early returns)
    for (int i = threadIdx.x; i < 8192; i += 256) {
        int k = i >> 6, c = i & 63;
        Bls[c][k] = lwb[i];
    }
    for (int i = threadIdx.x; i < 2048; i += 256) {
        int r = i >> 7, c = i & 127;
        Ahi[r][c] = (__bf16)0.f;
        Alo[r][c] = (__bf16)0.f;
    }
    __syncthreads();
    const int widx = threadIdx.x >> 6;
    const int node = blockIdx.x * 4 + widx;
    const int lane = threadIdx.x & 63;
    const bool valid = node < n;
    const int nodec = valid ? node : 0;
    const int t = lane & (G - 1);
    const int g = lane >> 4;
    const bool h1 = (t * 8) >= C;
    const int selfoff = nodec * (F * 2);
    if (lane >= 48) { sA[widx][lane + 16] = selfoff; sW[widx][lane + 16] = make_float2(0.f, 0.f); }
    const char* xbt = (const char*)xh + t * 16;
    const int* crow = col + ((size_t)nodec << 7);
    const int deg = valid ? min(degv[(size_t)nodec * DEGS], CAP) : 0;
    const float2 adv = *reinterpret_cast<const float2*>(adst + 2 * nodec);
    const float2 asv = *reinterpret_cast<const float2*>(asrc + 2 * nodec);
    const float es0 = leaky(asv.x + adv.x), es1 = leaky(asv.y + adv.y);
    bf16x8 vself = *reinterpret_cast<const bf16x8*>(xbt + selfoff);
    float acc[8] = {};
    float d0 = 0.f, d1 = 0.f;
    for (int base = 0; base < deg; base += 64) {
        const int cnt = min(64, deg - base);
        int s = (lane < cnt) ? crow[base + lane] : nodec;
        sA[widx][lane] = s * (F * 2);
        float2 av = *reinterpret_cast<const float2*>(asrc + 2 * s);
        float w0 = 0.f, w1 = 0.f;
        if (lane < cnt) {
            w0 = __expf(leaky(av.x + adv.x));
            w1 = __expf(leaky(av.y + adv.y));
            d0 += w0; d1 += w1;
        }
        sW[widx][lane] = make_float2(w0, w1);
        for (int j = g; j < cnt; j += 16) {
            int o0 = sA[widx][j], o1 = sA[widx][j + 4], o2 = sA[widx][j + 8], o3 = sA[widx][j + 12];
            bf16x8 v0 = *reinterpret_cast<const bf16x8*>(xbt + o0);
            bf16x8 v1 = *reinterpret_cast<const bf16x8*>(xbt + o1);
            bf16x8 v2 = *reinterpret_cast<const bf16x8*>(xbt + o2);
            bf16x8 v3 = *reinterpret_cast<const bf16x8*>(xbt + o3);
            float2 x0 = sW[widx][j], x1 = sW[widx][j + 4], x2 = sW[widx][j + 8], x3 = sW[widx][j + 12];
            float w0 = h1 ? x0.y : x0.x;
            float w1 = h1 ? x1.y : x1.x;
            float w2 = h1 ? x2.y : x2.x;
            float w3 = h1 ? x3.y : x3.x;
#pragma unroll
            for (int q = 0; q < 8; ++q)
                acc[q] += w0 * (float)v0[q] + w1 * (float)v1[q] +
                          w2 * (float)v2[q] + w3 * (float)v3[q];
        }
    }
#pragma unroll
    for (int off = 1; off <= 32; off <<= 1) {
        d0 += __shfl_xor(d0, off);
        d1 += __shfl_xor(d1, off);
    }
#pragma unroll
    for (int q = 0; q < 8; ++q) {
#pragma unroll
        for (int off = G; off < 64; off <<= 1) acc[q] += __shfl_xor(acc[q], off);
    }
    float exs0 = __expf(es0), exs1 = __expf(es1);
    d0 += exs0; d1 += exs1;
    {
        float ws = h1 ? exs1 : exs0;
#pragma unroll
        for (int q = 0; q < 8; ++q) acc[q] += ws * (float)vself[q];
    }
    float inv = 1.0f / ((h1 ? d1 : d0) + EPS_SM);
    // h3 row (relu'd, f32) -> hi/lo bf16 into A-tile row widx
    if (g == 0 && valid) {
#pragma unroll
        for (int q = 0; q < 8; ++q) {
            float v = fmaxf(acc[q] * inv + bias[t * 8 + q], 0.f);
            __bf16 hi = (__bf16)v;
            Ahi[widx][t * 8 + q] = hi;
            Alo[widx][t * 8 + q] = (__bf16)(v - (float)hi);
        }
    }
    __syncthreads();
    // MFMA: wave widx computes cols widx*16..+15 for all 4 node-rows
    const int m = lane & 15, quad = lane >> 4;
    floatx4 oacc = (floatx4)0.f;
#pragma unroll
    for (int ks = 0; ks < 128; ks += 32) {
        bf16x8 ah = *reinterpret_cast<const bf16x8*>(&Ahi[m][ks + quad * 8]);
        bf16x8 al = *reinterpret_cast<const bf16x8*>(&Alo[m][ks + quad * 8]);
        bf16x8 b  = *reinterpret_cast<const bf16x8*>(&Bls[widx * 16 + m][ks + quad * 8]);
        oacc = __builtin_amdgcn_mfma_f32_16x16x32_bf16(ah, b, oacc, 0, 0, 0);
        oacc = __builtin_amdgcn_mfma_f32_16x16x32_bf16(al, b, oacc, 0, 0, 0);
    }
    // C layout: col = widx*16 + m, row = quad*4 + r; rows 0..3 = block's nodes
    if (quad == 0) {
        int c = widx * 16 + m;
        float lbv = lb[c];
#pragma unroll
        for (int r = 0; r < 4; ++r) {
            int nd = blockIdx.x * 4 + r;
            if (nd < n) out[(size_t)nd * 64 + c] = oacc[r] + lbv;
        }
    }
}

// ---------------- BatchNorm stats (layer 2 only; 256 blocks = low contention) ----
template <typename T>
__global__ void k_bn_stats(const T* __restrict__ x, float* __restrict__ sums,
                           float* __restrict__ sqs, int n, int f) {
    int c = threadIdx.x;
    float s = 0.f, q = 0.f;
    for (int r = blockIdx.x; r < n; r += gridDim.x) {
        float v = (float)x[(size_t)r * f + c];
        s += v; q += v * v;
    }
    atomicAdd(&sums[c], s);
    atomicAdd(&sqs[c], q);
}

// ---------------- launch ----------------
extern "C" void kernel_launch(void* const* d_in, const int* in_sizes, int n_in,
                              void* d_out, int out_size, void* d_ws, size_t ws_size,
                              hipStream_t stream) {
    const float* x   = (const float*)d_in[0];
    const int*   ei  = (const int*)d_in[1];
    const float* W1  = (const float*)d_in[2];
    const float* as1 = (const float*)d_in[3];
    const float* ad1 = (const float*)d_in[4];
    const float* b1  = (const float*)d_in[5];
    const float* g1  = (const float*)d_in[6];
    const float* be1 = (const float*)d_in[7];
    const float* W2  = (const float*)d_in[8];
    const float* as2 = (const float*)d_in[9];
    const float* ad2 = (const float*)d_in[10];
    const float* b2  = (const float*)d_in[11];
    const float* g2  = (const float*)d_in[12];
    const float* be2 = (const float*)d_in[13];
    const float* W3  = (const float*)d_in[14];
    const float* as3 = (const float*)d_in[15];
    const float* ad3 = (const float*)d_in[16];
    const float* b3  = (const float*)d_in[17];
    const float* lw  = (const float*)d_in[18];
    const float* lb  = (const float*)d_in[19];
    float* outp = (float*)d_out;

    const int n = in_sizes[0] / 128;  // 50000
    const int e = in_sizes[1] / 2;    // 800000

    char* w = (char*)d_ws;
    size_t off = 0;
    auto alloc = [&](size_t bytes) -> void* {
        void* p = w + off;
        off += (bytes + 255) & ~(size_t)255;
        return p;
    };
    __bf16* xhb = (__bf16*)alloc((size_t)n * 256 * 2);  // layer-1 agg out; later xh2/xh3
    __bf16* h1b = (__bf16*)alloc((size_t)n * 256 * 2);
    __bf16* h2b = (__bf16*)alloc((size_t)n * 128 * 2);
    int* colb   = (int*)alloc((size_t)n * CAP * 4);  // padded adjacency (25.6 MB)
    __bf16* xb  = (__bf16*)alloc((size_t)n * 128 * 2);  // bf16 copy of x (12.8 MB)
    __bf16* Wb1 = (__bf16*)alloc(256 * 128 * 2);
    __bf16* Wb2 = (__bf16*)alloc(128 * 256 * 2);
    __bf16* Wb3 = (__bf16*)alloc(128 * 128 * 2);
    __bf16* lwb = (__bf16*)alloc(128 * 64 * 2);
    float* wsd  = (float*)alloc(512 * 4);
    int* flag   = (int*)alloc(256);
    float* as1p = (float*)alloc((size_t)n * 2 * 4);
    float* ad1p = (float*)alloc((size_t)n * 2 * 4);
    float* as2p = (float*)alloc((size_t)n * 2 * 4);
    float* ad2p = (float*)alloc((size_t)n * 2 * 4);
    float* as3p = (float*)alloc((size_t)n * 2 * 4);
    float* ad3p = (float*)alloc((size_t)n * 2 * 4);
    // ---- contiguous zero block ----
    char* zb_begin = (char*)(w + off);
    int* deg    = (int*)alloc((size_t)n * DEGS * 4);  // line-padded counters (3.2 MB)
    float* bn1  = (float*)alloc(512 * 4);
    float* bn2  = (float*)alloc(512 * 4);
    char* zb_end = (char*)(w + off);
    const int zwords = (int)((zb_end - zb_begin) / 4);

    // init: detect (block 0) + zero (blocks 1..128) + wsd projection (block 129)
    k_init<<<130, 256, 0, stream>>>(ei, flag, (int*)zb_begin, zwords, e, W1, as1, ad1, wsd);

    const int ebase = ((e + 255) / 256) * 256;
    const int preblocks = (n + 31) / 32;
    const int histblocks = ebase / 256 + 352 + preblocks;  // edges + wconv(+lwb) + pre-pass
    k_hist_wconv<<<histblocks, 256, 0, stream>>>(ei, flag, deg, colb, e, ebase,
                                                 W1, Wb1, W2, Wb2, W3, Wb3,
                                                 lw, lwb, x, wsd, xb, as1p, ad1p, n);

    const int nwb = (n + 3) / 4;
    const int nrow = (n + 127) / 128;

    // ---- layer 1: input-space aggregation, then GEMM (+fused BN1 stats) ----
    k_agg_in<<<nwb, 256, 0, stream>>>(xb, as1p, ad1p, deg, colb, xhb, n);
    k_gemm_ar<<<dim3(2, nrow), 256, 0, stream>>>(xhb, Wb1, b1, h1b, bn1, n);

    // ---- layer 2: 256 -> 2x64 (BN1 inline in GEMM prologue; 64-col tiles) ----
    k_gemm<256, 6, true, 4><<<dim3(2, nrow), 256, 0, stream>>>(
        h1b, Wb2, xhb, n, 128, bn1, g1, be1, as2, ad2, as2p, ad2p);
    k_agg<64, true><<<nwb, 256, 0, stream>>>(xhb, as2p, ad2p, deg, colb, b2, h2b, n);
    k_bn_stats<__bf16><<<256, 128, 0, stream>>>(h2b, bn2, bn2 + 256, n, 128);

    // ---- layer 3: 128 -> 2x64 (BN2 inline) + MFMA-fused final linear ----
    k_gemm<128, 6, true, 4><<<dim3(2, nrow), 256, 0, stream>>>(
        h2b, Wb3, xhb, n, 128, bn2, g2, be2, as3, ad3, as3p, ad3p);
    k_agg_lin<<<nwb, 256, 0, stream>>>(xhb, as3p, ad3p, deg, colb, b3, lwb, lb, outp, n);
}

// Round 14
// 441.270 us; speedup vs baseline: 1.0523x; 1.0017x over previous
//
#include <hip/hip_runtime.h>
#include <hip/hip_bf16.h>

#define NEG_SLOPE 0.2f
#define EPS_BN 1e-5f
#define EPS_SM 1e-16f
#define CAP 128   // padded adjacency row capacity (Poisson(17): P(deg>128) ~ 0; clamped anyway)
#define DEGS 16   // deg counter stride (ints): one counter per 64B line

typedef __bf16 bf16x8 __attribute__((ext_vector_type(8)));
typedef __bf16 bf16x4 __attribute__((ext_vector_type(4)));
typedef float floatx4 __attribute__((ext_vector_type(4)));

__device__ __forceinline__ float leaky(float x) { return x > 0.f ? x : NEG_SLOPE * x; }

// ---- init: block 0 = edge dtype detect; blocks 1..128 = zero; block 129 = wsd ----
// wsd[j][k], j in {src_h0, src_h1, dst_h0, dst_h1}: wsd_s[h][k] = sum_c W1[k, h*128+c]*att[h,c]
__global__ void k_init(const int* __restrict__ ei, int* __restrict__ flag,
                       int* __restrict__ zbase, int zwords, int e,
                       const float* __restrict__ W1, const float* __restrict__ as1,
                       const float* __restrict__ ad1, float* __restrict__ wsd) {
    if (blockIdx.x == 0) {
        __shared__ int cnt_s[256];
        int i = threadIdx.x;  // pairs 0..255
        int nz = (2 * i + 1 < 2 * e && ei[2 * i + 1] != 0) ? 1 : 0;
        cnt_s[i] = nz;
        __syncthreads();
        for (int off = 128; off > 0; off >>= 1) {
            if (i < off) cnt_s[i] += cnt_s[i + off];
            __syncthreads();
        }
        if (i == 0) *flag = (cnt_s[0] < 128) ? 1 : 0;  // 1 => int64 layout
        return;
    }
    if (blockIdx.x == 129) {
        int k = threadIdx.x;
        if (k < 128) {
            const float* wr = W1 + (size_t)k * 256;
            float s0 = 0.f, s1 = 0.f, d0 = 0.f, d1 = 0.f;
            for (int c = 0; c < 128; ++c) {
                float w0 = wr[c], w1 = wr[128 + c];
                s0 += w0 * as1[c];
                s1 += w1 * as1[128 + c];
                d0 += w0 * ad1[c];
                d1 += w1 * ad1[128 + c];
            }
            wsd[k] = s0; wsd[128 + k] = s1; wsd[256 + k] = d0; wsd[384 + k] = d1;
        }
        return;
    }
    int g = (blockIdx.x - 1) * 256 + threadIdx.x;
    const int stride = 128 * 256;
    for (int k = g; k < zwords; k += stride) zbase[k] = 0;
}

// ---- hist + DIRECT scatter + weight convert (incl. TRANSPOSED lwbT) + fused pre-pass ----
__global__ void k_hist_wconv(const int* __restrict__ ei, const int* __restrict__ flag,
                             int* __restrict__ deg, int* __restrict__ col, int e, int ebase,
                             const float* __restrict__ W1, __bf16* __restrict__ Wb1,
                             const float* __restrict__ W2, __bf16* __restrict__ Wb2,
                             const float* __restrict__ W3, __bf16* __restrict__ Wb3,
                             const float* __restrict__ lw, __bf16* __restrict__ lwbT,
                             const float* __restrict__ x, const float* __restrict__ wsd,
                             __bf16* __restrict__ xb, float* __restrict__ asp,
                             float* __restrict__ adp, int n) {
    int g = threadIdx.x + blockIdx.x * blockDim.x;
    if (g < e) {
        bool is64 = (*flag) != 0;
        int s = is64 ? ei[2 * g] : ei[g];
        int d = is64 ? ei[2 * (e + g)] : ei[e + g];
        int r = atomicAdd(&deg[(size_t)d * DEGS], 1);   // padded counter: 1 per 64B line
        if (r < CAP) col[((size_t)d << 7) + r] = s;
        return;
    }
    int idx = g - ebase;
    if (idx < 0) return;
    if (idx < 90112) {
        if (idx < 32768) {                      // W1: K=128, M=256
            int mm = idx >> 7, kk = idx & 127;
            Wb1[idx] = (__bf16)W1[(size_t)kk * 256 + mm];
        } else if (idx < 65536) {               // W2: K=256, M=128
            int i2 = idx - 32768;
            int mm = i2 >> 8, kk = i2 & 255;
            Wb2[i2] = (__bf16)W2[(size_t)kk * 128 + mm];
        } else if (idx < 81920) {               // W3: K=128, M=128
            int i3 = idx - 65536;
            int mm = i3 >> 7, kk = i3 & 127;
            Wb3[i3] = (__bf16)W3[(size_t)kk * 128 + mm];
        } else {                                // lw: [128][64] -> TRANSPOSED [64][128]
            int i4 = idx - 81920;
            int kk = i4 >> 6, cc = i4 & 63;
            lwbT[(size_t)cc * 128 + kk] = (__bf16)lw[i4];
        }
        return;
    }
    // ---- pre-pass region (whole blocks: e%256==0, 90112%256==0) ----
    int p = idx - 90112;
    __shared__ float ws[4][128];
    for (int i = threadIdx.x; i < 512; i += 256) ws[i >> 7][i & 127] = wsd[i];
    __syncthreads();
    const int lane = threadIdx.x & 63, widx = threadIdx.x >> 6;
    const int sub = lane & 7;
    const int node = (p >> 8) * 32 + widx * 8 + (lane >> 3);
    if (node >= n) return;
    const int c0 = sub * 16;
    const float* xp = x + (size_t)node * 128 + c0;
    float xv[16];
#pragma unroll
    for (int q = 0; q < 4; ++q) {
        float4 v = *reinterpret_cast<const float4*>(xp + q * 4);
        xv[q * 4 + 0] = v.x; xv[q * 4 + 1] = v.y; xv[q * 4 + 2] = v.z; xv[q * 4 + 3] = v.w;
    }
    float s0 = 0.f, s1 = 0.f, d0 = 0.f, d1 = 0.f;
#pragma unroll
    for (int i = 0; i < 16; ++i) {
        float xi = xv[i];
        int c = c0 + i;
        s0 += xi * ws[0][c]; s1 += xi * ws[1][c];
        d0 += xi * ws[2][c]; d1 += xi * ws[3][c];
    }
#pragma unroll
    for (int off = 1; off <= 4; off <<= 1) {
        s0 += __shfl_xor(s0, off); s1 += __shfl_xor(s1, off);
        d0 += __shfl_xor(d0, off); d1 += __shfl_xor(d1, off);
    }
    bf16x8 b0, b1;
#pragma unroll
    for (int i = 0; i < 8; ++i) { b0[i] = (__bf16)xv[i]; b1[i] = (__bf16)xv[8 + i]; }
    __bf16* po = xb + (size_t)node * 128 + c0;
    *reinterpret_cast<bf16x8*>(po) = b0;
    *reinterpret_cast<bf16x8*>(po + 8) = b1;
    if (sub == 0) {
        *reinterpret_cast<float2*>(asp + 2 * node) = make_float2(s0, s1);
        *reinterpret_cast<float2*>(adp + 2 * node) = make_float2(d0, d1);
    }
}

// ---- layer-1 aggregation in INPUT space, SPLIT slots ----
__global__ __launch_bounds__(256) void k_agg_in(const __bf16* __restrict__ xb,
                                                const float* __restrict__ asrc,
                                                const float* __restrict__ adst,
                                                const int* __restrict__ degv,
                                                const int* __restrict__ col,
                                                __bf16* __restrict__ aggv, int n) {
    __shared__ int sA[4][80];
    __shared__ float2 sW[4][80];
    const int widx = threadIdx.x >> 6;
    const int node = blockIdx.x * 4 + widx;
    const int lane = threadIdx.x & 63;
    if (node >= n) return;
    const int t = lane & 15;          // 16 lanes per edge, 8 ch each
    const int g = lane >> 4;          // 4 edges per wave-instr
    const int selfoff = node * 256;
    if (lane >= 48) { sA[widx][lane + 16] = selfoff; sW[widx][lane + 16] = make_float2(0.f, 0.f); }
    const char* xbt = (const char*)xb + t * 16;
    const int* crow = col + ((size_t)node << 7);
    const int deg = min(degv[(size_t)node * DEGS], CAP);
    const float2 adv = *reinterpret_cast<const float2*>(adst + 2 * node);
    const float2 asv = *reinterpret_cast<const float2*>(asrc + 2 * node);
    const float es0 = leaky(asv.x + adv.x), es1 = leaky(asv.y + adv.y);
    bf16x8 vself = *reinterpret_cast<const bf16x8*>(xbt + selfoff);  // early issue
    float a0[8] = {}, a1[8] = {};
    float d0 = 0.f, d1 = 0.f;
    for (int base = 0; base < deg; base += 64) {
        const int cnt = min(64, deg - base);
        int s = (lane < cnt) ? crow[base + lane] : node;
        sA[widx][lane] = s * 256;     // address available BEFORE exp chain completes
        float2 av = *reinterpret_cast<const float2*>(asrc + 2 * s);
        float w0 = 0.f, w1 = 0.f;
        if (lane < cnt) {
            w0 = __expf(leaky(av.x + adv.x));
            w1 = __expf(leaky(av.y + adv.y));
            d0 += w0; d1 += w1;
        }
        sW[widx][lane] = make_float2(w0, w1);
        for (int j = g; j < cnt; j += 16) {
            int o0 = sA[widx][j], o1 = sA[widx][j + 4], o2 = sA[widx][j + 8], o3 = sA[widx][j + 12];
            bf16x8 v0 = *reinterpret_cast<const bf16x8*>(xbt + o0);
            bf16x8 v1 = *reinterpret_cast<const bf16x8*>(xbt + o1);
            bf16x8 v2 = *reinterpret_cast<const bf16x8*>(xbt + o2);
            bf16x8 v3 = *reinterpret_cast<const bf16x8*>(xbt + o3);
            float2 x0 = sW[widx][j], x1 = sW[widx][j + 4], x2 = sW[widx][j + 8], x3 = sW[widx][j + 12];
#pragma unroll
            for (int q = 0; q < 8; ++q) {
                float f0 = (float)v0[q], f1 = (float)v1[q], f2 = (float)v2[q], f3 = (float)v3[q];
                a0[q] += x0.x * f0 + x1.x * f1 + x2.x * f2 + x3.x * f3;
                a1[q] += x0.y * f0 + x1.y * f1 + x2.y * f2 + x3.y * f3;
            }
        }
    }
#pragma unroll
    for (int off = 1; off <= 32; off <<= 1) {
        d0 += __shfl_xor(d0, off);
        d1 += __shfl_xor(d1, off);
    }
#pragma unroll
    for (int q = 0; q < 8; ++q) {
#pragma unroll
        for (int off = 16; off < 64; off <<= 1) {
            a0[q] += __shfl_xor(a0[q], off);
            a1[q] += __shfl_xor(a1[q], off);
        }
    }
    float exs0 = __expf(es0), exs1 = __expf(es1);
    d0 += exs0; d1 += exs1;
#pragma unroll
    for (int q = 0; q < 8; ++q) {
        a0[q] += exs0 * (float)vself[q];
        a1[q] += exs1 * (float)vself[q];
    }
    float i0 = 1.0f / (d0 + EPS_SM), i1 = 1.0f / (d1 + EPS_SM);
    if (g == 0) {
        bf16x8 st0, st1;
#pragma unroll
        for (int q = 0; q < 8; ++q) {
            st0[q] = (__bf16)(a0[q] * i0);
            st1[q] = (__bf16)(a1[q] * i1);
        }
        __bf16* po = aggv + (size_t)node * 256 + t * 8;
        *reinterpret_cast<bf16x8*>(po) = st0;
        *reinterpret_cast<bf16x8*>(po + 128) = st1;
    }
}

// ---- layer-1 post-GEMM with fused BN1 stats ----
__global__ __launch_bounds__(256) void k_gemm_ar(const __bf16* __restrict__ A,
                                                 const __bf16* __restrict__ Bt,
                                                 const float* __restrict__ bias,
                                                 __bf16* __restrict__ Cb,
                                                 float* __restrict__ bnsums, int n) {
    __shared__ __align__(16) __bf16 As[128][72];
    __shared__ __align__(16) __bf16 Bs[128][72];
    const int row0 = blockIdx.y * 128, col0 = blockIdx.x * 128;
    const int h = col0 >> 7;
    const int lane = threadIdx.x & 63, w = threadIdx.x >> 6;
    const int m = lane & 15, quad = lane >> 4;
    floatx4 acc[2][8];
#pragma unroll
    for (int i = 0; i < 2; ++i)
#pragma unroll
        for (int j = 0; j < 8; ++j) acc[i][j] = (floatx4)0.f;
    const int sr = threadIdx.x >> 1;
    const int sk = (threadIdx.x & 1) * 32;
    for (int kc = 0; kc < 128; kc += 64) {
        {
            int grow = row0 + sr;
            if (grow < n) {
                const __bf16* p = A + (size_t)grow * 256 + h * 128 + kc + sk;
#pragma unroll
                for (int q = 0; q < 4; ++q)
                    *reinterpret_cast<bf16x8*>(&As[sr][sk + q * 8]) =
                        *reinterpret_cast<const bf16x8*>(p + q * 8);
            } else {
#pragma unroll
                for (int q = 0; q < 4; ++q)
                    *reinterpret_cast<bf16x8*>(&As[sr][sk + q * 8]) = (bf16x8)(__bf16)0.f;
            }
        }
        {
            const __bf16* p = Bt + (size_t)(col0 + sr) * 128 + kc + sk;
#pragma unroll
            for (int q = 0; q < 4; ++q)
                *reinterpret_cast<bf16x8*>(&Bs[sr][sk + q * 8]) =
                    *reinterpret_cast<const bf16x8*>(p + q * 8);
        }
        __syncthreads();
#pragma unroll
        for (int ks = 0; ks < 64; ks += 32) {
            bf16x8 a0 = *reinterpret_cast<const bf16x8*>(&As[w * 32 + m][ks + quad * 8]);
            bf16x8 a1 = *reinterpret_cast<const bf16x8*>(&As[w * 32 + 16 + m][ks + quad * 8]);
#pragma unroll
            for (int nt = 0; nt < 8; ++nt) {
                bf16x8 b = *reinterpret_cast<const bf16x8*>(&Bs[nt * 16 + m][ks + quad * 8]);
                acc[0][nt] = __builtin_amdgcn_mfma_f32_16x16x32_bf16(a0, b, acc[0][nt], 0, 0, 0);
                acc[1][nt] = __builtin_amdgcn_mfma_f32_16x16x32_bf16(a1, b, acc[1][nt], 0, 0, 0);
            }
        }
        __syncthreads();
    }
    // epilogue: store relu + accumulate BN stats (As free after final k-loop sync)
    float* redS = reinterpret_cast<float*>(As);      // [4][128]
    float* redQ = redS + 512;                        // [4][128]
#pragma unroll
    for (int nt = 0; nt < 8; ++nt) {
        float bsv = bias[col0 + nt * 16 + m];
        float ssum = 0.f, ssq = 0.f;
#pragma unroll
        for (int mt = 0; mt < 2; ++mt)
#pragma unroll
            for (int r = 0; r < 4; ++r) {
                int row = row0 + w * 32 + mt * 16 + quad * 4 + r;
                float v = 0.f;
                if (row < n) {
                    v = fmaxf(acc[mt][nt][r] + bsv, 0.f);
                    Cb[(size_t)row * 256 + col0 + nt * 16 + m] = (__bf16)v;
                }
                ssum += v; ssq += v * v;
            }
        ssum += __shfl_xor(ssum, 16); ssum += __shfl_xor(ssum, 32);
        ssq  += __shfl_xor(ssq, 16);  ssq  += __shfl_xor(ssq, 32);
        if (quad == 0) {
            redS[w * 128 + nt * 16 + m] = ssum;
            redQ[w * 128 + nt * 16 + m] = ssq;
        }
    }
    __syncthreads();
    if (threadIdx.x < 128) {
        int c = threadIdx.x;
        float s = redS[c] + redS[128 + c] + redS[256 + c] + redS[384 + c];
        float q2 = redQ[c] + redQ[128 + c] + redQ[256 + c] + redQ[384 + c];
        atomicAdd(&bnsums[col0 + c], s);
        atomicAdd(&bnsums[256 + col0 + c], q2);
    }
}

// ---- bf16 MFMA GEMM (layers 2/3), inline BN prep + attn dots ----
template <int K, int LC, bool BF16IN, int NT>
__global__ __launch_bounds__(256) void k_gemm(const void* __restrict__ Ain,
                                              const __bf16* __restrict__ Bt,
                                              __bf16* __restrict__ Cb, int n, int M,
                                              const float* __restrict__ bnsums,
                                              const float* __restrict__ gam,
                                              const float* __restrict__ bet,
                                              const float* __restrict__ att_s,
                                              const float* __restrict__ att_d,
                                              float* __restrict__ asrc,
                                              float* __restrict__ adst) {
    __shared__ __align__(16) __bf16 As[128][72];
    __shared__ __align__(16) __bf16 Bs[NT * 16][72];
    __shared__ float sc_lds[K], sh_lds[K];
    const int row0 = blockIdx.y * 128, col0 = blockIdx.x * (NT * 16);
    const int lane = threadIdx.x & 63, w = threadIdx.x >> 6;
    const int m = lane & 15, quad = lane >> 4;

    if (bnsums) {
        for (int c = threadIdx.x; c < K; c += 256) {
            float mean = bnsums[c] / n;
            float var = bnsums[256 + c] / n - mean * mean;
            float sc = gam[c] * rsqrtf(var + EPS_BN);
            sc_lds[c] = sc;
            sh_lds[c] = bet[c] - mean * sc;
        }
        __syncthreads();
    }

    floatx4 acc[2][NT];
#pragma unroll
    for (int i = 0; i < 2; ++i)
#pragma unroll
        for (int j = 0; j < NT; ++j) acc[i][j] = (floatx4)0.f;

    const int sr = threadIdx.x >> 1;        // A-stage: 0..127
    const int sk = (threadIdx.x & 1) * 32;

    for (int kc = 0; kc < K; kc += 64) {
        {
            int grow = row0 + sr;
            if (grow < n) {
                if (BF16IN) {
                    const __bf16* p = (const __bf16*)Ain + (size_t)grow * K + kc + sk;
#pragma unroll
                    for (int q = 0; q < 4; ++q) {
                        bf16x8 vv = *reinterpret_cast<const bf16x8*>(p + q * 8);
                        if (bnsums) {
                            int c = kc + sk + q * 8;
                            bf16x8 r;
#pragma unroll
                            for (int e2 = 0; e2 < 8; ++e2)
                                r[e2] = (__bf16)((float)vv[e2] * sc_lds[c + e2] + sh_lds[c + e2]);
                            vv = r;
                        }
                        *reinterpret_cast<bf16x8*>(&As[sr][sk + q * 8]) = vv;
                    }
                } else {
                    const float* p = (const float*)Ain + (size_t)grow * K + kc + sk;
#pragma unroll
                    for (int q = 0; q < 8; ++q) {
                        float4 v = *reinterpret_cast<const float4*>(p + q * 4);
                        bf16x4 cv = {(__bf16)v.x, (__bf16)v.y, (__bf16)v.z, (__bf16)v.w};
                        *reinterpret_cast<bf16x4*>(&As[sr][sk + q * 4]) = cv;
                    }
                }
            } else {
#pragma unroll
                for (int q = 0; q < 4; ++q)
                    *reinterpret_cast<bf16x8*>(&As[sr][sk + q * 8]) = (bf16x8)(__bf16)0.f;
            }
        }
        if (NT == 8) {
            const __bf16* p = Bt + (size_t)(col0 + sr) * K + kc + sk;
#pragma unroll
            for (int q = 0; q < 4; ++q)
                *reinterpret_cast<bf16x8*>(&Bs[sr][sk + q * 8]) =
                    *reinterpret_cast<const bf16x8*>(p + q * 8);
        } else {  // NT==4: 64 B-rows, 16 bf16 per thread
            int sr4 = threadIdx.x >> 2, sk4 = (threadIdx.x & 3) * 16;
            const __bf16* p = Bt + (size_t)(col0 + sr4) * K + kc + sk4;
            *reinterpret_cast<bf16x8*>(&Bs[sr4][sk4]) = *reinterpret_cast<const bf16x8*>(p);
            *reinterpret_cast<bf16x8*>(&Bs[sr4][sk4 + 8]) = *reinterpret_cast<const bf16x8*>(p + 8);
        }
        __syncthreads();
#pragma unroll
        for (int ks = 0; ks < 64; ks += 32) {
            bf16x8 a0 = *reinterpret_cast<const bf16x8*>(&As[w * 32 + m][ks + quad * 8]);
            bf16x8 a1 = *reinterpret_cast<const bf16x8*>(&As[w * 32 + 16 + m][ks + quad * 8]);
#pragma unroll
            for (int nt = 0; nt < NT; ++nt) {
                bf16x8 b = *reinterpret_cast<const bf16x8*>(&Bs[nt * 16 + m][ks + quad * 8]);
                acc[0][nt] = __builtin_amdgcn_mfma_f32_16x16x32_bf16(a0, b, acc[0][nt], 0, 0, 0);
                acc[1][nt] = __builtin_amdgcn_mfma_f32_16x16x32_bf16(a1, b, acc[1][nt], 0, 0, 0);
            }
        }
        __syncthreads();
    }
#pragma unroll
    for (int mt = 0; mt < 2; ++mt)
#pragma unroll
        for (int nt = 0; nt < NT; ++nt)
#pragma unroll
            for (int r = 0; r < 4; ++r) {
                int row = row0 + w * 32 + mt * 16 + quad * 4 + r;
                if (row < n) Cb[(size_t)row * M + col0 + nt * 16 + m] = (__bf16)acc[mt][nt][r];
            }
    // fused attention dots (single complete head per block -> plain store)
    {
        float asv[NT], adv[NT];
#pragma unroll
        for (int nt = 0; nt < NT; ++nt) {
            int c = col0 + nt * 16 + m;
            asv[nt] = att_s[c];
            adv[nt] = att_d[c];
        }
        const int h = (col0 >> LC) & 1;
#pragma unroll
        for (int mt = 0; mt < 2; ++mt)
#pragma unroll
            for (int r = 0; r < 4; ++r) {
                int row = row0 + w * 32 + mt * 16 + quad * 4 + r;
                float pa = 0.f, pb = 0.f;
#pragma unroll
                for (int nt = 0; nt < NT; ++nt) {
                    float v = acc[mt][nt][r];
                    pa += v * asv[nt];
                    pb += v * adv[nt];
                }
#pragma unroll
                for (int off = 1; off <= 8; off <<= 1) {
                    pa += __shfl_xor(pa, off);
                    pb += __shfl_xor(pb, off);
                }
                if (m == 0 && row < n) {
                    asrc[2 * row + h] = pa;
                    adst[2 * row + h] = pb;
                }
            }
    }
}

// ---- GAT aggregation (layer 2): node-per-wave depth-4 + SPLIT slots ----
template <int C, bool OUTBF16>
__global__ __launch_bounds__(256) void k_agg(const __bf16* __restrict__ xh,
                                             const float* __restrict__ asrc,
                                             const float* __restrict__ adst,
                                             const int* __restrict__ degv,
                                             const int* __restrict__ col,
                                             const float* __restrict__ bias,
                                             void* __restrict__ outv, int n) {
    constexpr int F = 2 * C;          // bf16 per row (128)
    constexpr int G = F / 8;          // lanes per edge (16)
    constexpr int NG = 64 / G;        // edges per wave-step (4)
    constexpr int GSH = (G == 32) ? 5 : 4;
    __shared__ int sA[4][80];
    __shared__ float2 sW[4][80];
    const int widx = threadIdx.x >> 6;
    const int node = blockIdx.x * 4 + widx;
    const int lane = threadIdx.x & 63;
    if (node >= n) return;
    const int t = lane & (G - 1);
    const int g = lane >> GSH;
    const bool h1 = (t * 8) >= C;
    const int selfoff = node * (F * 2);
    if (lane >= 48) { sA[widx][lane + 16] = selfoff; sW[widx][lane + 16] = make_float2(0.f, 0.f); }
    const char* xbt = (const char*)xh + t * 16;
    const int* crow = col + ((size_t)node << 7);
    const int deg = min(degv[(size_t)node * DEGS], CAP);
    const float2 adv = *reinterpret_cast<const float2*>(adst + 2 * node);
    const float2 asv = *reinterpret_cast<const float2*>(asrc + 2 * node);
    const float es0 = leaky(asv.x + adv.x), es1 = leaky(asv.y + adv.y);
    bf16x8 vself = *reinterpret_cast<const bf16x8*>(xbt + selfoff);  // early issue
    float acc[8] = {};
    float d0 = 0.f, d1 = 0.f;
    for (int base = 0; base < deg; base += 64) {
        const int cnt = min(64, deg - base);
        int s = (lane < cnt) ? crow[base + lane] : node;
        sA[widx][lane] = s * (F * 2);
        float2 av = *reinterpret_cast<const float2*>(asrc + 2 * s);
        float w0 = 0.f, w1 = 0.f;
        if (lane < cnt) {
            w0 = __expf(leaky(av.x + adv.x));
            w1 = __expf(leaky(av.y + adv.y));
            d0 += w0; d1 += w1;
        }
        sW[widx][lane] = make_float2(w0, w1);
        for (int j = g; j < cnt; j += 4 * NG) {
            int o0 = sA[widx][j], o1 = sA[widx][j + NG], o2 = sA[widx][j + 2 * NG], o3 = sA[widx][j + 3 * NG];
            bf16x8 v0 = *reinterpret_cast<const bf16x8*>(xbt + o0);
            bf16x8 v1 = *reinterpret_cast<const bf16x8*>(xbt + o1);
            bf16x8 v2 = *reinterpret_cast<const bf16x8*>(xbt + o2);
            bf16x8 v3 = *reinterpret_cast<const bf16x8*>(xbt + o3);
            float2 x0 = sW[widx][j], x1 = sW[widx][j + NG], x2 = sW[widx][j + 2 * NG], x3 = sW[widx][j + 3 * NG];
            float w0 = h1 ? x0.y : x0.x;
            float w1 = h1 ? x1.y : x1.x;
            float w2 = h1 ? x2.y : x2.x;
            float w3 = h1 ? x3.y : x3.x;
#pragma unroll
            for (int q = 0; q < 8; ++q)
                acc[q] += w0 * (float)v0[q] + w1 * (float)v1[q] +
                          w2 * (float)v2[q] + w3 * (float)v3[q];
        }
    }
#pragma unroll
    for (int off = 1; off <= 32; off <<= 1) {
        d0 += __shfl_xor(d0, off);
        d1 += __shfl_xor(d1, off);
    }
#pragma unroll
    for (int q = 0; q < 8; ++q) {
#pragma unroll
        for (int off = G; off < 64; off <<= 1) acc[q] += __shfl_xor(acc[q], off);
    }
    float exs0 = __expf(es0), exs1 = __expf(es1);
    d0 += exs0; d1 += exs1;
    {
        float ws = h1 ? exs1 : exs0;
#pragma unroll
        for (int q = 0; q < 8; ++q) acc[q] += ws * (float)vself[q];
    }
    float inv = 1.0f / ((h1 ? d1 : d0) + EPS_SM);
    float o[8];
#pragma unroll
    for (int q = 0; q < 8; ++q) o[q] = fmaxf(acc[q] * inv + bias[t * 8 + q], 0.f);
    if (g == 0) {
        if constexpr (OUTBF16) {
            __bf16* po = (__bf16*)outv + (size_t)node * F + t * 8;
            bf16x8 st;
#pragma unroll
            for (int q = 0; q < 8; ++q) st[q] = (__bf16)o[q];
            *reinterpret_cast<bf16x8*>(po) = st;
        } else {
            float* po = (float*)outv + (size_t)node * F + t * 8;
            *reinterpret_cast<float4*>(po) = make_float4(o[0], o[1], o[2], o[3]);
            *reinterpret_cast<float4*>(po + 4) = make_float4(o[4], o[5], o[6], o[7]);
        }
    }
}

// ---- layer-3 aggregation + FUSED final linear via MFMA (vectorized staging):
//      lwbT is pre-transposed [64][128] -> Bls staging is a linear bf16x8 copy
//      (1024 chunks: 64 rows x 16 chunks); A-tile zero is 1 bf16x8/thread.
__global__ __launch_bounds__(256) void k_agg_lin(const __bf16* __restrict__ xh,
                                                 const float* __restrict__ asrc,
                                                 const float* __restrict__ adst,
                                                 const int* __restrict__ degv,
                                                 const int* __restrict__ col,
                                                 const float* __restrict__ bias,
                                                 const __bf16* __restrict__ lwbT,
                                                 const float* __restrict__ lb,
                                                 float* __restrict__ out, int n) {
    constexpr int C = 64, F = 128, G = 16;
    __shared__ int sA[4][80];
    __shared__ float2 sW[4][80];
    __shared__ __align__(16) __bf16 Ahi[16][136];
    __shared__ __align__(16) __bf16 Alo[16][136];
    __shared__ __align__(16) __bf16 Bls[64][136];   // lw transposed: [c][k]
    // cooperative staging (vectorized) + A-tile zero, before any divergence
    for (int i = threadIdx.x; i < 1024; i += 256) {       // 1024 x 16B chunks of lwbT
        int c = i >> 4, k8 = (i & 15) * 8;
        *reinterpret_cast<bf16x8*>(&Bls[c][k8]) =
            *reinterpret_cast<const bf16x8*>(lwbT + c * 128 + k8);
    }
    {
        int i = threadIdx.x;                               // 256 chunks: 16 rows x 128 cols
        int r = i >> 4, c8 = (i & 15) * 8;
        *reinterpret_cast<bf16x8*>(&Ahi[r][c8]) = (bf16x8)(__bf16)0.f;
        *reinterpret_cast<bf16x8*>(&Alo[r][c8]) = (bf16x8)(__bf16)0.f;
    }
    __syncthreads();
    const int widx = threadIdx.x >> 6;
    const int node = blockIdx.x * 4 + widx;
    const int lane = threadIdx.x & 63;
    const bool valid = node < n;
    const int nodec = valid ? node : 0;
    const int t = lane & (G - 1);
    const int g = lane >> 4;
    const bool h1 = (t * 8) >= C;
    const int selfoff = nodec * (F * 2);
    if (lane >= 48) { sA[widx][lane + 16] = selfoff; sW[widx][lane + 16] = make_float2(0.f, 0.f); }
    const char* xbt = (const char*)xh + t * 16;
    const int* crow = col + ((size_t)nodec << 7);
    const int deg = valid ? min(degv[(size_t)nodec * DEGS], CAP) : 0;
    const float2 adv = *reinterpret_cast<const float2*>(adst + 2 * nodec);
    const float2 asv = *reinterpret_cast<const float2*>(asrc + 2 * nodec);
    const float es0 = leaky(asv.x + adv.x), es1 = leaky(asv.y + adv.y);
    bf16x8 vself = *reinterpret_cast<const bf16x8*>(xbt + selfoff);
    float acc[8] = {};
    float d0 = 0.f, d1 = 0.f;
    for (int base = 0; base < deg; base += 64) {
        const int cnt = min(64, deg - base);
        int s = (lane < cnt) ? crow[base + lane] : nodec;
        sA[widx][lane] = s * (F * 2);
        float2 av = *reinterpret_cast<const float2*>(asrc + 2 * s);
        float w0 = 0.f, w1 = 0.f;
        if (lane < cnt) {
            w0 = __expf(leaky(av.x + adv.x));
            w1 = __expf(leaky(av.y + adv.y));
            d0 += w0; d1 += w1;
        }
        sW[widx][lane] = make_float2(w0, w1);
        for (int j = g; j < cnt; j += 16) {
            int o0 = sA[widx][j], o1 = sA[widx][j + 4], o2 = sA[widx][j + 8], o3 = sA[widx][j + 12];
            bf16x8 v0 = *reinterpret_cast<const bf16x8*>(xbt + o0);
            bf16x8 v1 = *reinterpret_cast<const bf16x8*>(xbt + o1);
            bf16x8 v2 = *reinterpret_cast<const bf16x8*>(xbt + o2);
            bf16x8 v3 = *reinterpret_cast<const bf16x8*>(xbt + o3);
            float2 x0 = sW[widx][j], x1 = sW[widx][j + 4], x2 = sW[widx][j + 8], x3 = sW[widx][j + 12];
            float w0 = h1 ? x0.y : x0.x;
            float w1 = h1 ? x1.y : x1.x;
            float w2 = h1 ? x2.y : x2.x;
            float w3 = h1 ? x3.y : x3.x;
#pragma unroll
            for (int q = 0; q < 8; ++q)
                acc[q] += w0 * (float)v0[q] + w1 * (float)v1[q] +
                          w2 * (float)v2[q] + w3 * (float)v3[q];
        }
    }
#pragma unroll
    for (int off = 1; off <= 32; off <<= 1) {
        d0 += __shfl_xor(d0, off);
        d1 += __shfl_xor(d1, off);
    }
#pragma unroll
    for (int q = 0; q < 8; ++q) {
#pragma unroll
        for (int off = G; off < 64; off <<= 1) acc[q] += __shfl_xor(acc[q], off);
    }
    float exs0 = __expf(es0), exs1 = __expf(es1);
    d0 += exs0; d1 += exs1;
    {
        float ws = h1 ? exs1 : exs0;
#pragma unroll
        for (int q = 0; q < 8; ++q) acc[q] += ws * (float)vself[q];
    }
    float inv = 1.0f / ((h1 ? d1 : d0) + EPS_SM);
    // h3 row (relu'd, f32) -> hi/lo bf16 into A-tile row widx
    if (g == 0 && valid) {
#pragma unroll
        for (int q = 0; q < 8; ++q) {
            float v = fmaxf(acc[q] * inv + bias[t * 8 + q], 0.f);
            __bf16 hi = (__bf16)v;
            Ahi[widx][t * 8 + q] = hi;
            Alo[widx][t * 8 + q] = (__bf16)(v - (float)hi);
        }
    }
    __syncthreads();
    // MFMA: wave widx computes cols widx*16..+15 for all 4 node-rows
    const int m = lane & 15, quad = lane >> 4;
    floatx4 oacc = (floatx4)0.f;
#pragma unroll
    for (int ks = 0; ks < 128; ks += 32) {
        bf16x8 ah = *reinterpret_cast<const bf16x8*>(&Ahi[m][ks + quad * 8]);
        bf16x8 al = *reinterpret_cast<const bf16x8*>(&Alo[m][ks + quad * 8]);
        bf16x8 b  = *reinterpret_cast<const bf16x8*>(&Bls[widx * 16 + m][ks + quad * 8]);
        oacc = __builtin_amdgcn_mfma_f32_16x16x32_bf16(ah, b, oacc, 0, 0, 0);
        oacc = __builtin_amdgcn_mfma_f32_16x16x32_bf16(al, b, oacc, 0, 0, 0);
    }
    // C layout: col = widx*16 + m, row = quad*4 + r; rows 0..3 = block's nodes
    if (quad == 0) {
        int c = widx * 16 + m;
        float lbv = lb[c];
#pragma unroll
        for (int r = 0; r < 4; ++r) {
            int nd = blockIdx.x * 4 + r;
            if (nd < n) out[(size_t)nd * 64 + c] = oacc[r] + lbv;
        }
    }
}

// ---------------- BatchNorm stats (layer 2 only; 256 blocks = low contention) ----
template <typename T>
__global__ void k_bn_stats(const T* __restrict__ x, float* __restrict__ sums,
                           float* __restrict__ sqs, int n, int f) {
    int c = threadIdx.x;
    float s = 0.f, q = 0.f;
    for (int r = blockIdx.x; r < n; r += gridDim.x) {
        float v = (float)x[(size_t)r * f + c];
        s += v; q += v * v;
    }
    atomicAdd(&sums[c], s);
    atomicAdd(&sqs[c], q);
}

// ---------------- launch ----------------
extern "C" void kernel_launch(void* const* d_in, const int* in_sizes, int n_in,
                              void* d_out, int out_size, void* d_ws, size_t ws_size,
                              hipStream_t stream) {
    const float* x   = (const float*)d_in[0];
    const int*   ei  = (const int*)d_in[1];
    const float* W1  = (const float*)d_in[2];
    const float* as1 = (const float*)d_in[3];
    const float* ad1 = (const float*)d_in[4];
    const float* b1  = (const float*)d_in[5];
    const float* g1  = (const float*)d_in[6];
    const float* be1 = (const float*)d_in[7];
    const float* W2  = (const float*)d_in[8];
    const float* as2 = (const float*)d_in[9];
    const float* ad2 = (const float*)d_in[10];
    const float* b2  = (const float*)d_in[11];
    const float* g2  = (const float*)d_in[12];
    const float* be2 = (const float*)d_in[13];
    const float* W3  = (const float*)d_in[14];
    const float* as3 = (const float*)d_in[15];
    const float* ad3 = (const float*)d_in[16];
    const float* b3  = (const float*)d_in[17];
    const float* lw  = (const float*)d_in[18];
    const float* lb  = (const float*)d_in[19];
    float* outp = (float*)d_out;

    const int n = in_sizes[0] / 128;  // 50000
    const int e = in_sizes[1] / 2;    // 800000

    char* w = (char*)d_ws;
    size_t off = 0;
    auto alloc = [&](size_t bytes) -> void* {
        void* p = w + off;
        off += (bytes + 255) & ~(size_t)255;
        return p;
    };
    __bf16* xhb = (__bf16*)alloc((size_t)n * 256 * 2);  // layer-1 agg out; later xh2/xh3
    __bf16* h1b = (__bf16*)alloc((size_t)n * 256 * 2);
    __bf16* h2b = (__bf16*)alloc((size_t)n * 128 * 2);
    int* colb   = (int*)alloc((size_t)n * CAP * 4);  // padded adjacency (25.6 MB)
    __bf16* xb  = (__bf16*)alloc((size_t)n * 128 * 2);  // bf16 copy of x (12.8 MB)
    __bf16* Wb1 = (__bf16*)alloc(256 * 128 * 2);
    __bf16* Wb2 = (__bf16*)alloc(128 * 256 * 2);
    __bf16* Wb3 = (__bf16*)alloc(128 * 128 * 2);
    __bf16* lwbT = (__bf16*)alloc(64 * 128 * 2);     // transposed [c][k]
    float* wsd  = (float*)alloc(512 * 4);
    int* flag   = (int*)alloc(256);
    float* as1p = (float*)alloc((size_t)n * 2 * 4);
    float* ad1p = (float*)alloc((size_t)n * 2 * 4);
    float* as2p = (float*)alloc((size_t)n * 2 * 4);
    float* ad2p = (float*)alloc((size_t)n * 2 * 4);
    float* as3p = (float*)alloc((size_t)n * 2 * 4);
    float* ad3p = (float*)alloc((size_t)n * 2 * 4);
    // ---- contiguous zero block ----
    char* zb_begin = (char*)(w + off);
    int* deg    = (int*)alloc((size_t)n * DEGS * 4);  // line-padded counters (3.2 MB)
    float* bn1  = (float*)alloc(512 * 4);
    float* bn2  = (float*)alloc(512 * 4);
    char* zb_end = (char*)(w + off);
    const int zwords = (int)((zb_end - zb_begin) / 4);

    // init: detect (block 0) + zero (blocks 1..128) + wsd projection (block 129)
    k_init<<<130, 256, 0, stream>>>(ei, flag, (int*)zb_begin, zwords, e, W1, as1, ad1, wsd);

    const int ebase = ((e + 255) / 256) * 256;
    const int preblocks = (n + 31) / 32;
    const int histblocks = ebase / 256 + 352 + preblocks;  // edges + wconv(+lwbT) + pre-pass
    k_hist_wconv<<<histblocks, 256, 0, stream>>>(ei, flag, deg, colb, e, ebase,
                                                 W1, Wb1, W2, Wb2, W3, Wb3,
                                                 lw, lwbT, x, wsd, xb, as1p, ad1p, n);

    const int nwb = (n + 3) / 4;
    const int nrow = (n + 127) / 128;

    // ---- layer 1: input-space aggregation, then GEMM (+fused BN1 stats) ----
    k_agg_in<<<nwb, 256, 0, stream>>>(xb, as1p, ad1p, deg, colb, xhb, n);
    k_gemm_ar<<<dim3(2, nrow), 256, 0, stream>>>(xhb, Wb1, b1, h1b, bn1, n);

    // ---- layer 2: 256 -> 2x64 (BN1 inline in GEMM prologue; 64-col tiles) ----
    k_gemm<256, 6, true, 4><<<dim3(2, nrow), 256, 0, stream>>>(
        h1b, Wb2, xhb, n, 128, bn1, g1, be1, as2, ad2, as2p, ad2p);
    k_agg<64, true><<<nwb, 256, 0, stream>>>(xhb, as2p, ad2p, deg, colb, b2, h2b, n);
    k_bn_stats<__bf16><<<256, 128, 0, stream>>>(h2b, bn2, bn2 + 256, n, 128);

    // ---- layer 3: 128 -> 2x64 (BN2 inline) + MFMA-fused final linear ----
    k_gemm<128, 6, true, 4><<<dim3(2, nrow), 256, 0, stream>>>(
        h2b, Wb3, xhb, n, 128, bn2, g2, be2, as3, ad3, as3p, ad3p);
    k_agg_lin<<<nwb, 256, 0, stream>>>(xhb, as3p, ad3p, deg, colb, b3, lwbT, lb, outp, n);
}

// Round 16
// 431.600 us; speedup vs baseline: 1.0758x; 1.0224x over previous
//
#include <hip/hip_runtime.h>
#include <hip/hip_bf16.h>

#define NEG_SLOPE 0.2f
#define EPS_BN 1e-5f
#define EPS_SM 1e-16f
#define CAP 128   // padded adjacency row capacity (Poisson(17): P(deg>128) ~ 0; clamped anyway)
#define DEGS 16   // deg counter stride (ints): one counter per 64B line

typedef __bf16 bf16x8 __attribute__((ext_vector_type(8)));
typedef __bf16 bf16x4 __attribute__((ext_vector_type(4)));
typedef float floatx4 __attribute__((ext_vector_type(4)));

__device__ __forceinline__ float leaky(float x) { return x > 0.f ? x : NEG_SLOPE * x; }

// ---- init: block 0 = edge dtype detect; blocks 1..128 = zero; block 129 = wsd ----
// wsd[j][k], j in {src_h0, src_h1, dst_h0, dst_h1}: wsd_s[h][k] = sum_c W1[k, h*128+c]*att[h,c]
__global__ void k_init(const int* __restrict__ ei, int* __restrict__ flag,
                       int* __restrict__ zbase, int zwords, int e,
                       const float* __restrict__ W1, const float* __restrict__ as1,
                       const float* __restrict__ ad1, float* __restrict__ wsd) {
    if (blockIdx.x == 0) {
        __shared__ int cnt_s[256];
        int i = threadIdx.x;  // pairs 0..255
        int nz = (2 * i + 1 < 2 * e && ei[2 * i + 1] != 0) ? 1 : 0;
        cnt_s[i] = nz;
        __syncthreads();
        for (int off = 128; off > 0; off >>= 1) {
            if (i < off) cnt_s[i] += cnt_s[i + off];
            __syncthreads();
        }
        if (i == 0) *flag = (cnt_s[0] < 128) ? 1 : 0;  // 1 => int64 layout
        return;
    }
    if (blockIdx.x == 129) {
        int k = threadIdx.x;
        if (k < 128) {
            const float* wr = W1 + (size_t)k * 256;
            float s0 = 0.f, s1 = 0.f, d0 = 0.f, d1 = 0.f;
            for (int c = 0; c < 128; ++c) {
                float w0 = wr[c], w1 = wr[128 + c];
                s0 += w0 * as1[c];
                s1 += w1 * as1[128 + c];
                d0 += w0 * ad1[c];
                d1 += w1 * ad1[128 + c];
            }
            wsd[k] = s0; wsd[128 + k] = s1; wsd[256 + k] = d0; wsd[384 + k] = d1;
        }
        return;
    }
    int g = (blockIdx.x - 1) * 256 + threadIdx.x;
    const int stride = 128 * 256;
    for (int k = g; k < zwords; k += stride) zbase[k] = 0;
}

// ---- hist + DIRECT scatter + weight convert + (fused) layer-1 pre-pass in grid tail ----
// pre-pass: xb = bf16(x); attention dots directly from x via wsd (overlaps with hist)
__global__ void k_hist_wconv(const int* __restrict__ ei, const int* __restrict__ flag,
                             int* __restrict__ deg, int* __restrict__ col, int e, int ebase,
                             const float* __restrict__ W1, __bf16* __restrict__ Wb1,
                             const float* __restrict__ W2, __bf16* __restrict__ Wb2,
                             const float* __restrict__ W3, __bf16* __restrict__ Wb3,
                             const float* __restrict__ x, const float* __restrict__ wsd,
                             __bf16* __restrict__ xb, float* __restrict__ asp,
                             float* __restrict__ adp, int n) {
    int g = threadIdx.x + blockIdx.x * blockDim.x;
    if (g < e) {
        bool is64 = (*flag) != 0;
        int s = is64 ? ei[2 * g] : ei[g];
        int d = is64 ? ei[2 * (e + g)] : ei[e + g];
        int r = atomicAdd(&deg[(size_t)d * DEGS], 1);   // padded counter: 1 per 64B line
        if (r < CAP) col[((size_t)d << 7) + r] = s;
        return;
    }
    int idx = g - ebase;
    if (idx < 0) return;
    if (idx < 81920) {
        if (idx < 32768) {                      // W1: K=128, M=256
            int mm = idx >> 7, kk = idx & 127;
            Wb1[idx] = (__bf16)W1[(size_t)kk * 256 + mm];
        } else if (idx < 65536) {               // W2: K=256, M=128
            int i2 = idx - 32768;
            int mm = i2 >> 8, kk = i2 & 255;
            Wb2[i2] = (__bf16)W2[(size_t)kk * 128 + mm];
        } else {                                // W3: K=128, M=128
            int i3 = idx - 65536;
            int mm = i3 >> 7, kk = i3 & 127;
            Wb3[i3] = (__bf16)W3[(size_t)kk * 128 + mm];
        }
        return;
    }
    // ---- pre-pass region (whole blocks: e%256==0, 81920%256==0) ----
    int p = idx - 81920;
    __shared__ float ws[4][128];
    for (int i = threadIdx.x; i < 512; i += 256) ws[i >> 7][i & 127] = wsd[i];
    __syncthreads();
    const int lane = threadIdx.x & 63, widx = threadIdx.x >> 6;
    const int sub = lane & 7;
    const int node = (p >> 8) * 32 + widx * 8 + (lane >> 3);
    if (node >= n) return;
    const int c0 = sub * 16;
    const float* xp = x + (size_t)node * 128 + c0;
    float xv[16];
#pragma unroll
    for (int q = 0; q < 4; ++q) {
        float4 v = *reinterpret_cast<const float4*>(xp + q * 4);
        xv[q * 4 + 0] = v.x; xv[q * 4 + 1] = v.y; xv[q * 4 + 2] = v.z; xv[q * 4 + 3] = v.w;
    }
    float s0 = 0.f, s1 = 0.f, d0 = 0.f, d1 = 0.f;
#pragma unroll
    for (int i = 0; i < 16; ++i) {
        float xi = xv[i];
        int c = c0 + i;
        s0 += xi * ws[0][c]; s1 += xi * ws[1][c];
        d0 += xi * ws[2][c]; d1 += xi * ws[3][c];
    }
#pragma unroll
    for (int off = 1; off <= 4; off <<= 1) {
        s0 += __shfl_xor(s0, off); s1 += __shfl_xor(s1, off);
        d0 += __shfl_xor(d0, off); d1 += __shfl_xor(d1, off);
    }
    bf16x8 b0, b1;
#pragma unroll
    for (int i = 0; i < 8; ++i) { b0[i] = (__bf16)xv[i]; b1[i] = (__bf16)xv[8 + i]; }
    __bf16* po = xb + (size_t)node * 128 + c0;
    *reinterpret_cast<bf16x8*>(po) = b0;
    *reinterpret_cast<bf16x8*>(po + 8) = b1;
    if (sub == 0) {
        *reinterpret_cast<float2*>(asp + 2 * node) = make_float2(s0, s1);
        *reinterpret_cast<float2*>(adp + 2 * node) = make_float2(d0, d1);
    }
}

// ---- layer-1 aggregation in INPUT space, SPLIT slots: addresses (sA) written
//      before exp so row gathers overlap the asrc gather + exp chain; weights (sW)
//      written after. Both heads per wave. ----
__global__ __launch_bounds__(256) void k_agg_in(const __bf16* __restrict__ xb,
                                                const float* __restrict__ asrc,
                                                const float* __restrict__ adst,
                                                const int* __restrict__ degv,
                                                const int* __restrict__ col,
                                                __bf16* __restrict__ aggv, int n) {
    __shared__ int sA[4][80];
    __shared__ float2 sW[4][80];
    const int widx = threadIdx.x >> 6;
    const int node = blockIdx.x * 4 + widx;
    const int lane = threadIdx.x & 63;
    if (node >= n) return;
    const int t = lane & 15;          // 16 lanes per edge, 8 ch each
    const int g = lane >> 4;          // 4 edges per wave-instr
    const int selfoff = node * 256;
    if (lane >= 48) { sA[widx][lane + 16] = selfoff; sW[widx][lane + 16] = make_float2(0.f, 0.f); }
    const char* xbt = (const char*)xb + t * 16;
    const int* crow = col + ((size_t)node << 7);
    const int deg = min(degv[(size_t)node * DEGS], CAP);
    const float2 adv = *reinterpret_cast<const float2*>(adst + 2 * node);
    const float2 asv = *reinterpret_cast<const float2*>(asrc + 2 * node);
    const float es0 = leaky(asv.x + adv.x), es1 = leaky(asv.y + adv.y);
    bf16x8 vself = *reinterpret_cast<const bf16x8*>(xbt + selfoff);  // early issue
    float a0[8] = {}, a1[8] = {};
    float d0 = 0.f, d1 = 0.f;
    for (int base = 0; base < deg; base += 64) {
        const int cnt = min(64, deg - base);
        int s = (lane < cnt) ? crow[base + lane] : node;
        sA[widx][lane] = s * 256;     // address available BEFORE exp chain completes
        float2 av = *reinterpret_cast<const float2*>(asrc + 2 * s);
        float w0 = 0.f, w1 = 0.f;
        if (lane < cnt) {
            w0 = __expf(leaky(av.x + adv.x));
            w1 = __expf(leaky(av.y + adv.y));
            d0 += w0; d1 += w1;
        }
        sW[widx][lane] = make_float2(w0, w1);
        for (int j = g; j < cnt; j += 16) {
            int o0 = sA[widx][j], o1 = sA[widx][j + 4], o2 = sA[widx][j + 8], o3 = sA[widx][j + 12];
            bf16x8 v0 = *reinterpret_cast<const bf16x8*>(xbt + o0);
            bf16x8 v1 = *reinterpret_cast<const bf16x8*>(xbt + o1);
            bf16x8 v2 = *reinterpret_cast<const bf16x8*>(xbt + o2);
            bf16x8 v3 = *reinterpret_cast<const bf16x8*>(xbt + o3);
            float2 x0 = sW[widx][j], x1 = sW[widx][j + 4], x2 = sW[widx][j + 8], x3 = sW[widx][j + 12];
#pragma unroll
            for (int q = 0; q < 8; ++q) {
                float f0 = (float)v0[q], f1 = (float)v1[q], f2 = (float)v2[q], f3 = (float)v3[q];
                a0[q] += x0.x * f0 + x1.x * f1 + x2.x * f2 + x3.x * f3;
                a1[q] += x0.y * f0 + x1.y * f1 + x2.y * f2 + x3.y * f3;
            }
        }
    }
#pragma unroll
    for (int off = 1; off <= 32; off <<= 1) {
        d0 += __shfl_xor(d0, off);
        d1 += __shfl_xor(d1, off);
    }
#pragma unroll
    for (int q = 0; q < 8; ++q) {
#pragma unroll
        for (int off = 16; off < 64; off <<= 1) {
            a0[q] += __shfl_xor(a0[q], off);
            a1[q] += __shfl_xor(a1[q], off);
        }
    }
    float exs0 = __expf(es0), exs1 = __expf(es1);
    d0 += exs0; d1 += exs1;
#pragma unroll
    for (int q = 0; q < 8; ++q) {
        a0[q] += exs0 * (float)vself[q];
        a1[q] += exs1 * (float)vself[q];
    }
    float i0 = 1.0f / (d0 + EPS_SM), i1 = 1.0f / (d1 + EPS_SM);
    if (g == 0) {
        bf16x8 st0, st1;
#pragma unroll
        for (int q = 0; q < 8; ++q) {
            st0[q] = (__bf16)(a0[q] * i0);
            st1[q] = (__bf16)(a1[q] * i1);
        }
        __bf16* po = aggv + (size_t)node * 256 + t * 8;
        *reinterpret_cast<bf16x8*>(po) = st0;
        *reinterpret_cast<bf16x8*>(po + 128) = st1;
    }
}

// ---- layer-1 post-GEMM with fused BN1 stats: h1 = relu(agg @ W1_h + b1); atomically
//      accumulates per-column sum/sumsq into bnsums (replaces separate bn_stats pass) ----
__global__ __launch_bounds__(256) void k_gemm_ar(const __bf16* __restrict__ A,
                                                 const __bf16* __restrict__ Bt,
                                                 const float* __restrict__ bias,
                                                 __bf16* __restrict__ Cb,
                                                 float* __restrict__ bnsums, int n) {
    __shared__ __align__(16) __bf16 As[128][72];
    __shared__ __align__(16) __bf16 Bs[128][72];
    const int row0 = blockIdx.y * 128, col0 = blockIdx.x * 128;
    const int h = col0 >> 7;
    const int lane = threadIdx.x & 63, w = threadIdx.x >> 6;
    const int m = lane & 15, quad = lane >> 4;
    floatx4 acc[2][8];
#pragma unroll
    for (int i = 0; i < 2; ++i)
#pragma unroll
        for (int j = 0; j < 8; ++j) acc[i][j] = (floatx4)0.f;
    const int sr = threadIdx.x >> 1;
    const int sk = (threadIdx.x & 1) * 32;
    for (int kc = 0; kc < 128; kc += 64) {
        {
            int grow = row0 + sr;
            if (grow < n) {
                const __bf16* p = A + (size_t)grow * 256 + h * 128 + kc + sk;
#pragma unroll
                for (int q = 0; q < 4; ++q)
                    *reinterpret_cast<bf16x8*>(&As[sr][sk + q * 8]) =
                        *reinterpret_cast<const bf16x8*>(p + q * 8);
            } else {
#pragma unroll
                for (int q = 0; q < 4; ++q)
                    *reinterpret_cast<bf16x8*>(&As[sr][sk + q * 8]) = (bf16x8)(__bf16)0.f;
            }
        }
        {
            const __bf16* p = Bt + (size_t)(col0 + sr) * 128 + kc + sk;
#pragma unroll
            for (int q = 0; q < 4; ++q)
                *reinterpret_cast<bf16x8*>(&Bs[sr][sk + q * 8]) =
                    *reinterpret_cast<const bf16x8*>(p + q * 8);
        }
        __syncthreads();
#pragma unroll
        for (int ks = 0; ks < 64; ks += 32) {
            bf16x8 a0 = *reinterpret_cast<const bf16x8*>(&As[w * 32 + m][ks + quad * 8]);
            bf16x8 a1 = *reinterpret_cast<const bf16x8*>(&As[w * 32 + 16 + m][ks + quad * 8]);
#pragma unroll
            for (int nt = 0; nt < 8; ++nt) {
                bf16x8 b = *reinterpret_cast<const bf16x8*>(&Bs[nt * 16 + m][ks + quad * 8]);
                acc[0][nt] = __builtin_amdgcn_mfma_f32_16x16x32_bf16(a0, b, acc[0][nt], 0, 0, 0);
                acc[1][nt] = __builtin_amdgcn_mfma_f32_16x16x32_bf16(a1, b, acc[1][nt], 0, 0, 0);
            }
        }
        __syncthreads();
    }
    // epilogue: store relu + accumulate BN stats (As free after final k-loop sync)
    float* redS = reinterpret_cast<float*>(As);      // [4][128]
    float* redQ = redS + 512;                        // [4][128]
#pragma unroll
    for (int nt = 0; nt < 8; ++nt) {
        float bsv = bias[col0 + nt * 16 + m];
        float ssum = 0.f, ssq = 0.f;
#pragma unroll
        for (int mt = 0; mt < 2; ++mt)
#pragma unroll
            for (int r = 0; r < 4; ++r) {
                int row = row0 + w * 32 + mt * 16 + quad * 4 + r;
                float v = 0.f;
                if (row < n) {
                    v = fmaxf(acc[mt][nt][r] + bsv, 0.f);
                    Cb[(size_t)row * 256 + col0 + nt * 16 + m] = (__bf16)v;
                }
                ssum += v; ssq += v * v;
            }
        ssum += __shfl_xor(ssum, 16); ssum += __shfl_xor(ssum, 32);
        ssq  += __shfl_xor(ssq, 16);  ssq  += __shfl_xor(ssq, 32);
        if (quad == 0) {
            redS[w * 128 + nt * 16 + m] = ssum;
            redQ[w * 128 + nt * 16 + m] = ssq;
        }
    }
    __syncthreads();
    if (threadIdx.x < 128) {
        int c = threadIdx.x;
        float s = redS[c] + redS[128 + c] + redS[256 + c] + redS[384 + c];
        float q2 = redQ[c] + redQ[128 + c] + redQ[256 + c] + redQ[384 + c];
        atomicAdd(&bnsums[col0 + c], s);
        atomicAdd(&bnsums[256 + col0 + c], q2);
    }
}

// ---- bf16 MFMA GEMM (layers 2/3), inline BN prep + attn dots ----
template <int K, int LC, bool BF16IN, int NT>
__global__ __launch_bounds__(256) void k_gemm(const void* __restrict__ Ain,
                                              const __bf16* __restrict__ Bt,
                                              __bf16* __restrict__ Cb, int n, int M,
                                              const float* __restrict__ bnsums,
                                              const float* __restrict__ gam,
                                              const float* __restrict__ bet,
                                              const float* __restrict__ att_s,
                                              const float* __restrict__ att_d,
                                              float* __restrict__ asrc,
                                              float* __restrict__ adst) {
    __shared__ __align__(16) __bf16 As[128][72];
    __shared__ __align__(16) __bf16 Bs[NT * 16][72];
    __shared__ float sc_lds[K], sh_lds[K];
    const int row0 = blockIdx.y * 128, col0 = blockIdx.x * (NT * 16);
    const int lane = threadIdx.x & 63, w = threadIdx.x >> 6;
    const int m = lane & 15, quad = lane >> 4;

    if (bnsums) {
        for (int c = threadIdx.x; c < K; c += 256) {
            float mean = bnsums[c] / n;
            float var = bnsums[256 + c] / n - mean * mean;
            float sc = gam[c] * rsqrtf(var + EPS_BN);
            sc_lds[c] = sc;
            sh_lds[c] = bet[c] - mean * sc;
        }
        __syncthreads();
    }

    floatx4 acc[2][NT];
#pragma unroll
    for (int i = 0; i < 2; ++i)
#pragma unroll
        for (int j = 0; j < NT; ++j) acc[i][j] = (floatx4)0.f;

    const int sr = threadIdx.x >> 1;        // A-stage: 0..127
    const int sk = (threadIdx.x & 1) * 32;

    for (int kc = 0; kc < K; kc += 64) {
        {
            int grow = row0 + sr;
            if (grow < n) {
                if (BF16IN) {
                    const __bf16* p = (const __bf16*)Ain + (size_t)grow * K + kc + sk;
#pragma unroll
                    for (int q = 0; q < 4; ++q) {
                        bf16x8 vv = *reinterpret_cast<const bf16x8*>(p + q * 8);
                        if (bnsums) {
                            int c = kc + sk + q * 8;
                            bf16x8 r;
#pragma unroll
                            for (int e2 = 0; e2 < 8; ++e2)
                                r[e2] = (__bf16)((float)vv[e2] * sc_lds[c + e2] + sh_lds[c + e2]);
                            vv = r;
                        }
                        *reinterpret_cast<bf16x8*>(&As[sr][sk + q * 8]) = vv;
                    }
                } else {
                    const float* p = (const float*)Ain + (size_t)grow * K + kc + sk;
#pragma unroll
                    for (int q = 0; q < 8; ++q) {
                        float4 v = *reinterpret_cast<const float4*>(p + q * 4);
                        bf16x4 cv = {(__bf16)v.x, (__bf16)v.y, (__bf16)v.z, (__bf16)v.w};
                        *reinterpret_cast<bf16x4*>(&As[sr][sk + q * 4]) = cv;
                    }
                }
            } else {
#pragma unroll
                for (int q = 0; q < 4; ++q)
                    *reinterpret_cast<bf16x8*>(&As[sr][sk + q * 8]) = (bf16x8)(__bf16)0.f;
            }
        }
        if (NT == 8) {
            const __bf16* p = Bt + (size_t)(col0 + sr) * K + kc + sk;
#pragma unroll
            for (int q = 0; q < 4; ++q)
                *reinterpret_cast<bf16x8*>(&Bs[sr][sk + q * 8]) =
                    *reinterpret_cast<const bf16x8*>(p + q * 8);
        } else {  // NT==4: 64 B-rows, 16 bf16 per thread
            int sr4 = threadIdx.x >> 2, sk4 = (threadIdx.x & 3) * 16;
            const __bf16* p = Bt + (size_t)(col0 + sr4) * K + kc + sk4;
            *reinterpret_cast<bf16x8*>(&Bs[sr4][sk4]) = *reinterpret_cast<const bf16x8*>(p);
            *reinterpret_cast<bf16x8*>(&Bs[sr4][sk4 + 8]) = *reinterpret_cast<const bf16x8*>(p + 8);
        }
        __syncthreads();
#pragma unroll
        for (int ks = 0; ks < 64; ks += 32) {
            bf16x8 a0 = *reinterpret_cast<const bf16x8*>(&As[w * 32 + m][ks + quad * 8]);
            bf16x8 a1 = *reinterpret_cast<const bf16x8*>(&As[w * 32 + 16 + m][ks + quad * 8]);
#pragma unroll
            for (int nt = 0; nt < NT; ++nt) {
                bf16x8 b = *reinterpret_cast<const bf16x8*>(&Bs[nt * 16 + m][ks + quad * 8]);
                acc[0][nt] = __builtin_amdgcn_mfma_f32_16x16x32_bf16(a0, b, acc[0][nt], 0, 0, 0);
                acc[1][nt] = __builtin_amdgcn_mfma_f32_16x16x32_bf16(a1, b, acc[1][nt], 0, 0, 0);
            }
        }
        __syncthreads();
    }
#pragma unroll
    for (int mt = 0; mt < 2; ++mt)
#pragma unroll
        for (int nt = 0; nt < NT; ++nt)
#pragma unroll
            for (int r = 0; r < 4; ++r) {
                int row = row0 + w * 32 + mt * 16 + quad * 4 + r;
                if (row < n) Cb[(size_t)row * M + col0 + nt * 16 + m] = (__bf16)acc[mt][nt][r];
            }
    // fused attention dots (single complete head per block -> plain store)
    {
        float asv[NT], adv[NT];
#pragma unroll
        for (int nt = 0; nt < NT; ++nt) {
            int c = col0 + nt * 16 + m;
            asv[nt] = att_s[c];
            adv[nt] = att_d[c];
        }
        const int h = (col0 >> LC) & 1;
#pragma unroll
        for (int mt = 0; mt < 2; ++mt)
#pragma unroll
            for (int r = 0; r < 4; ++r) {
                int row = row0 + w * 32 + mt * 16 + quad * 4 + r;
                float pa = 0.f, pb = 0.f;
#pragma unroll
                for (int nt = 0; nt < NT; ++nt) {
                    float v = acc[mt][nt][r];
                    pa += v * asv[nt];
                    pb += v * adv[nt];
                }
#pragma unroll
                for (int off = 1; off <= 8; off <<= 1) {
                    pa += __shfl_xor(pa, off);
                    pb += __shfl_xor(pb, off);
                }
                if (m == 0 && row < n) {
                    asrc[2 * row + h] = pa;
                    adst[2 * row + h] = pb;
                }
            }
    }
}

// ---- final linear via MFMA: out[n,64](f32) = A[n,128](f32) @ lw[128,64] + lb ----
__global__ __launch_bounds__(256) void k_lin(const float* __restrict__ A,
                                             const float* __restrict__ lw,
                                             const float* __restrict__ lb,
                                             float* __restrict__ out, int n) {
    __shared__ __align__(16) __bf16 Ahi[64][136];
    __shared__ __align__(16) __bf16 Alo[64][136];
    __shared__ __align__(16) __bf16 Bhi[64][136];
    const int row0 = blockIdx.x * 64;
    const int lane = threadIdx.x & 63, w = threadIdx.x >> 6;
    const int m = lane & 15, quad = lane >> 4;
    floatx4 acc[4];
#pragma unroll
    for (int i = 0; i < 4; ++i) acc[i] = (floatx4)0.f;
    {
        int sr = threadIdx.x >> 2, sk0 = (threadIdx.x & 3) * 32;
        int grow = row0 + sr;
#pragma unroll
        for (int q = 0; q < 8; ++q) {
            float4 v = make_float4(0.f, 0.f, 0.f, 0.f);
            if (grow < n) v = *reinterpret_cast<const float4*>(A + (size_t)grow * 128 + sk0 + q * 4);
            float vv[4] = {v.x, v.y, v.z, v.w};
#pragma unroll
            for (int i = 0; i < 4; ++i) {
                __bf16 h = (__bf16)vv[i];
                Ahi[sr][sk0 + q * 4 + i] = h;
                Alo[sr][sk0 + q * 4 + i] = (__bf16)(vv[i] - (float)h);
            }
        }
    }
    {
        int k0 = threadIdx.x >> 1, m0 = (threadIdx.x & 1) * 32;
#pragma unroll
        for (int q = 0; q < 8; ++q) {
            float4 v = *reinterpret_cast<const float4*>(lw + (size_t)k0 * 64 + m0 + q * 4);
            float vv[4] = {v.x, v.y, v.z, v.w};
#pragma unroll
            for (int i = 0; i < 4; ++i) Bhi[m0 + q * 4 + i][k0] = (__bf16)vv[i];
        }
    }
    __syncthreads();
#pragma unroll
    for (int ks = 0; ks < 128; ks += 32) {
        bf16x8 ah = *reinterpret_cast<const bf16x8*>(&Ahi[w * 16 + m][ks + quad * 8]);
        bf16x8 al = *reinterpret_cast<const bf16x8*>(&Alo[w * 16 + m][ks + quad * 8]);
#pragma unroll
        for (int nt = 0; nt < 4; ++nt) {
            bf16x8 bh = *reinterpret_cast<const bf16x8*>(&Bhi[nt * 16 + m][ks + quad * 8]);
            acc[nt] = __builtin_amdgcn_mfma_f32_16x16x32_bf16(ah, bh, acc[nt], 0, 0, 0);
            acc[nt] = __builtin_amdgcn_mfma_f32_16x16x32_bf16(al, bh, acc[nt], 0, 0, 0);
        }
    }
#pragma unroll
    for (int nt = 0; nt < 4; ++nt)
#pragma unroll
        for (int r = 0; r < 4; ++r) {
            int row = row0 + w * 16 + quad * 4 + r;
            int c = nt * 16 + m;
            if (row < n) out[(size_t)row * 64 + c] = acc[nt][r] + lb[c];
        }
}

// ---- GAT aggregation (layers 2/3): node-per-wave depth-4 + SPLIT slots (same
//      addr-early / weight-late reorder as k_agg_in) ----
template <int C, bool OUTBF16>
__global__ __launch_bounds__(256) void k_agg(const __bf16* __restrict__ xh,
                                             const float* __restrict__ asrc,
                                             const float* __restrict__ adst,
                                             const int* __restrict__ degv,
                                             const int* __restrict__ col,
                                             const float* __restrict__ bias,
                                             void* __restrict__ outv, int n) {
    constexpr int F = 2 * C;          // bf16 per row (128)
    constexpr int G = F / 8;          // lanes per edge (16)
    constexpr int NG = 64 / G;        // edges per wave-step (4)
    constexpr int GSH = (G == 32) ? 5 : 4;
    __shared__ int sA[4][80];
    __shared__ float2 sW[4][80];
    const int widx = threadIdx.x >> 6;
    const int node = blockIdx.x * 4 + widx;
    const int lane = threadIdx.x & 63;
    if (node >= n) return;
    const int t = lane & (G - 1);
    const int g = lane >> GSH;
    const bool h1 = (t * 8) >= C;
    const int selfoff = node * (F * 2);
    if (lane >= 48) { sA[widx][lane + 16] = selfoff; sW[widx][lane + 16] = make_float2(0.f, 0.f); }
    const char* xbt = (const char*)xh + t * 16;
    const int* crow = col + ((size_t)node << 7);
    const int deg = min(degv[(size_t)node * DEGS], CAP);
    const float2 adv = *reinterpret_cast<const float2*>(adst + 2 * node);
    const float2 asv = *reinterpret_cast<const float2*>(asrc + 2 * node);
    const float es0 = leaky(asv.x + adv.x), es1 = leaky(asv.y + adv.y);
    bf16x8 vself = *reinterpret_cast<const bf16x8*>(xbt + selfoff);  // early issue
    float acc[8] = {};
    float d0 = 0.f, d1 = 0.f;
    for (int base = 0; base < deg; base += 64) {
        const int cnt = min(64, deg - base);
        int s = (lane < cnt) ? crow[base + lane] : node;
        sA[widx][lane] = s * (F * 2);
        float2 av = *reinterpret_cast<const float2*>(asrc + 2 * s);
        float w0 = 0.f, w1 = 0.f;
        if (lane < cnt) {
            w0 = __expf(leaky(av.x + adv.x));
            w1 = __expf(leaky(av.y + adv.y));
            d0 += w0; d1 += w1;
        }
        sW[widx][lane] = make_float2(w0, w1);
        for (int j = g; j < cnt; j += 4 * NG) {
            int o0 = sA[widx][j], o1 = sA[widx][j + NG], o2 = sA[widx][j + 2 * NG], o3 = sA[widx][j + 3 * NG];
            bf16x8 v0 = *reinterpret_cast<const bf16x8*>(xbt + o0);
            bf16x8 v1 = *reinterpret_cast<const bf16x8*>(xbt + o1);
            bf16x8 v2 = *reinterpret_cast<const bf16x8*>(xbt + o2);
            bf16x8 v3 = *reinterpret_cast<const bf16x8*>(xbt + o3);
            float2 x0 = sW[widx][j], x1 = sW[widx][j + NG], x2 = sW[widx][j + 2 * NG], x3 = sW[widx][j + 3 * NG];
            float w0 = h1 ? x0.y : x0.x;
            float w1 = h1 ? x1.y : x1.x;
            float w2 = h1 ? x2.y : x2.x;
            float w3 = h1 ? x3.y : x3.x;
#pragma unroll
            for (int q = 0; q < 8; ++q)
                acc[q] += w0 * (float)v0[q] + w1 * (float)v1[q] +
                          w2 * (float)v2[q] + w3 * (float)v3[q];
        }
    }
#pragma unroll
    for (int off = 1; off <= 32; off <<= 1) {
        d0 += __shfl_xor(d0, off);
        d1 += __shfl_xor(d1, off);
    }
#pragma unroll
    for (int q = 0; q < 8; ++q) {
#pragma unroll
        for (int off = G; off < 64; off <<= 1) acc[q] += __shfl_xor(acc[q], off);
    }
    float exs0 = __expf(es0), exs1 = __expf(es1);
    d0 += exs0; d1 += exs1;
    {
        float ws = h1 ? exs1 : exs0;
#pragma unroll
        for (int q = 0; q < 8; ++q) acc[q] += ws * (float)vself[q];
    }
    float inv = 1.0f / ((h1 ? d1 : d0) + EPS_SM);
    float o[8];
#pragma unroll
    for (int q = 0; q < 8; ++q) o[q] = fmaxf(acc[q] * inv + bias[t * 8 + q], 0.f);
    if (g == 0) {
        if constexpr (OUTBF16) {
            __bf16* po = (__bf16*)outv + (size_t)node * F + t * 8;
            bf16x8 st;
#pragma unroll
            for (int q = 0; q < 8; ++q) st[q] = (__bf16)o[q];
            *reinterpret_cast<bf16x8*>(po) = st;
        } else {
            float* po = (float*)outv + (size_t)node * F + t * 8;
            *reinterpret_cast<float4*>(po) = make_float4(o[0], o[1], o[2], o[3]);
            *reinterpret_cast<float4*>(po + 4) = make_float4(o[4], o[5], o[6], o[7]);
        }
    }
}

// ---------------- BatchNorm stats (layer 2 only; 256 blocks = low contention) ----
template <typename T>
__global__ void k_bn_stats(const T* __restrict__ x, float* __restrict__ sums,
                           float* __restrict__ sqs, int n, int f) {
    int c = threadIdx.x;
    float s = 0.f, q = 0.f;
    for (int r = blockIdx.x; r < n; r += gridDim.x) {
        float v = (float)x[(size_t)r * f + c];
        s += v; q += v * v;
    }
    atomicAdd(&sums[c], s);
    atomicAdd(&sqs[c], q);
}

// ---------------- launch ----------------
extern "C" void kernel_launch(void* const* d_in, const int* in_sizes, int n_in,
                              void* d_out, int out_size, void* d_ws, size_t ws_size,
                              hipStream_t stream) {
    const float* x   = (const float*)d_in[0];
    const int*   ei  = (const int*)d_in[1];
    const float* W1  = (const float*)d_in[2];
    const float* as1 = (const float*)d_in[3];
    const float* ad1 = (const float*)d_in[4];
    const float* b1  = (const float*)d_in[5];
    const float* g1  = (const float*)d_in[6];
    const float* be1 = (const float*)d_in[7];
    const float* W2  = (const float*)d_in[8];
    const float* as2 = (const float*)d_in[9];
    const float* ad2 = (const float*)d_in[10];
    const float* b2  = (const float*)d_in[11];
    const float* g2  = (const float*)d_in[12];
    const float* be2 = (const float*)d_in[13];
    const float* W3  = (const float*)d_in[14];
    const float* as3 = (const float*)d_in[15];
    const float* ad3 = (const float*)d_in[16];
    const float* b3  = (const float*)d_in[17];
    const float* lw  = (const float*)d_in[18];
    const float* lb  = (const float*)d_in[19];
    float* outp = (float*)d_out;

    const int n = in_sizes[0] / 128;  // 50000
    const int e = in_sizes[1] / 2;    // 800000

    char* w = (char*)d_ws;
    size_t off = 0;
    auto alloc = [&](size_t bytes) -> void* {
        void* p = w + off;
        off += (bytes + 255) & ~(size_t)255;
        return p;
    };
    __bf16* xhb = (__bf16*)alloc((size_t)n * 256 * 2);  // layer-1 agg out; later xh2/xh3
    __bf16* h1b = (__bf16*)alloc((size_t)n * 256 * 2);
    __bf16* h2b = (__bf16*)alloc((size_t)n * 128 * 2);
    float*  h3f = (float*)alloc((size_t)n * 128 * 4);
    int* colb   = (int*)alloc((size_t)n * CAP * 4);  // padded adjacency (25.6 MB)
    __bf16* xb  = (__bf16*)alloc((size_t)n * 128 * 2);  // bf16 copy of x (12.8 MB)
    __bf16* Wb1 = (__bf16*)alloc(256 * 128 * 2);
    __bf16* Wb2 = (__bf16*)alloc(128 * 256 * 2);
    __bf16* Wb3 = (__bf16*)alloc(128 * 128 * 2);
    float* wsd  = (float*)alloc(512 * 4);
    int* flag   = (int*)alloc(256);
    float* as1p = (float*)alloc((size_t)n * 2 * 4);
    float* ad1p = (float*)alloc((size_t)n * 2 * 4);
    float* as2p = (float*)alloc((size_t)n * 2 * 4);
    float* ad2p = (float*)alloc((size_t)n * 2 * 4);
    float* as3p = (float*)alloc((size_t)n * 2 * 4);
    float* ad3p = (float*)alloc((size_t)n * 2 * 4);
    // ---- contiguous zero block ----
    char* zb_begin = (char*)(w + off);
    int* deg    = (int*)alloc((size_t)n * DEGS * 4);  // line-padded counters (3.2 MB)
    float* bn1  = (float*)alloc(512 * 4);
    float* bn2  = (float*)alloc(512 * 4);
    char* zb_end = (char*)(w + off);
    const int zwords = (int)((zb_end - zb_begin) / 4);

    // init: detect (block 0) + zero (blocks 1..128) + wsd projection (block 129)
    k_init<<<130, 256, 0, stream>>>(ei, flag, (int*)zb_begin, zwords, e, W1, as1, ad1, wsd);

    const int ebase = ((e + 255) / 256) * 256;
    const int preblocks = (n + 31) / 32;
    const int histblocks = ebase / 256 + 320 + preblocks;  // edges + wconv + fused pre-pass
    k_hist_wconv<<<histblocks, 256, 0, stream>>>(ei, flag, deg, colb, e, ebase,
                                                 W1, Wb1, W2, Wb2, W3, Wb3,
                                                 x, wsd, xb, as1p, ad1p, n);

    const int nwb = (n + 3) / 4;
    const int nrow = (n + 127) / 128;

    // ---- layer 1: input-space aggregation, then GEMM (+fused BN1 stats) ----
    k_agg_in<<<nwb, 256, 0, stream>>>(xb, as1p, ad1p, deg, colb, xhb, n);
    k_gemm_ar<<<dim3(2, nrow), 256, 0, stream>>>(xhb, Wb1, b1, h1b, bn1, n);

    // ---- layer 2: 256 -> 2x64 (BN1 inline in GEMM prologue; 64-col tiles) ----
    k_gemm<256, 6, true, 4><<<dim3(2, nrow), 256, 0, stream>>>(
        h1b, Wb2, xhb, n, 128, bn1, g1, be1, as2, ad2, as2p, ad2p);
    k_agg<64, true><<<nwb, 256, 0, stream>>>(xhb, as2p, ad2p, deg, colb, b2, h2b, n);
    k_bn_stats<__bf16><<<256, 128, 0, stream>>>(h2b, bn2, bn2 + 256, n, 128);

    // ---- layer 3: 128 -> 2x64 (BN2 inline) ----
    k_gemm<128, 6, true, 4><<<dim3(2, nrow), 256, 0, stream>>>(
        h2b, Wb3, xhb, n, 128, bn2, g2, be2, as3, ad3, as3p, ad3p);
    k_agg<64, false><<<nwb, 256, 0, stream>>>(xhb, as3p, ad3p, deg, colb, b3, h3f, n);

    // ---- final linear ----
    k_lin<<<(n + 63) / 64, 256, 0, stream>>>(h3f, lw, lb, outp, n);
}